// Round 10
// baseline (6112.054 us; speedup 1.0000x reference)
//
#include <hip/hip_runtime.h>
#include <hip/hip_bf16.h>
#include <stdint.h>

// ---- problem constants ----
constexpr int LI   = 128;    // L_IN
constexpr int LO   = 64;     // L_OUT
constexpr int NB   = 32;     // batch
constexpr int HD   = 1024;   // H
constexpr int HHD  = 512;    // HH
constexpr int NLAY = 2;
constexpr int NV   = 32000;  // V_OUT
constexpr int SOST = 1;

// FP32 tensors; bf16x3 split MFMA. Persistent recurrence: W in registers,
// h exchanged via agent-scope (L3) atomics. Round-10: COMMUNICATOR SPLIT —
// enc: per-direction 32-block barriers; dec: 64-block layer groups with
// one-directional epoch cross-waits (layers overlap), layer1 merged to
// full-K blocks (PART handoff eliminated). Tests the "overhead ~ 0.13us x
// nblk" model that three barrier designs all exhibited.

typedef __hip_bfloat16 bf16;
typedef __attribute__((ext_vector_type(8))) short bf16x8;
typedef __attribute__((ext_vector_type(4))) float f32x4;
typedef unsigned long long u64;

constexpr int BSTR = 2048;   // flag stride in ints = 8 KB
constexpr int NEP  = 16;     // epoch replicas

__device__ __forceinline__ float b2f(bf16 x) { return __bfloat162float(x); }
__device__ __forceinline__ bf16  f2b(float x) { return __float2bfloat16(x); }
__device__ __forceinline__ float sigm(float x) { return 1.0f / (1.0f + expf(-x)); }

__device__ __forceinline__ f32x4 mfma(bf16x8 a, bf16x8 b, f32x4 c) {
    return __builtin_amdgcn_mfma_f32_16x16x32_bf16(a, b, c, 0, 0, 0);
}
__device__ __forceinline__ f32x4 mfma3(bf16x8 ah, bf16x8 al, bf16x8 bh, bf16x8 bl, f32x4 c) {
    c = mfma(ah, bh, c);
    c = mfma(ah, bl, c);
    c = mfma(al, bh, c);
    return c;
}
__device__ __forceinline__ bf16x8 ld8(const bf16* p) { return *(const bf16x8*)p; }

// ---- coherent (agent/L3) exchange helpers ----
__device__ __forceinline__ bf16x8 ldc(const bf16* p) {
    union { bf16x8 v; u64 q[2]; } u;
    u.q[0] = __hip_atomic_load((const u64*)p,     __ATOMIC_RELAXED, __HIP_MEMORY_SCOPE_AGENT);
    u.q[1] = __hip_atomic_load((const u64*)p + 1, __ATOMIC_RELAXED, __HIP_MEMORY_SCOPE_AGENT);
    return u.v;
}
__device__ __forceinline__ void stc2(bf16* p, bf16 a, bf16 b) {
    unsigned v = (unsigned)*(const unsigned short*)&a |
                 ((unsigned)*(const unsigned short*)&b << 16);
    __hip_atomic_store((unsigned*)p, v, __ATOMIC_RELAXED, __HIP_MEMORY_SCOPE_AGENT);
}

__device__ __forceinline__ void split8(const float* p, bf16x8& h8, bf16x8& l8) {
    #pragma unroll
    for (int j = 0; j < 8; j++) {
        float v = p[j];
        bf16 h = f2b(v);
        bf16 l = f2b(v - b2f(h));
        ((bf16*)&h8)[j] = h;
        ((bf16*)&l8)[j] = l;
    }
}

// ---- group barrier with optional cross-group epoch wait ----
// Arrival: store own 8KB-strided flag. Master polls group flags, releases
// NEP strided epoch replicas. Consumers poll own replica. Optionally all
// blocks then wait for the OTHER group's epoch >= valo (pipeline coupling).
__device__ __forceinline__ void gbar3(int* __restrict__ fl, int* __restrict__ ep,
                                      int nblk, int myid, int val, bool master,
                                      int* __restrict__ epo, int valo) {
    __syncthreads();
    const int tid = threadIdx.x;
    if (tid < 64) {
        if (tid == 0) {
            asm volatile("s_waitcnt vmcnt(0)" ::: "memory");
            __hip_atomic_store(&fl[myid * BSTR], val, __ATOMIC_RELAXED, __HIP_MEMORY_SCOPE_AGENT);
        }
        if (master) {
            bool done = false;
            while (!done) {
                bool ok = true;
                for (int i = tid; i < nblk; i += 64)
                    ok &= (__hip_atomic_load(&fl[i * BSTR], __ATOMIC_RELAXED, __HIP_MEMORY_SCOPE_AGENT) >= val);
                done = __all(ok);
                if (!done) __builtin_amdgcn_s_sleep(1);
            }
            if (tid < NEP)
                __hip_atomic_store(&ep[tid * BSTR], val, __ATOMIC_RELAXED, __HIP_MEMORY_SCOPE_AGENT);
        } else if (tid == 0) {
            int* e = &ep[(myid & (NEP - 1)) * BSTR];
            while (__hip_atomic_load(e, __ATOMIC_RELAXED, __HIP_MEMORY_SCOPE_AGENT) < val)
                __builtin_amdgcn_s_sleep(1);
        }
        if (epo != nullptr && tid == 0) {
            int* e2 = &epo[(myid & (NEP - 1)) * BSTR];
            while (__hip_atomic_load(e2, __ATOMIC_RELAXED, __HIP_MEMORY_SCOPE_AGENT) < valo)
                __builtin_amdgcn_s_sleep(1);
        }
        asm volatile("" ::: "memory");
    }
    __syncthreads();
}

// =====================================================================
// Split-precision MFMA GEMM (unchanged).
// =====================================================================
template<int BM, bool BIAS, bool TANH>
__global__ __launch_bounds__(256) void gemm_k(
    const float* __restrict__ A, int64_t lda, int64_t sA,
    const float* __restrict__ W, int64_t ldw, int64_t sW,
    float* __restrict__ C, int64_t ldc, int64_t sC,
    const float* __restrict__ bias, int64_t sBias,
    int K)
{
    constexpr int FM = BM / 32;
    __shared__ __align__(16) bf16 Ahi[BM * 32], Alo[BM * 32];
    __shared__ __align__(16) bf16 Whi[128 * 32], Wlo[128 * 32];
    const int z    = blockIdx.z;
    const float* Ab = A + (int64_t)z * sA;
    const float* Wb = W + (int64_t)z * sW;
    const int n0   = blockIdx.x * 128;
    const int m0   = blockIdx.y * BM;
    const int tid  = threadIdx.x;
    const int lane = tid & 63, wid = tid >> 6;
    const int wm   = wid >> 1, wn = wid & 1;
    const int srow = lane >> 2;
    const int skb  = (lane & 3) * 8;
    const int r16  = lane & 15;
    const int k8   = (lane >> 4) * 8;

    f32x4 acc[FM][4];
    #pragma unroll
    for (int i = 0; i < FM; i++)
        #pragma unroll
        for (int j = 0; j < 4; j++)
            acc[i][j] = f32x4{0.f, 0.f, 0.f, 0.f};

    for (int k0 = 0; k0 < K; k0 += 32) {
        for (int c = wid; c < BM / 16; c += 4) {
            bf16x8 h8, l8;
            split8(Ab + (int64_t)(m0 + c * 16 + srow) * lda + k0 + skb, h8, l8);
            *(bf16x8*)(Ahi + c * 512 + lane * 8) = h8;
            *(bf16x8*)(Alo + c * 512 + lane * 8) = l8;
        }
        for (int c = wid; c < 8; c += 4) {
            bf16x8 h8, l8;
            split8(Wb + (int64_t)(n0 + c * 16 + srow) * ldw + k0 + skb, h8, l8);
            *(bf16x8*)(Whi + c * 512 + lane * 8) = h8;
            *(bf16x8*)(Wlo + c * 512 + lane * 8) = l8;
        }
        __syncthreads();
        bf16x8 afh[FM], afl[FM], wfh[4], wfl[4];
        #pragma unroll
        for (int mt = 0; mt < FM; mt++) {
            const int off = (wm * (BM / 2) + mt * 16 + r16) * 32 + k8;
            afh[mt] = ld8(Ahi + off);
            afl[mt] = ld8(Alo + off);
        }
        #pragma unroll
        for (int nt = 0; nt < 4; nt++) {
            const int off = (wn * 64 + nt * 16 + r16) * 32 + k8;
            wfh[nt] = ld8(Whi + off);
            wfl[nt] = ld8(Wlo + off);
        }
        #pragma unroll
        for (int mt = 0; mt < FM; mt++)
            #pragma unroll
            for (int nt = 0; nt < 4; nt++)
                acc[mt][nt] = mfma3(afh[mt], afl[mt], wfh[nt], wfl[nt], acc[mt][nt]);
        __syncthreads();
    }
    #pragma unroll
    for (int nt = 0; nt < 4; nt++) {
        const int n = n0 + wn * 64 + nt * 16 + r16;
        float bv = 0.f;
        if constexpr (BIAS) bv = bias[(int64_t)z * sBias + n];
        #pragma unroll
        for (int mt = 0; mt < FM; mt++) {
            const int mb = m0 + wm * (BM / 2) + mt * 16 + (lane >> 4) * 4;
            #pragma unroll
            for (int r = 0; r < 4; r++) {
                float v = acc[mt][nt][r] + bv;
                if constexpr (TANH) v = tanhf(v);
                C[(int64_t)z * sC + (int64_t)(mb + r) * ldc + n] = v;
            }
        }
    }
}

__global__ void presplit_k(const float* __restrict__ x, bf16* __restrict__ hi,
                           bf16* __restrict__ lo, int n)
{
    const int i = blockIdx.x * 256 + threadIdx.x;
    if (i < n) {
        float v = x[i];
        bf16 h = f2b(v);
        hi[i] = h;
        lo[i] = f2b(v - b2f(h));
    }
}

__global__ void embed_k(const int* __restrict__ toks, const float* __restrict__ tab,
                        float* __restrict__ out, int shifted)
{
    const int row = blockIdx.x;
    int tok;
    if (shifted) {
        const int t = row / NB, b = row - t * NB;
        tok = (t == 0) ? SOST : toks[(t - 1) * NB + b];
    } else {
        tok = toks[row];
    }
    const uint4* s = (const uint4*)(tab + (int64_t)tok * HD);
    uint4* d = (uint4*)(out + (int64_t)row * HD);
    d[threadIdx.x] = s[threadIdx.x];
}

// =====================================================================
// Persistent encoder layer. Directions are INDEPENDENT -> per-dir
// 32-block barrier. Grid (HHD/16=32, 2 dirs) x 256 thr.
// =====================================================================
__global__ __launch_bounds__(256, 1) void enc_persist_k(
    const float* __restrict__ gi,
    const bf16* __restrict__ whhHi,
    const bf16* __restrict__ whhLo,
    const float* __restrict__ bhh,
    float* __restrict__ h32,
    bf16* __restrict__ hHi, bf16* __restrict__ hLo,
    float* __restrict__ Y,
    float* __restrict__ dh32, bf16* __restrict__ dhHi, bf16* __restrict__ dhLo,
    int* __restrict__ flags, int* __restrict__ epoch)
{
    __shared__ f32x4 red[4][6][64];
    const int d = blockIdx.y;
    const int j0 = blockIdx.x * 16;
    const int tid = threadIdx.x;
    const int lane = tid & 63, wid = tid >> 6;
    const int r16 = lane & 15, k8 = (lane >> 4) * 8;
    const int kq = wid * 128;
    const bf16* WdH = whhHi + (int64_t)d * 3 * HHD * HHD;
    const bf16* WdL = whhLo + (int64_t)d * 3 * HHD * HHD;
    const int j = j0 + r16;
    int* fl = flags + d * 32 * BSTR;
    int* ep = epoch + d * NEP * BSTR;
    const bool master = (blockIdx.x == 0);

    bf16x8 wh[3][4], wl[3][4];
    #pragma unroll
    for (int g = 0; g < 3; g++)
        #pragma unroll
        for (int kk = 0; kk < 4; kk++) {
            const int64_t wo = (int64_t)(g * HHD + j0 + r16) * HHD + kq + kk * 32 + k8;
            wh[g][kk] = ld8(WdH + wo);
            wl[g][kk] = ld8(WdL + wo);
        }
    const float br = bhh[d * 3 * HHD + j];
    const float bz = bhh[d * 3 * HHD + HHD + j];
    const float bn = bhh[d * 3 * HHD + 2 * HHD + j];

    for (int s = 0; s < LI; s++) {
        const int t = d ? (LI - 1 - s) : s;
        const int par = s & 1, npar = par ^ 1;
        const int64_t hbase = (int64_t)(par * 2 + d) * NB * HHD;

        f32x4 acc[2][3];
        #pragma unroll
        for (int m = 0; m < 2; m++)
            #pragma unroll
            for (int g = 0; g < 3; g++) acc[m][g] = f32x4{0.f, 0.f, 0.f, 0.f};

        #pragma unroll
        for (int kk = 0; kk < 4; kk++) {
            const int64_t o0 = hbase + (int64_t)r16 * HHD + kq + kk * 32 + k8;
            const int64_t o1 = hbase + (int64_t)(16 + r16) * HHD + kq + kk * 32 + k8;
            bf16x8 a0h = ldc(hHi + o0), a0l = ldc(hLo + o0);
            bf16x8 a1h = ldc(hHi + o1), a1l = ldc(hLo + o1);
            #pragma unroll
            for (int g = 0; g < 3; g++) {
                acc[0][g] = mfma3(a0h, a0l, wh[g][kk], wl[g][kk], acc[0][g]);
                acc[1][g] = mfma3(a1h, a1l, wh[g][kk], wl[g][kk], acc[1][g]);
            }
        }
        #pragma unroll
        for (int m = 0; m < 2; m++)
            #pragma unroll
            for (int g = 0; g < 3; g++)
                red[wid][m * 3 + g][lane] = acc[m][g];
        __syncthreads();
        if (wid == 0) {
            f32x4 a2[2][3];
            #pragma unroll
            for (int m = 0; m < 2; m++)
                #pragma unroll
                for (int g = 0; g < 3; g++)
                    a2[m][g] = red[0][m * 3 + g][lane] + red[1][m * 3 + g][lane]
                             + red[2][m * 3 + g][lane] + red[3][m * 3 + g][lane];
            const float* gid = gi + ((int64_t)d * LI * NB + (int64_t)t * NB) * (3 * HHD);
            #pragma unroll
            for (int mt = 0; mt < 2; mt++)
                #pragma unroll
                for (int r = 0; r < 4; r++) {
                    const int b = mt * 16 + (lane >> 4) * 4 + r;
                    const float ir  = gid[b * 3 * HHD + j];
                    const float iz  = gid[b * 3 * HHD + HHD + j];
                    const float inn = gid[b * 3 * HHD + 2 * HHD + j];
                    const float rg = sigm(ir + a2[mt][0][r] + br);
                    const float zg = sigm(iz + a2[mt][1][r] + bz);
                    const float ng = tanhf(inn + rg * (a2[mt][2][r] + bn));
                    const float hold = h32[hbase + (int64_t)b * HHD + j];
                    const float hnew = (1.f - zg) * ng + zg * hold;
                    const int64_t no = (int64_t)(npar * 2 + d) * NB * HHD + (int64_t)b * HHD + j;
                    bf16 hh = f2b(hnew);
                    bf16 hl = f2b(hnew - b2f(hh));
                    h32[no] = hnew;
                    const float hn2 = __shfl_xor(hnew, 1);
                    if (!(lane & 1)) {
                        bf16 hh2 = f2b(hn2);
                        bf16 hl2 = f2b(hn2 - b2f(hh2));
                        stc2(hHi + no, hh, hh2);
                        stc2(hLo + no, hl, hl2);
                    }
                    Y[((int64_t)t * NB + b) * HD + d * HHD + j] = hnew;
                    if (s == LI - 1) {
                        const int64_t dof = (int64_t)b * HD + d * HHD + j;
                        dh32[dof] = hnew;
                        dhHi[dof] = hh;
                        dhLo[dof] = hl;
                    }
                }
        }
        if (s < LI - 1) gbar3(fl, ep, 32, blockIdx.x, s + 1, master, nullptr, 0);
    }
}

// =====================================================================
// Persistent decoder: two 64-block layer groups, each with its own
// barrier; epoch cross-waits couple them (layer0 <=1 step ahead).
// Grid (HD/16=64, 2) x 512 thr. Layer1: full-K per block,
// wave = matrix(2) x Kquarter(4); W = 192 VGPR/wave.
// =====================================================================
__global__ __launch_bounds__(512, 1) void dec_persist_k(
    const float* __restrict__ gi0,
    const bf16* __restrict__ wih1Hi, const bf16* __restrict__ wih1Lo,
    const bf16* __restrict__ whh0Hi, const bf16* __restrict__ whh0Lo,
    const bf16* __restrict__ whh1Hi, const bf16* __restrict__ whh1Lo,
    const float* __restrict__ bih1,
    const float* __restrict__ bhh0,
    const float* __restrict__ bhh1,
    float* __restrict__ h32,
    bf16* __restrict__ hHi, bf16* __restrict__ hLo,
    float* __restrict__ rnn,
    int* __restrict__ fl0, int* __restrict__ ep0,
    int* __restrict__ fl1, int* __restrict__ ep1)
{
    __shared__ f32x4 red[8][6][64];   // 48 KiB
    const int tid = threadIdx.x;
    const int lane = tid & 63, wid = tid >> 6;
    const int r16 = lane & 15, k8 = (lane >> 4) * 8;
    const int bx = blockIdx.x;
    const int j0 = bx * 16;
    const int j = j0 + r16;
    const bool master = (bx == 0);

    if (blockIdx.y == 0) {
        // ---- layer 0 group: 64 blocks, K-split 128/wave ----
        const int kq = wid * 128;
        bf16x8 wh[3][4], wl[3][4];
        #pragma unroll
        for (int g = 0; g < 3; g++)
            #pragma unroll
            for (int kk = 0; kk < 4; kk++) {
                const int64_t wo = (int64_t)(g * HD + j0 + r16) * HD + kq + kk * 32 + k8;
                wh[g][kk] = ld8(whh0Hi + wo);
                wl[g][kk] = ld8(whh0Lo + wo);
            }
        const float b0r = bhh0[j], b0z = bhh0[HD + j], b0n = bhh0[2 * HD + j];

        for (int s = 0; s < LO; s++) {
            const int t = s, par = t & 1, npar = par ^ 1;
            const int64_t hb = (int64_t)(par * NLAY + 0) * NB * HD;
            f32x4 acc[2][3];
            #pragma unroll
            for (int m = 0; m < 2; m++)
                #pragma unroll
                for (int g = 0; g < 3; g++) acc[m][g] = f32x4{0.f, 0.f, 0.f, 0.f};
            #pragma unroll
            for (int kk = 0; kk < 4; kk++) {
                const int64_t o0 = hb + (int64_t)r16 * HD + kq + kk * 32 + k8;
                const int64_t o1 = hb + (int64_t)(16 + r16) * HD + kq + kk * 32 + k8;
                bf16x8 a0h = ldc(hHi + o0), a0l = ldc(hLo + o0);
                bf16x8 a1h = ldc(hHi + o1), a1l = ldc(hLo + o1);
                #pragma unroll
                for (int g = 0; g < 3; g++) {
                    acc[0][g] = mfma3(a0h, a0l, wh[g][kk], wl[g][kk], acc[0][g]);
                    acc[1][g] = mfma3(a1h, a1l, wh[g][kk], wl[g][kk], acc[1][g]);
                }
            }
            #pragma unroll
            for (int m = 0; m < 2; m++)
                #pragma unroll
                for (int g = 0; g < 3; g++)
                    red[wid][m * 3 + g][lane] = acc[m][g];
            __syncthreads();
            if (wid == 0) {
                f32x4 a2[2][3];
                #pragma unroll
                for (int m = 0; m < 2; m++)
                    #pragma unroll
                    for (int g = 0; g < 3; g++) {
                        f32x4 v = red[0][m * 3 + g][lane];
                        #pragma unroll
                        for (int w2 = 1; w2 < 8; w2++) v += red[w2][m * 3 + g][lane];
                        a2[m][g] = v;
                    }
                const float* gid = gi0 + (int64_t)t * NB * 3 * HD;
                #pragma unroll
                for (int mt = 0; mt < 2; mt++)
                    #pragma unroll
                    for (int r = 0; r < 4; r++) {
                        const int b = mt * 16 + (lane >> 4) * 4 + r;
                        const float ir  = gid[b * 3 * HD + j];
                        const float iz  = gid[b * 3 * HD + HD + j];
                        const float inn = gid[b * 3 * HD + 2 * HD + j];
                        const float rg = sigm(ir + a2[mt][0][r] + b0r);
                        const float zg = sigm(iz + a2[mt][1][r] + b0z);
                        const float ng = tanhf(inn + rg * (a2[mt][2][r] + b0n));
                        const float hold = h32[hb + (int64_t)b * HD + j];
                        const float hnew = (1.f - zg) * ng + zg * hold;
                        const int64_t no = (int64_t)(npar * NLAY + 0) * NB * HD + (int64_t)b * HD + j;
                        bf16 hh = f2b(hnew);
                        bf16 hl = f2b(hnew - b2f(hh));
                        h32[no] = hnew;
                        const float hn2 = __shfl_xor(hnew, 1);
                        if (!(lane & 1)) {
                            bf16 hh2 = f2b(hn2);
                            bf16 hl2 = f2b(hn2 - b2f(hh2));
                            stc2(hHi + no, hh, hh2);
                            stc2(hLo + no, hl, hl2);
                        }
                    }
            }
            // own group barrier (val s+1); before overwriting h0 slot at
            // iter s+1 we need layer1 iter s done reading -> wait ep1 >= s.
            gbar3(fl0, ep0, 64, bx, s + 1, master, (s >= 1) ? ep1 : nullptr, s);
        }
    } else {
        // ---- layer 1 group: 64 blocks, full K; wave = mm*4 + kquarter ----
        const int mm = wid >> 2;                 // 0: x @ wih1, 1: y @ whh1
        const int kq = (wid & 3) * 256;
        const bf16* WHi = mm ? whh1Hi : wih1Hi;
        const bf16* WLo = mm ? whh1Lo : wih1Lo;
        bf16x8 wh[3][8], wl[3][8];
        #pragma unroll
        for (int g = 0; g < 3; g++)
            #pragma unroll
            for (int kk = 0; kk < 8; kk++) {
                const int64_t wo = (int64_t)(g * HD + j0 + r16) * HD + kq + kk * 32 + k8;
                wh[g][kk] = ld8(WHi + wo);
                wl[g][kk] = ld8(WLo + wo);
            }
        const float brr = bih1[j] + bhh1[j];
        const float bzz = bih1[HD + j] + bhh1[HD + j];
        const float bin = bih1[2 * HD + j];
        const float bhn = bhh1[2 * HD + j];

        // wait for layer0 step 0 (h0(0) ready)
        if (tid == 0) {
            int* e = &ep0[(bx & (NEP - 1)) * BSTR];
            while (__hip_atomic_load(e, __ATOMIC_RELAXED, __HIP_MEMORY_SCOPE_AGENT) < 1)
                __builtin_amdgcn_s_sleep(1);
        }
        __syncthreads();

        for (int s = 1; s <= LO; s++) {
            const int t = s - 1;
            const int p0 = (t + 1) & 1;
            const int p1 = t & 1, np1 = p1 ^ 1;
            const int64_t h0b = (int64_t)(p0 * NLAY + 0) * NB * HD;
            const int64_t h1b = (int64_t)(p1 * NLAY + 1) * NB * HD;
            const int64_t hb = mm ? h1b : h0b;

            f32x4 a[3][2];
            #pragma unroll
            for (int g = 0; g < 3; g++) {
                a[g][0] = f32x4{0.f, 0.f, 0.f, 0.f};
                a[g][1] = f32x4{0.f, 0.f, 0.f, 0.f};
            }
            #pragma unroll
            for (int kk = 0; kk < 8; kk++) {
                const int64_t o0 = hb + (int64_t)r16 * HD + kq + kk * 32 + k8;
                const int64_t o1 = hb + (int64_t)(16 + r16) * HD + kq + kk * 32 + k8;
                bf16x8 a0h = ldc(hHi + o0), a0l = ldc(hLo + o0);
                bf16x8 a1h = ldc(hHi + o1), a1l = ldc(hLo + o1);
                #pragma unroll
                for (int g = 0; g < 3; g++) {
                    a[g][0] = mfma3(a0h, a0l, wh[g][kk], wl[g][kk], a[g][0]);
                    a[g][1] = mfma3(a1h, a1l, wh[g][kk], wl[g][kk], a[g][1]);
                }
            }
            #pragma unroll
            for (int g = 0; g < 3; g++) {
                red[wid][g * 2 + 0][lane] = a[g][0];
                red[wid][g * 2 + 1][lane] = a[g][1];
            }
            __syncthreads();
            if (wid == 0) {
                f32x4 rr[2], zz[2], in_[2], hn[2];
                #pragma unroll
                for (int mt = 0; mt < 2; mt++) {
                    f32x4 vr = red[0][0 * 2 + mt][lane];
                    f32x4 vz = red[0][1 * 2 + mt][lane];
                    #pragma unroll
                    for (int w2 = 1; w2 < 8; w2++) {
                        vr += red[w2][0 * 2 + mt][lane];
                        vz += red[w2][1 * 2 + mt][lane];
                    }
                    rr[mt] = vr; zz[mt] = vz;
                    f32x4 vi = red[0][2 * 2 + mt][lane];
                    #pragma unroll
                    for (int w2 = 1; w2 < 4; w2++) vi += red[w2][2 * 2 + mt][lane];
                    in_[mt] = vi;
                    f32x4 vh = red[4][2 * 2 + mt][lane];
                    #pragma unroll
                    for (int w2 = 5; w2 < 8; w2++) vh += red[w2][2 * 2 + mt][lane];
                    hn[mt] = vh;
                }
                #pragma unroll
                for (int mt = 0; mt < 2; mt++)
                    #pragma unroll
                    for (int r = 0; r < 4; r++) {
                        const int b = mt * 16 + (lane >> 4) * 4 + r;
                        const float rg = sigm(rr[mt][r] + brr);
                        const float zg = sigm(zz[mt][r] + bzz);
                        const float ng = tanhf(in_[mt][r] + bin + rg * (hn[mt][r] + bhn));
                        const float hold = h32[h1b + (int64_t)b * HD + j];
                        const float hnew = (1.f - zg) * ng + zg * hold;
                        const int64_t no = (int64_t)(np1 * NLAY + 1) * NB * HD + (int64_t)b * HD + j;
                        bf16 hh = f2b(hnew);
                        bf16 hl = f2b(hnew - b2f(hh));
                        h32[no] = hnew;
                        const float hn2 = __shfl_xor(hnew, 1);
                        if (!(lane & 1)) {
                            bf16 hh2 = f2b(hn2);
                            bf16 hl2 = f2b(hn2 - b2f(hh2));
                            stc2(hHi + no, hh, hh2);
                            stc2(hLo + no, hl, hl2);
                        }
                        rnn[((int64_t)t * NB + b) * HD + j] = hnew;
                    }
            }
            // own barrier (val s) + wait for layer0's next h0 (ep0 >= s+1)
            if (s < LO) gbar3(fl1, ep1, 64, bx, s, master, ep0, s + 1);
        }
    }
}

// =====================================================================
__global__ __launch_bounds__(64) void softmax_k(const float* __restrict__ sc,
                                                float* __restrict__ aout)
{
    const int row = blockIdx.x, l = threadIdx.x;
    float v0 = sc[row * LI + l], v1 = sc[row * LI + 64 + l];
    float m = fmaxf(v0, v1);
    #pragma unroll
    for (int o = 32; o > 0; o >>= 1) m = fmaxf(m, __shfl_xor(m, o));
    float e0 = expf(v0 - m), e1 = expf(v1 - m);
    float s = e0 + e1;
    #pragma unroll
    for (int o = 32; o > 0; o >>= 1) s += __shfl_xor(s, o);
    const float inv = 1.f / s;
    aout[row * LI + l] = e0 * inv;
    aout[row * LI + 64 + l] = e1 * inv;
}

__global__ __launch_bounds__(256) void ctx_k(const float* __restrict__ at,
                                             const float* __restrict__ enc,
                                             float* __restrict__ jin)
{
    const int b = blockIdx.y, h0 = blockIdx.x * 128;
    __shared__ __align__(16) float al[LO][LI];
    for (int i = threadIdx.x; i < LO * LI; i += 256) {
        const int to = i >> 7, ti = i & 127;
        al[to][ti] = at[(to * NB + b) * LI + ti];
    }
    __syncthreads();
    const int hc = h0 + (threadIdx.x & 127);
    const int rh = threadIdx.x >> 7;
    float acc[32];
    #pragma unroll
    for (int i = 0; i < 32; i++) acc[i] = 0.f;
    for (int t = 0; t < LI; t++) {
        const float ev = enc[((int64_t)t * NB + b) * HD + hc];
        #pragma unroll
        for (int i = 0; i < 32; i++) acc[i] += ev * al[rh * 32 + i][t];
    }
    #pragma unroll
    for (int i = 0; i < 32; i++)
        jin[((int64_t)(rh * 32 + i) * NB + b) * (2 * HD) + hc] = acc[i];
}

__global__ void rnncopy_k(const float* __restrict__ rnn, float* __restrict__ jin)
{
    const int idx = blockIdx.x * 256 + threadIdx.x;
    const int row = idx >> 8;
    const int c = idx & 255;
    ((uint4*)jin)[(int64_t)row * 512 + 256 + c] = ((const uint4*)rnn)[idx];
}

// =====================================================================
extern "C" void kernel_launch(void* const* d_in, const int* in_sizes, int n_in,
                              void* d_out, int out_size, void* d_ws, size_t ws_size,
                              hipStream_t stream)
{
    (void)in_sizes; (void)n_in; (void)out_size; (void)ws_size;
    const int*   in_tok   = (const int*)d_in[0];
    const int*   out_tok  = (const int*)d_in[2];
    const float* enc_emb  = (const float*)d_in[4];
    const float* enc_wih  = (const float*)d_in[5];
    const float* enc_whh  = (const float*)d_in[6];
    const float* enc_bih  = (const float*)d_in[7];
    const float* enc_bhh  = (const float*)d_in[8];
    const float* dec_emb  = (const float*)d_in[9];
    const float* dec_wih  = (const float*)d_in[10];
    const float* dec_whh  = (const float*)d_in[11];
    const float* dec_bih  = (const float*)d_in[12];
    const float* dec_bhh  = (const float*)d_in[13];
    const float* attn_W   = (const float*)d_in[14];
    const float* joiner_W = (const float*)d_in[15];
    const float* joiner_b = (const float*)d_in[16];
    const float* proj_W   = (const float*)d_in[17];
    const float* proj_b   = (const float*)d_in[18];
    float* logits   = (float*)d_out;
    float* attn_out = logits + (size_t)LO * NB * NV;

    const size_t MB = 1ull << 20;
    char* o = (char*)d_out;   // logits region alone is 262 MiB fp32
    float* XB0   = (float*)(o);              // 16 MiB enc embedded input
    float* XB1   = (float*)(o + 16 * MB);    // 16 MiB enc layer0 output
    float* EOUT  = (float*)(o + 32 * MB);    // 16 MiB enc_outputs
    float* PENC  = (float*)(o + 48 * MB);    // 16 MiB proj_enc
    float* GI    = (float*)(o + 64 * MB);    // 48 MiB enc gi (both dirs)
    float* DEMB  = (float*)(o + 112 * MB);   //  8 MiB dec embedded
    float* DGI0  = (float*)(o + 120 * MB);   // 24 MiB dec layer0 gi
    float* RNN   = (float*)(o + 144 * MB);   //  8 MiB rnn_out
    float* SC    = (float*)(o + 152 * MB);   //  1 MiB scores
    float* JIN   = (float*)(o + 153 * MB);   // 16 MiB cat(ctx, rnn)
    bf16* WencHi = (bf16*)(o + 169 * MB);    //  6 MiB enc_whh hi
    bf16* WencLo = (bf16*)(o + 175 * MB);    //  6 MiB enc_whh lo
    bf16* WdhHi  = (bf16*)(o + 181 * MB);    // 12 MiB dec_whh hi
    bf16* WdhLo  = (bf16*)(o + 193 * MB);    // 12 MiB dec_whh lo
    bf16* Wih1Hi = (bf16*)(o + 205 * MB);    //  6 MiB dec_wih[1] hi
    bf16* Wih1Lo = (bf16*)(o + 211 * MB);    //  6 MiB dec_wih[1] lo
    // ---- barrier arena: 8KB-strided flags + epoch replicas ----
    char* ba = o + 220 * MB;                 // <= 4 MiB
    const size_t KB = 1024;
    int* FL_E0 = (int*)(ba);                 // 2 dirs x 32 x 8KB = 512 KiB
    int* EP_E0 = (int*)(ba + 512 * KB);      // 2 dirs x 16 x 8KB = 256 KiB
    int* FL_E1 = (int*)(ba + 768 * KB);      // 512 KiB
    int* EP_E1 = (int*)(ba + 1280 * KB);     // 256 KiB
    int* FL_D0 = (int*)(ba + 1536 * KB);     // 64 x 8KB = 512 KiB
    int* EP_D0 = (int*)(ba + 2048 * KB);     // 128 KiB
    int* FL_D1 = (int*)(ba + 2176 * KB);     // 512 KiB
    int* EP_D1 = (int*)(ba + 2688 * KB);     // 128 KiB -> ends 2816 KiB

    char* w = (char*)d_ws;                   // 10 MiB total
    float* VECS = (float*)(w);                       // 8 MiB tanh(joiner)
    float* EH32 = (float*)(w + 8 * MB);              // 512 KiB
    bf16*  EHhi = (bf16*) (w + 8 * MB + 524288);     // 256 KiB
    bf16*  EHlo = (bf16*) (w + 8 * MB + 786432);     // 256 KiB
    float* DH32 = (float*)(w + 9 * MB);              // 512 KiB
    bf16*  DHhi = (bf16*) (w + 9 * MB + 524288);     // 256 KiB
    bf16*  DHlo = (bf16*) (w + 9 * MB + 786432);     // 256 KiB

    hipMemsetAsync(ba, 0, 4 * MB, stream);

    // ---- pre-split recurrent weights ----
    const int nEnc = NLAY * 2 * 3 * HHD * HHD;
    const int nDhh = NLAY * 3 * HD * HD;
    const int nIh1 = 3 * HD * HD;
    presplit_k<<<dim3((nEnc + 255) / 256), dim3(256), 0, stream>>>(enc_whh, WencHi, WencLo, nEnc);
    presplit_k<<<dim3((nDhh + 255) / 256), dim3(256), 0, stream>>>(dec_whh, WdhHi, WdhLo, nDhh);
    presplit_k<<<dim3((nIh1 + 255) / 256), dim3(256), 0, stream>>>(dec_wih + (size_t)3 * HD * HD, Wih1Hi, Wih1Lo, nIh1);

    // ---- decoder prep ----
    embed_k<<<dim3(LO * NB), dim3(256), 0, stream>>>(out_tok, dec_emb, DEMB, 1);
    gemm_k<128, true, false><<<dim3(3 * HD / 128, LO * NB / 128, 1), 256, 0, stream>>>(
        DEMB, HD, 0, dec_wih, HD, 0, DGI0, 3 * HD, 0, dec_bih, 0, HD);

    // ---- encoder ----
    embed_k<<<dim3(LI * NB), dim3(256), 0, stream>>>(in_tok, enc_emb, XB0, 0);
    for (int l = 0; l < NLAY; l++) {
        const float* Xin = l ? XB1 : XB0;
        float* Yout = l ? EOUT : XB1;
        hipMemsetAsync(EH32, 0, (size_t)2 * 2 * NB * HHD * 4, stream);
        hipMemsetAsync(EHhi, 0, (size_t)2 * 2 * NB * HHD * 2, stream);
        hipMemsetAsync(EHlo, 0, (size_t)2 * 2 * NB * HHD * 2, stream);
        gemm_k<128, true, false><<<dim3(3 * HHD / 128, LI * NB / 128, 2), 256, 0, stream>>>(
            Xin, HD, 0,
            enc_wih + (size_t)l * 2 * 3 * HHD * HD, HD, (int64_t)3 * HHD * HD,
            GI, 3 * HHD, (int64_t)LI * NB * 3 * HHD,
            enc_bih + l * 2 * 3 * HHD, 3 * HHD, HD);
        enc_persist_k<<<dim3(HHD / 16, 2), dim3(256), 0, stream>>>(
            GI,
            WencHi + (size_t)l * 2 * 3 * HHD * HHD,
            WencLo + (size_t)l * 2 * 3 * HHD * HHD,
            enc_bhh + l * 2 * 3 * HHD,
            EH32, EHhi, EHlo, Yout,
            DH32 + (size_t)l * NB * HD, DHhi + (size_t)l * NB * HD,
            DHlo + (size_t)l * NB * HD,
            l ? FL_E1 : FL_E0, l ? EP_E1 : EP_E0);
    }

    // proj_enc = enc_outputs @ attn_W^T
    gemm_k<128, false, false><<<dim3(HD / 128, LI * NB / 128, 1), 256, 0, stream>>>(
        EOUT, HD, 0, attn_W, HD, 0, PENC, HD, 0, nullptr, 0, HD);

    // ---- decoder recurrence (persistent, split communicators) ----
    dec_persist_k<<<dim3(HD / 16, 2), dim3(512), 0, stream>>>(
        DGI0,
        Wih1Hi, Wih1Lo,
        WdhHi, WdhLo,
        WdhHi + (size_t)3 * HD * HD, WdhLo + (size_t)3 * HD * HD,
        dec_bih + 3 * HD, dec_bhh, dec_bhh + 3 * HD,
        DH32, DHhi, DHlo, RNN,
        FL_D0, EP_D0, FL_D1, EP_D1);

    // ---- batched epilogue ----
    gemm_k<64, false, false><<<dim3(1, 1, NB), 256, 0, stream>>>(
        RNN, (int64_t)NB * HD, HD, PENC, (int64_t)NB * HD, HD,
        SC, (int64_t)NB * LI, LI, nullptr, 0, HD);
    softmax_k<<<dim3(LO * NB), dim3(64), 0, stream>>>(SC, attn_out);
    ctx_k<<<dim3(HD / 128, NB), dim3(256), 0, stream>>>(attn_out, EOUT, JIN);
    rnncopy_k<<<dim3(LO * NB * HD / 4 / 256), dim3(256), 0, stream>>>(RNN, JIN);
    gemm_k<128, true, true><<<dim3(HD / 128, LO * NB / 128, 1), 256, 0, stream>>>(
        JIN, 2 * HD, 0, joiner_W, 2 * HD, 0, VECS, HD, 0, joiner_b, 0, 2 * HD);
    gemm_k<128, true, false><<<dim3(NV / 128, LO * NB / 128, 1), 256, 0, stream>>>(
        VECS, HD, 0, proj_W, HD, 0, logits, NV, 0, proj_b, 0, HD);
}

// Round 11
// 5118.131 us; speedup vs baseline: 1.1942x; 1.1942x over previous
//
#include <hip/hip_runtime.h>
#include <hip/hip_bf16.h>
#include <stdint.h>

// ---- problem constants ----
constexpr int LI   = 128;    // L_IN
constexpr int LO   = 64;     // L_OUT
constexpr int NB   = 32;     // batch
constexpr int HD   = 1024;   // H
constexpr int HHD  = 512;    // HH
constexpr int NLAY = 2;
constexpr int NV   = 32000;  // V_OUT
constexpr int SOST = 1;

// FP32 tensors; bf16x3 split MFMA. Persistent recurrence, W in registers.
// Round-11: CACHED h-reads via per-step fresh buffers. Rounds 7-10 showed
// per-step cost invariant to barrier design; it tracks the UNCACHED
// (agent-atomic) h read volume. Fix: atomic STORES (to L3) + normal cached
// LOADS from per-step slots (never-cached addresses -> first touch pulls
// fresh from L3, once per XCD instead of once per block).

typedef __hip_bfloat16 bf16;
typedef __attribute__((ext_vector_type(8))) short bf16x8;
typedef __attribute__((ext_vector_type(4))) float f32x4;
typedef unsigned long long u64;

constexpr int BSTR = 2048;   // barrier flag stride in ints = 8 KB
constexpr int NEP  = 16;     // epoch replicas
constexpr int ESLOT = 2 * NB * HHD;     // enc per-step slot (elems) = 64 KB
constexpr int DSLOT = NLAY * NB * HD;   // dec per-step slot (elems) = 128 KB

__device__ __forceinline__ float b2f(bf16 x) { return __bfloat162float(x); }
__device__ __forceinline__ bf16  f2b(float x) { return __float2bfloat16(x); }
__device__ __forceinline__ float sigm(float x) { return 1.0f / (1.0f + expf(-x)); }

__device__ __forceinline__ f32x4 mfma(bf16x8 a, bf16x8 b, f32x4 c) {
    return __builtin_amdgcn_mfma_f32_16x16x32_bf16(a, b, c, 0, 0, 0);
}
__device__ __forceinline__ f32x4 mfma3(bf16x8 ah, bf16x8 al, bf16x8 bh, bf16x8 bl, f32x4 c) {
    c = mfma(ah, bh, c);
    c = mfma(ah, bl, c);
    c = mfma(al, bh, c);
    return c;
}
__device__ __forceinline__ bf16x8 ld8(const bf16* p) { return *(const bf16x8*)p; }

// ---- coherent store helpers (write-through to L3) ----
__device__ __forceinline__ void stc2(bf16* p, bf16 a, bf16 b) {
    unsigned v = (unsigned)*(const unsigned short*)&a |
                 ((unsigned)*(const unsigned short*)&b << 16);
    __hip_atomic_store((unsigned*)p, v, __ATOMIC_RELAXED, __HIP_MEMORY_SCOPE_AGENT);
}
__device__ __forceinline__ f32x4 ldc4f(const float* p) {
    union { f32x4 v; u64 q[2]; } u;
    u.q[0] = __hip_atomic_load((const u64*)p,     __ATOMIC_RELAXED, __HIP_MEMORY_SCOPE_AGENT);
    u.q[1] = __hip_atomic_load((const u64*)p + 1, __ATOMIC_RELAXED, __HIP_MEMORY_SCOPE_AGENT);
    return u.v;
}
__device__ __forceinline__ void stc4f(float* p, f32x4 v) {
    union { f32x4 v; u64 q[2]; } u;
    u.v = v;
    __hip_atomic_store((u64*)p,     u.q[0], __ATOMIC_RELAXED, __HIP_MEMORY_SCOPE_AGENT);
    __hip_atomic_store((u64*)p + 1, u.q[1], __ATOMIC_RELAXED, __HIP_MEMORY_SCOPE_AGENT);
}

__device__ __forceinline__ void split8(const float* p, bf16x8& h8, bf16x8& l8) {
    #pragma unroll
    for (int j = 0; j < 8; j++) {
        float v = p[j];
        bf16 h = f2b(v);
        bf16 l = f2b(v - b2f(h));
        ((bf16*)&h8)[j] = h;
        ((bf16*)&l8)[j] = l;
    }
}

// ---- distributed flag/epoch grid barrier (round-9, proven) ----
__device__ __forceinline__ void gbar2(int* __restrict__ flags, int* __restrict__ epoch,
                                      int nblk, int myid, int val, bool master) {
    __syncthreads();
    const int tid = threadIdx.x;
    if (tid < 64) {
        if (tid == 0) {
            asm volatile("s_waitcnt vmcnt(0)" ::: "memory");
            __hip_atomic_store(&flags[myid * BSTR], val, __ATOMIC_RELAXED, __HIP_MEMORY_SCOPE_AGENT);
        }
        if (master) {
            bool done = false;
            while (!done) {
                bool ok = true;
                for (int i = tid; i < nblk; i += 64)
                    ok &= (__hip_atomic_load(&flags[i * BSTR], __ATOMIC_RELAXED, __HIP_MEMORY_SCOPE_AGENT) >= val);
                done = __all(ok);
                if (!done) __builtin_amdgcn_s_sleep(1);
            }
            if (tid < NEP)
                __hip_atomic_store(&epoch[tid * BSTR], val, __ATOMIC_RELAXED, __HIP_MEMORY_SCOPE_AGENT);
        } else if (tid == 0) {
            int* ep = &epoch[(myid & (NEP - 1)) * BSTR];
            while (__hip_atomic_load(ep, __ATOMIC_RELAXED, __HIP_MEMORY_SCOPE_AGENT) < val)
                __builtin_amdgcn_s_sleep(1);
        }
        asm volatile("" ::: "memory");
    }
    __syncthreads();
}

// =====================================================================
// Split-precision MFMA GEMM (unchanged).
// =====================================================================
template<int BM, bool BIAS, bool TANH>
__global__ __launch_bounds__(256) void gemm_k(
    const float* __restrict__ A, int64_t lda, int64_t sA,
    const float* __restrict__ W, int64_t ldw, int64_t sW,
    float* __restrict__ C, int64_t ldc, int64_t sC,
    const float* __restrict__ bias, int64_t sBias,
    int K)
{
    constexpr int FM = BM / 32;
    __shared__ __align__(16) bf16 Ahi[BM * 32], Alo[BM * 32];
    __shared__ __align__(16) bf16 Whi[128 * 32], Wlo[128 * 32];
    const int z    = blockIdx.z;
    const float* Ab = A + (int64_t)z * sA;
    const float* Wb = W + (int64_t)z * sW;
    const int n0   = blockIdx.x * 128;
    const int m0   = blockIdx.y * BM;
    const int tid  = threadIdx.x;
    const int lane = tid & 63, wid = tid >> 6;
    const int wm   = wid >> 1, wn = wid & 1;
    const int srow = lane >> 2;
    const int skb  = (lane & 3) * 8;
    const int r16  = lane & 15;
    const int k8   = (lane >> 4) * 8;

    f32x4 acc[FM][4];
    #pragma unroll
    for (int i = 0; i < FM; i++)
        #pragma unroll
        for (int j = 0; j < 4; j++)
            acc[i][j] = f32x4{0.f, 0.f, 0.f, 0.f};

    for (int k0 = 0; k0 < K; k0 += 32) {
        for (int c = wid; c < BM / 16; c += 4) {
            bf16x8 h8, l8;
            split8(Ab + (int64_t)(m0 + c * 16 + srow) * lda + k0 + skb, h8, l8);
            *(bf16x8*)(Ahi + c * 512 + lane * 8) = h8;
            *(bf16x8*)(Alo + c * 512 + lane * 8) = l8;
        }
        for (int c = wid; c < 8; c += 4) {
            bf16x8 h8, l8;
            split8(Wb + (int64_t)(n0 + c * 16 + srow) * ldw + k0 + skb, h8, l8);
            *(bf16x8*)(Whi + c * 512 + lane * 8) = h8;
            *(bf16x8*)(Wlo + c * 512 + lane * 8) = l8;
        }
        __syncthreads();
        bf16x8 afh[FM], afl[FM], wfh[4], wfl[4];
        #pragma unroll
        for (int mt = 0; mt < FM; mt++) {
            const int off = (wm * (BM / 2) + mt * 16 + r16) * 32 + k8;
            afh[mt] = ld8(Ahi + off);
            afl[mt] = ld8(Alo + off);
        }
        #pragma unroll
        for (int nt = 0; nt < 4; nt++) {
            const int off = (wn * 64 + nt * 16 + r16) * 32 + k8;
            wfh[nt] = ld8(Whi + off);
            wfl[nt] = ld8(Wlo + off);
        }
        #pragma unroll
        for (int mt = 0; mt < FM; mt++)
            #pragma unroll
            for (int nt = 0; nt < 4; nt++)
                acc[mt][nt] = mfma3(afh[mt], afl[mt], wfh[nt], wfl[nt], acc[mt][nt]);
        __syncthreads();
    }
    #pragma unroll
    for (int nt = 0; nt < 4; nt++) {
        const int n = n0 + wn * 64 + nt * 16 + r16;
        float bv = 0.f;
        if constexpr (BIAS) bv = bias[(int64_t)z * sBias + n];
        #pragma unroll
        for (int mt = 0; mt < FM; mt++) {
            const int mb = m0 + wm * (BM / 2) + mt * 16 + (lane >> 4) * 4;
            #pragma unroll
            for (int r = 0; r < 4; r++) {
                float v = acc[mt][nt][r] + bv;
                if constexpr (TANH) v = tanhf(v);
                C[(int64_t)z * sC + (int64_t)(mb + r) * ldc + n] = v;
            }
        }
    }
}

__global__ void presplit_k(const float* __restrict__ x, bf16* __restrict__ hi,
                           bf16* __restrict__ lo, int n)
{
    const int i = blockIdx.x * 256 + threadIdx.x;
    if (i < n) {
        float v = x[i];
        bf16 h = f2b(v);
        hi[i] = h;
        lo[i] = f2b(v - b2f(h));
    }
}

__global__ void embed_k(const int* __restrict__ toks, const float* __restrict__ tab,
                        float* __restrict__ out, int shifted)
{
    const int row = blockIdx.x;
    int tok;
    if (shifted) {
        const int t = row / NB, b = row - t * NB;
        tok = (t == 0) ? SOST : toks[(t - 1) * NB + b];
    } else {
        tok = toks[row];
    }
    const uint4* s = (const uint4*)(tab + (int64_t)tok * HD);
    uint4* d = (uint4*)(out + (int64_t)row * HD);
    d[threadIdx.x] = s[threadIdx.x];
}

// =====================================================================
// Persistent encoder layer, W in registers, per-step h slots (cached
// reads, atomic writes). Grid (HHD/16=32, 2 dirs) x 256 thr.
// =====================================================================
__global__ __launch_bounds__(256, 1) void enc_persist_k(
    const float* __restrict__ gi,
    const bf16* __restrict__ whhHi,
    const bf16* __restrict__ whhLo,
    const float* __restrict__ bhh,
    float* __restrict__ h32,          // [2 par][2 dir][NB][HHD] (block-local)
    bf16* __restrict__ hsHi,          // [LI][2 dir][NB][HHD] per-step slots
    bf16* __restrict__ hsLo,
    float* __restrict__ Y,
    float* __restrict__ dh32, bf16* __restrict__ dhHi, bf16* __restrict__ dhLo,
    int* __restrict__ flags, int* __restrict__ epoch)
{
    __shared__ f32x4 red[4][6][64];
    const int d = blockIdx.y;
    const int j0 = blockIdx.x * 16;
    const int tid = threadIdx.x;
    const int lane = tid & 63, wid = tid >> 6;
    const int r16 = lane & 15, k8 = (lane >> 4) * 8;
    const int kq = wid * 128;
    const bf16* WdH = whhHi + (int64_t)d * 3 * HHD * HHD;
    const bf16* WdL = whhLo + (int64_t)d * 3 * HHD * HHD;
    const int j = j0 + r16;
    const int myid = d * 32 + blockIdx.x;
    const bool master = (myid == 0);

    bf16x8 wh[3][4], wl[3][4];
    #pragma unroll
    for (int g = 0; g < 3; g++)
        #pragma unroll
        for (int kk = 0; kk < 4; kk++) {
            const int64_t wo = (int64_t)(g * HHD + j0 + r16) * HHD + kq + kk * 32 + k8;
            wh[g][kk] = ld8(WdH + wo);
            wl[g][kk] = ld8(WdL + wo);
        }
    const float br = bhh[d * 3 * HHD + j];
    const float bz = bhh[d * 3 * HHD + HHD + j];
    const float bn = bhh[d * 3 * HHD + 2 * HHD + j];

    for (int s = 0; s < LI; s++) {
        const int t = d ? (LI - 1 - s) : s;
        const int par = s & 1, npar = par ^ 1;
        const bf16* rH = hsHi + (size_t)s * ESLOT + (size_t)d * NB * HHD;
        const bf16* rL = hsLo + (size_t)s * ESLOT + (size_t)d * NB * HHD;

        f32x4 acc[2][3];
        #pragma unroll
        for (int m = 0; m < 2; m++)
            #pragma unroll
            for (int g = 0; g < 3; g++) acc[m][g] = f32x4{0.f, 0.f, 0.f, 0.f};

        #pragma unroll
        for (int kk = 0; kk < 4; kk++) {
            const int o0 = r16 * HHD + kq + kk * 32 + k8;
            const int o1 = (16 + r16) * HHD + kq + kk * 32 + k8;
            bf16x8 a0h = ld8(rH + o0), a0l = ld8(rL + o0);
            bf16x8 a1h = ld8(rH + o1), a1l = ld8(rL + o1);
            #pragma unroll
            for (int g = 0; g < 3; g++) {
                acc[0][g] = mfma3(a0h, a0l, wh[g][kk], wl[g][kk], acc[0][g]);
                acc[1][g] = mfma3(a1h, a1l, wh[g][kk], wl[g][kk], acc[1][g]);
            }
        }
        #pragma unroll
        for (int m = 0; m < 2; m++)
            #pragma unroll
            for (int g = 0; g < 3; g++)
                red[wid][m * 3 + g][lane] = acc[m][g];
        __syncthreads();
        if (wid == 0) {
            f32x4 a2[2][3];
            #pragma unroll
            for (int m = 0; m < 2; m++)
                #pragma unroll
                for (int g = 0; g < 3; g++)
                    a2[m][g] = red[0][m * 3 + g][lane] + red[1][m * 3 + g][lane]
                             + red[2][m * 3 + g][lane] + red[3][m * 3 + g][lane];
            const float* gid = gi + ((int64_t)d * LI * NB + (int64_t)t * NB) * (3 * HHD);
            bf16* wH = hsHi + (size_t)(s + 1) * ESLOT + (size_t)d * NB * HHD;
            bf16* wL = hsLo + (size_t)(s + 1) * ESLOT + (size_t)d * NB * HHD;
            const int64_t hbase = (int64_t)(par * 2 + d) * NB * HHD;
            #pragma unroll
            for (int mt = 0; mt < 2; mt++)
                #pragma unroll
                for (int r = 0; r < 4; r++) {
                    const int b = mt * 16 + (lane >> 4) * 4 + r;
                    const float ir  = gid[b * 3 * HHD + j];
                    const float iz  = gid[b * 3 * HHD + HHD + j];
                    const float inn = gid[b * 3 * HHD + 2 * HHD + j];
                    const float rg = sigm(ir + a2[mt][0][r] + br);
                    const float zg = sigm(iz + a2[mt][1][r] + bz);
                    const float ng = tanhf(inn + rg * (a2[mt][2][r] + bn));
                    const float hold = h32[hbase + (int64_t)b * HHD + j];
                    const float hnew = (1.f - zg) * ng + zg * hold;
                    bf16 hh = f2b(hnew);
                    bf16 hl = f2b(hnew - b2f(hh));
                    h32[(int64_t)(npar * 2 + d) * NB * HHD + (int64_t)b * HHD + j] = hnew;
                    const int lo_ = b * HHD + j;
                    const float hn2 = __shfl_xor(hnew, 1);
                    if (s < LI - 1 && !(lane & 1)) {
                        bf16 hh2 = f2b(hn2);
                        bf16 hl2 = f2b(hn2 - b2f(hh2));
                        stc2(wH + lo_, hh, hh2);
                        stc2(wL + lo_, hl, hl2);
                    }
                    Y[((int64_t)t * NB + b) * HD + d * HHD + j] = hnew;
                    if (s == LI - 1) {
                        const int64_t dof = (int64_t)b * HD + d * HHD + j;
                        dh32[dof] = hnew;
                        dhHi[dof] = hh;
                        dhLo[dof] = hl;
                    }
                }
        }
        if (s < LI - 1) gbar2(flags, epoch, 64, myid, s + 1, master);
    }
}

// =====================================================================
// Persistent decoder (round-9 structure), per-step h slots.
// Grid (HD/16=64, 3) x 512 thr. y=0: layer0; y=1,2: layer1 K-halves.
// =====================================================================
__global__ __launch_bounds__(512, 1) void dec_persist_k(
    const float* __restrict__ gi0,
    const bf16* __restrict__ wih1Hi, const bf16* __restrict__ wih1Lo,
    const bf16* __restrict__ whh0Hi, const bf16* __restrict__ whh0Lo,
    const bf16* __restrict__ whh1Hi, const bf16* __restrict__ whh1Lo,
    const float* __restrict__ bih1,
    const float* __restrict__ bhh0,
    const float* __restrict__ bhh1,
    float* __restrict__ h32,
    bf16* __restrict__ hsHi,          // [LO+1][NLAY][NB][HD] per-step slots
    bf16* __restrict__ hsLo,
    float* __restrict__ rnn,
    f32x4* __restrict__ part,
    int* __restrict__ flags, int* __restrict__ epoch,
    int* __restrict__ flagd)
{
    __shared__ f32x4 red[8][8][64];
    const int tid = threadIdx.x;
    const int lane = tid & 63, wid = tid >> 6;
    const int r16 = lane & 15, k8 = (lane >> 4) * 8;
    const int j0 = blockIdx.x * 16;
    const int j = j0 + r16;
    const int NBLK = 64 * 3;
    const int myid = blockIdx.y * 64 + blockIdx.x;
    const bool master = (myid == 0);

    if (blockIdx.y == 0) {
        const int kq = wid * 128;
        bf16x8 wh[3][4], wl[3][4];
        #pragma unroll
        for (int g = 0; g < 3; g++)
            #pragma unroll
            for (int kk = 0; kk < 4; kk++) {
                const int64_t wo = (int64_t)(g * HD + j0 + r16) * HD + kq + kk * 32 + k8;
                wh[g][kk] = ld8(whh0Hi + wo);
                wl[g][kk] = ld8(whh0Lo + wo);
            }
        const float b0r = bhh0[j], b0z = bhh0[HD + j], b0n = bhh0[2 * HD + j];

        for (int s = 0; s <= LO; s++) {
            if (s < LO) {
                const int t = s, par = t & 1, npar = par ^ 1;
                const bf16* rH = hsHi + (size_t)s * DSLOT;
                const bf16* rL = hsLo + (size_t)s * DSLOT;
                f32x4 acc[2][3];
                #pragma unroll
                for (int m = 0; m < 2; m++)
                    #pragma unroll
                    for (int g = 0; g < 3; g++) acc[m][g] = f32x4{0.f, 0.f, 0.f, 0.f};
                #pragma unroll
                for (int kk = 0; kk < 4; kk++) {
                    const int o0 = r16 * HD + kq + kk * 32 + k8;
                    const int o1 = (16 + r16) * HD + kq + kk * 32 + k8;
                    bf16x8 a0h = ld8(rH + o0), a0l = ld8(rL + o0);
                    bf16x8 a1h = ld8(rH + o1), a1l = ld8(rL + o1);
                    #pragma unroll
                    for (int g = 0; g < 3; g++) {
                        acc[0][g] = mfma3(a0h, a0l, wh[g][kk], wl[g][kk], acc[0][g]);
                        acc[1][g] = mfma3(a1h, a1l, wh[g][kk], wl[g][kk], acc[1][g]);
                    }
                }
                #pragma unroll
                for (int m = 0; m < 2; m++)
                    #pragma unroll
                    for (int g = 0; g < 3; g++)
                        red[wid][m * 3 + g][lane] = acc[m][g];
                __syncthreads();
                if (wid == 0) {
                    f32x4 a2[2][3];
                    #pragma unroll
                    for (int m = 0; m < 2; m++)
                        #pragma unroll
                        for (int g = 0; g < 3; g++) {
                            f32x4 v = red[0][m * 3 + g][lane];
                            #pragma unroll
                            for (int w2 = 1; w2 < 8; w2++) v += red[w2][m * 3 + g][lane];
                            a2[m][g] = v;
                        }
                    const float* gid = gi0 + (int64_t)t * NB * 3 * HD;
                    bf16* wHs = hsHi + (size_t)(s + 1) * DSLOT;
                    bf16* wLs = hsLo + (size_t)(s + 1) * DSLOT;
                    const int64_t hb = (int64_t)(par * NLAY + 0) * NB * HD;
                    #pragma unroll
                    for (int mt = 0; mt < 2; mt++)
                        #pragma unroll
                        for (int r = 0; r < 4; r++) {
                            const int b = mt * 16 + (lane >> 4) * 4 + r;
                            const float ir  = gid[b * 3 * HD + j];
                            const float iz  = gid[b * 3 * HD + HD + j];
                            const float inn = gid[b * 3 * HD + 2 * HD + j];
                            const float rg = sigm(ir + a2[mt][0][r] + b0r);
                            const float zg = sigm(iz + a2[mt][1][r] + b0z);
                            const float ng = tanhf(inn + rg * (a2[mt][2][r] + b0n));
                            const float hold = h32[hb + (int64_t)b * HD + j];
                            const float hnew = (1.f - zg) * ng + zg * hold;
                            bf16 hh = f2b(hnew);
                            bf16 hl = f2b(hnew - b2f(hh));
                            h32[(int64_t)(npar * NLAY + 0) * NB * HD + (int64_t)b * HD + j] = hnew;
                            const int lo_ = b * HD + j;
                            const float hn2 = __shfl_xor(hnew, 1);
                            if (!(lane & 1)) {
                                bf16 hh2 = f2b(hn2);
                                bf16 hl2 = f2b(hn2 - b2f(hh2));
                                stc2(wHs + lo_, hh, hh2);
                                stc2(wLs + lo_, hl, hl2);
                            }
                        }
                }
            }
            if (s < LO) gbar2(flags, epoch, NBLK, myid, s + 1, master);
        }
    } else {
        const int kh = blockIdx.y - 1;
        const int kb = kh * 512 + wid * 64;
        bf16x8 wIh[3][2], wIl[3][2], wHh[3][2], wHl[3][2];
        #pragma unroll
        for (int g = 0; g < 3; g++)
            #pragma unroll
            for (int kk = 0; kk < 2; kk++) {
                const int64_t wo = (int64_t)(g * HD + j0 + r16) * HD + kb + kk * 32 + k8;
                wIh[g][kk] = ld8(wih1Hi + wo);
                wIl[g][kk] = ld8(wih1Lo + wo);
                wHh[g][kk] = ld8(whh1Hi + wo);
                wHl[g][kk] = ld8(whh1Lo + wo);
            }
        const float brr = bih1[j] + bhh1[j];
        const float bzz = bih1[HD + j] + bhh1[HD + j];
        const float bin = bih1[2 * HD + j];
        const float bhn = bhh1[2 * HD + j];

        for (int s = 0; s <= LO; s++) {
            if (s >= 1) {
                const int t = s - 1;
                const int p1 = t & 1, np1 = p1 ^ 1;
                const bf16* xH = hsHi + (size_t)s * DSLOT;                      // h0 after step t
                const bf16* xL = hsLo + (size_t)s * DSLOT;
                const bf16* yH = hsHi + (size_t)(s - 1) * DSLOT + (size_t)NB * HD;  // h1 state
                const bf16* yL = hsLo + (size_t)(s - 1) * DSLOT + (size_t)NB * HD;
                f32x4 arz[2][2], ain[2], ahn[2];
                #pragma unroll
                for (int i = 0; i < 2; i++) {
                    arz[i][0] = f32x4{0.f, 0.f, 0.f, 0.f};
                    arz[i][1] = f32x4{0.f, 0.f, 0.f, 0.f};
                    ain[i] = f32x4{0.f, 0.f, 0.f, 0.f};
                    ahn[i] = f32x4{0.f, 0.f, 0.f, 0.f};
                }
                #pragma unroll
                for (int kk = 0; kk < 2; kk++) {
                    const int o0 = r16 * HD + kb + kk * 32 + k8;
                    const int o1 = (16 + r16) * HD + kb + kk * 32 + k8;
                    bf16x8 x0h = ld8(xH + o0), x0l = ld8(xL + o0);
                    bf16x8 x1h = ld8(xH + o1), x1l = ld8(xL + o1);
                    bf16x8 y0h = ld8(yH + o0), y0l = ld8(yL + o0);
                    bf16x8 y1h = ld8(yH + o1), y1l = ld8(yL + o1);
                    arz[0][0] = mfma3(x0h, x0l, wIh[0][kk], wIl[0][kk], arz[0][0]);
                    arz[0][0] = mfma3(y0h, y0l, wHh[0][kk], wHl[0][kk], arz[0][0]);
                    arz[1][0] = mfma3(x1h, x1l, wIh[0][kk], wIl[0][kk], arz[1][0]);
                    arz[1][0] = mfma3(y1h, y1l, wHh[0][kk], wHl[0][kk], arz[1][0]);
                    arz[0][1] = mfma3(x0h, x0l, wIh[1][kk], wIl[1][kk], arz[0][1]);
                    arz[0][1] = mfma3(y0h, y0l, wHh[1][kk], wHl[1][kk], arz[0][1]);
                    arz[1][1] = mfma3(x1h, x1l, wIh[1][kk], wIl[1][kk], arz[1][1]);
                    arz[1][1] = mfma3(y1h, y1l, wHh[1][kk], wHl[1][kk], arz[1][1]);
                    ain[0] = mfma3(x0h, x0l, wIh[2][kk], wIl[2][kk], ain[0]);
                    ain[1] = mfma3(x1h, x1l, wIh[2][kk], wIl[2][kk], ain[1]);
                    ahn[0] = mfma3(y0h, y0l, wHh[2][kk], wHl[2][kk], ahn[0]);
                    ahn[1] = mfma3(y1h, y1l, wHh[2][kk], wHl[2][kk], ahn[1]);
                }
                red[wid][0][lane] = arz[0][0];
                red[wid][1][lane] = arz[1][0];
                red[wid][2][lane] = arz[0][1];
                red[wid][3][lane] = arz[1][1];
                red[wid][4][lane] = ain[0];
                red[wid][5][lane] = ain[1];
                red[wid][6][lane] = ahn[0];
                red[wid][7][lane] = ahn[1];
                __syncthreads();
                if (wid == 0) {
                    f32x4 p[8];
                    #pragma unroll
                    for (int grp = 0; grp < 8; grp++) {
                        f32x4 v = red[0][grp][lane];
                        #pragma unroll
                        for (int w2 = 1; w2 < 8; w2++) v += red[w2][grp][lane];
                        p[grp] = v;
                    }
                    if (kh == 1) {
                        #pragma unroll
                        for (int grp = 0; grp < 8; grp++)
                            stc4f((float*)&part[((size_t)blockIdx.x * 8 + grp) * 64 + lane], p[grp]);
                        asm volatile("s_waitcnt vmcnt(0)" ::: "memory");
                        if (lane == 0)
                            __hip_atomic_store(&flagd[blockIdx.x * BSTR], s, __ATOMIC_RELAXED, __HIP_MEMORY_SCOPE_AGENT);
                    } else {
                        while (__hip_atomic_load(&flagd[blockIdx.x * BSTR], __ATOMIC_RELAXED, __HIP_MEMORY_SCOPE_AGENT) < s)
                            __builtin_amdgcn_s_sleep(1);
                        asm volatile("" ::: "memory");
                        #pragma unroll
                        for (int grp = 0; grp < 8; grp++)
                            p[grp] += ldc4f((const float*)&part[((size_t)blockIdx.x * 8 + grp) * 64 + lane]);
                        bf16* wHs = hsHi + (size_t)s * DSLOT + (size_t)NB * HD;
                        bf16* wLs = hsLo + (size_t)s * DSLOT + (size_t)NB * HD;
                        const int64_t h1b = (int64_t)(p1 * NLAY + 1) * NB * HD;
                        #pragma unroll
                        for (int mt = 0; mt < 2; mt++)
                            #pragma unroll
                            for (int r = 0; r < 4; r++) {
                                const int b = mt * 16 + (lane >> 4) * 4 + r;
                                const float rg = sigm(p[0 + mt][r] + brr);
                                const float zg = sigm(p[2 + mt][r] + bzz);
                                const float ng = tanhf(p[4 + mt][r] + bin + rg * (p[6 + mt][r] + bhn));
                                const float hold = h32[h1b + (int64_t)b * HD + j];
                                const float hnew = (1.f - zg) * ng + zg * hold;
                                bf16 hh = f2b(hnew);
                                bf16 hl = f2b(hnew - b2f(hh));
                                h32[(int64_t)(np1 * NLAY + 1) * NB * HD + (int64_t)b * HD + j] = hnew;
                                const int lo_ = b * HD + j;
                                const float hn2 = __shfl_xor(hnew, 1);
                                if (!(lane & 1)) {
                                    bf16 hh2 = f2b(hn2);
                                    bf16 hl2 = f2b(hn2 - b2f(hh2));
                                    stc2(wHs + lo_, hh, hh2);
                                    stc2(wLs + lo_, hl, hl2);
                                }
                                rnn[((int64_t)t * NB + b) * HD + j] = hnew;
                            }
                    }
                }
            }
            if (s < LO) gbar2(flags, epoch, NBLK, myid, s + 1, master);
        }
    }
}

// =====================================================================
__global__ __launch_bounds__(64) void softmax_k(const float* __restrict__ sc,
                                                float* __restrict__ aout)
{
    const int row = blockIdx.x, l = threadIdx.x;
    float v0 = sc[row * LI + l], v1 = sc[row * LI + 64 + l];
    float m = fmaxf(v0, v1);
    #pragma unroll
    for (int o = 32; o > 0; o >>= 1) m = fmaxf(m, __shfl_xor(m, o));
    float e0 = expf(v0 - m), e1 = expf(v1 - m);
    float s = e0 + e1;
    #pragma unroll
    for (int o = 32; o > 0; o >>= 1) s += __shfl_xor(s, o);
    const float inv = 1.f / s;
    aout[row * LI + l] = e0 * inv;
    aout[row * LI + 64 + l] = e1 * inv;
}

__global__ __launch_bounds__(256) void ctx_k(const float* __restrict__ at,
                                             const float* __restrict__ enc,
                                             float* __restrict__ jin)
{
    const int b = blockIdx.y, h0 = blockIdx.x * 128;
    __shared__ __align__(16) float al[LO][LI];
    for (int i = threadIdx.x; i < LO * LI; i += 256) {
        const int to = i >> 7, ti = i & 127;
        al[to][ti] = at[(to * NB + b) * LI + ti];
    }
    __syncthreads();
    const int hc = h0 + (threadIdx.x & 127);
    const int rh = threadIdx.x >> 7;
    float acc[32];
    #pragma unroll
    for (int i = 0; i < 32; i++) acc[i] = 0.f;
    for (int t = 0; t < LI; t++) {
        const float ev = enc[((int64_t)t * NB + b) * HD + hc];
        #pragma unroll
        for (int i = 0; i < 32; i++) acc[i] += ev * al[rh * 32 + i][t];
    }
    #pragma unroll
    for (int i = 0; i < 32; i++)
        jin[((int64_t)(rh * 32 + i) * NB + b) * (2 * HD) + hc] = acc[i];
}

__global__ void rnncopy_k(const float* __restrict__ rnn, float* __restrict__ jin)
{
    const int idx = blockIdx.x * 256 + threadIdx.x;
    const int row = idx >> 8;
    const int c = idx & 255;
    ((uint4*)jin)[(int64_t)row * 512 + 256 + c] = ((const uint4*)rnn)[idx];
}

// =====================================================================
extern "C" void kernel_launch(void* const* d_in, const int* in_sizes, int n_in,
                              void* d_out, int out_size, void* d_ws, size_t ws_size,
                              hipStream_t stream)
{
    (void)in_sizes; (void)n_in; (void)out_size; (void)ws_size;
    const int*   in_tok   = (const int*)d_in[0];
    const int*   out_tok  = (const int*)d_in[2];
    const float* enc_emb  = (const float*)d_in[4];
    const float* enc_wih  = (const float*)d_in[5];
    const float* enc_whh  = (const float*)d_in[6];
    const float* enc_bih  = (const float*)d_in[7];
    const float* enc_bhh  = (const float*)d_in[8];
    const float* dec_emb  = (const float*)d_in[9];
    const float* dec_wih  = (const float*)d_in[10];
    const float* dec_whh  = (const float*)d_in[11];
    const float* dec_bih  = (const float*)d_in[12];
    const float* dec_bhh  = (const float*)d_in[13];
    const float* attn_W   = (const float*)d_in[14];
    const float* joiner_W = (const float*)d_in[15];
    const float* joiner_b = (const float*)d_in[16];
    const float* proj_W   = (const float*)d_in[17];
    const float* proj_b   = (const float*)d_in[18];
    float* logits   = (float*)d_out;
    float* attn_out = logits + (size_t)LO * NB * NV;

    const size_t MB = 1ull << 20;
    char* o = (char*)d_out;   // logits region = 250 MiB fp32
    float* XB0   = (float*)(o);              // 16 MiB (dead after L0 gi GEMM -> DECH_HI)
    float* XB1   = (float*)(o + 16 * MB);    // 16 MiB enc layer0 output
    float* EOUT  = (float*)(o + 32 * MB);    // 16 MiB enc_outputs
    float* PENC  = (float*)(o + 48 * MB);    // 16 MiB proj_enc
    float* GI    = (float*)(o + 64 * MB);    // 48 MiB enc gi
    float* DEMB  = (float*)(o + 112 * MB);   //  8 MiB dec embedded
    float* DGI0  = (float*)(o + 120 * MB);   // 24 MiB dec layer0 gi
    float* RNN   = (float*)(o + 144 * MB);   //  8 MiB rnn_out
    float* SC    = (float*)(o + 152 * MB);   //  1 MiB scores
    float* JIN   = (float*)(o + 153 * MB);   // 16 MiB (dead during dec -> DECH_LO)
    bf16* WencHi = (bf16*)(o + 169 * MB);
    bf16* WencLo = (bf16*)(o + 175 * MB);
    bf16* WdhHi  = (bf16*)(o + 181 * MB);
    bf16* WdhLo  = (bf16*)(o + 193 * MB);
    bf16* Wih1Hi = (bf16*)(o + 205 * MB);
    bf16* Wih1Lo = (bf16*)(o + 211 * MB);
    f32x4* PART  = (f32x4*)(o + 218 * MB);   // 512 KiB
    char* ba = o + 220 * MB;                 // barrier arena, 4 MiB
    const size_t KB = 1024;
    int* FL_E  = (int*)(ba);                 // 64 x 8KB
    int* EP_E  = (int*)(ba + 512 * KB);      // 16 x 8KB
    int* FL_D  = (int*)(ba + 640 * KB);      // 192 x 8KB
    int* EP_D  = (int*)(ba + 2176 * KB);     // 16 x 8KB
    int* FLAGD = (int*)(ba + 2304 * KB);     // 64 x 8KB
    bf16* ENCH_HI = (bf16*)(o + 226 * MB);   // 128 slots x 64KB = 8 MiB
    bf16* ENCH_LO = (bf16*)(o + 235 * MB);   // 8 MiB (ends 243 < 250)
    bf16* DECH_HI = (bf16*)XB0;              // 65 slots x 128KB
    bf16* DECH_LO = (bf16*)JIN;

    char* w = (char*)d_ws;
    float* VECS = (float*)(w);                       // 8 MiB
    float* EH32 = (float*)(w + 8 * MB);              // 512 KiB
    float* DH32 = (float*)(w + 8 * MB + 524288);     // 512 KiB

    hipMemsetAsync(ba, 0, 4 * MB, stream);
    hipMemsetAsync(ENCH_HI, 0, (size_t)ESLOT * 2, stream);   // enc slot 0 = zeros
    hipMemsetAsync(ENCH_LO, 0, (size_t)ESLOT * 2, stream);

    const int nEnc = NLAY * 2 * 3 * HHD * HHD;
    const int nDhh = NLAY * 3 * HD * HD;
    const int nIh1 = 3 * HD * HD;
    presplit_k<<<dim3((nEnc + 255) / 256), dim3(256), 0, stream>>>(enc_whh, WencHi, WencLo, nEnc);
    presplit_k<<<dim3((nDhh + 255) / 256), dim3(256), 0, stream>>>(dec_whh, WdhHi, WdhLo, nDhh);
    presplit_k<<<dim3((nIh1 + 255) / 256), dim3(256), 0, stream>>>(dec_wih + (size_t)3 * HD * HD, Wih1Hi, Wih1Lo, nIh1);

    embed_k<<<dim3(LO * NB), dim3(256), 0, stream>>>(out_tok, dec_emb, DEMB, 1);
    gemm_k<128, true, false><<<dim3(3 * HD / 128, LO * NB / 128, 1), 256, 0, stream>>>(
        DEMB, HD, 0, dec_wih, HD, 0, DGI0, 3 * HD, 0, dec_bih, 0, HD);

    embed_k<<<dim3(LI * NB), dim3(256), 0, stream>>>(in_tok, enc_emb, XB0, 0);
    for (int l = 0; l < NLAY; l++) {
        const float* Xin = l ? XB1 : XB0;
        float* Yout = l ? EOUT : XB1;
        hipMemsetAsync(EH32, 0, (size_t)2 * 2 * NB * HHD * 4, stream);
        gemm_k<128, true, false><<<dim3(3 * HHD / 128, LI * NB / 128, 2), 256, 0, stream>>>(
            Xin, HD, 0,
            enc_wih + (size_t)l * 2 * 3 * HHD * HD, HD, (int64_t)3 * HHD * HD,
            GI, 3 * HHD, (int64_t)LI * NB * 3 * HHD,
            enc_bih + l * 2 * 3 * HHD, 3 * HHD, HD);
        enc_persist_k<<<dim3(HHD / 16, 2), dim3(256), 0, stream>>>(
            GI,
            WencHi + (size_t)l * 2 * 3 * HHD * HHD,
            WencLo + (size_t)l * 2 * 3 * HHD * HHD,
            enc_bhh + l * 2 * 3 * HHD,
            EH32, ENCH_HI, ENCH_LO, Yout,
            DH32 + (size_t)l * NB * HD,
            DECH_HI + (size_t)l * NB * HD,
            DECH_LO + (size_t)l * NB * HD,
            FL_E, EP_E);
    }

    gemm_k<128, false, false><<<dim3(HD / 128, LI * NB / 128, 1), 256, 0, stream>>>(
        EOUT, HD, 0, attn_W, HD, 0, PENC, HD, 0, nullptr, 0, HD);

    dec_persist_k<<<dim3(HD / 16, 3), dim3(512), 0, stream>>>(
        DGI0,
        Wih1Hi, Wih1Lo,
        WdhHi, WdhLo,
        WdhHi + (size_t)3 * HD * HD, WdhLo + (size_t)3 * HD * HD,
        dec_bih + 3 * HD, dec_bhh, dec_bhh + 3 * HD,
        DH32, DECH_HI, DECH_LO, RNN, PART, FL_D, EP_D, FLAGD);

    gemm_k<64, false, false><<<dim3(1, 1, NB), 256, 0, stream>>>(
        RNN, (int64_t)NB * HD, HD, PENC, (int64_t)NB * HD, HD,
        SC, (int64_t)NB * LI, LI, nullptr, 0, HD);
    softmax_k<<<dim3(LO * NB), dim3(64), 0, stream>>>(SC, attn_out);
    ctx_k<<<dim3(HD / 128, NB), dim3(256), 0, stream>>>(attn_out, EOUT, JIN);
    rnncopy_k<<<dim3(LO * NB * HD / 4 / 256), dim3(256), 0, stream>>>(RNN, JIN);
    gemm_k<128, true, true><<<dim3(HD / 128, LO * NB / 128, 1), 256, 0, stream>>>(
        JIN, 2 * HD, 0, joiner_W, 2 * HD, 0, VECS, HD, 0, joiner_b, 0, 2 * HD);
    gemm_k<128, true, false><<<dim3(NV / 128, LO * NB / 128, 1), 256, 0, stream>>>(
        VECS, HD, 0, proj_W, HD, 0, logits, NV, 0, proj_b, 0, HD);
}

// Round 12
// 4862.384 us; speedup vs baseline: 1.2570x; 1.0526x over previous
//
#include <hip/hip_runtime.h>
#include <hip/hip_bf16.h>
#include <stdint.h>

// ---- problem constants ----
constexpr int LI   = 128;    // L_IN
constexpr int LO   = 64;     // L_OUT
constexpr int NB   = 32;     // batch
constexpr int HD   = 1024;   // H
constexpr int HHD  = 512;    // HH
constexpr int NLAY = 2;
constexpr int NV   = 32000;  // V_OUT
constexpr int SOST = 1;

// Round-12: GEMM data-path overhaul. All GEMMs: A = pre-split hi/lo bf16
// (global_load_lds staged), W = fp32 rounded to bf16 in-register, 2 MFMA
// per fragment. Recurrence kernels (round-11, passing) unchanged except
// Y/RNN outputs now written as hi/lo bf16 pairs (values already computed).

typedef __hip_bfloat16 bf16;
typedef __attribute__((ext_vector_type(8))) short bf16x8;
typedef __attribute__((ext_vector_type(4))) float f32x4;
typedef unsigned long long u64;

constexpr int BSTR = 2048;   // barrier flag stride in ints = 8 KB
constexpr int NEP  = 16;     // epoch replicas
constexpr int ESLOT = 2 * NB * HHD;     // enc per-step slot (elems)
constexpr int DSLOT = NLAY * NB * HD;   // dec per-step slot (elems)

__device__ __forceinline__ float b2f(bf16 x) { return __bfloat162float(x); }
__device__ __forceinline__ bf16  f2b(float x) { return __float2bfloat16(x); }
__device__ __forceinline__ float sigm(float x) { return 1.0f / (1.0f + expf(-x)); }

__device__ __forceinline__ f32x4 mfma(bf16x8 a, bf16x8 b, f32x4 c) {
    return __builtin_amdgcn_mfma_f32_16x16x32_bf16(a, b, c, 0, 0, 0);
}
__device__ __forceinline__ f32x4 mfma3(bf16x8 ah, bf16x8 al, bf16x8 bh, bf16x8 bl, f32x4 c) {
    c = mfma(ah, bh, c);
    c = mfma(ah, bl, c);
    c = mfma(al, bh, c);
    return c;
}
__device__ __forceinline__ bf16x8 ld8(const bf16* p) { return *(const bf16x8*)p; }

// async global->LDS, 16B per lane; LDS base wave-uniform
__device__ __forceinline__ void g2l16(const void* g, void* l) {
    __builtin_amdgcn_global_load_lds(
        (const __attribute__((address_space(1))) unsigned int*)g,
        (__attribute__((address_space(3))) unsigned int*)l,
        16, 0, 0);
}

// ---- coherent (agent/L3) helpers (recurrence exchange, unchanged) ----
__device__ __forceinline__ void stc2(bf16* p, bf16 a, bf16 b) {
    unsigned v = (unsigned)*(const unsigned short*)&a |
                 ((unsigned)*(const unsigned short*)&b << 16);
    __hip_atomic_store((unsigned*)p, v, __ATOMIC_RELAXED, __HIP_MEMORY_SCOPE_AGENT);
}
__device__ __forceinline__ f32x4 ldc4f(const float* p) {
    union { f32x4 v; u64 q[2]; } u;
    u.q[0] = __hip_atomic_load((const u64*)p,     __ATOMIC_RELAXED, __HIP_MEMORY_SCOPE_AGENT);
    u.q[1] = __hip_atomic_load((const u64*)p + 1, __ATOMIC_RELAXED, __HIP_MEMORY_SCOPE_AGENT);
    return u.v;
}
__device__ __forceinline__ void stc4f(float* p, f32x4 v) {
    union { f32x4 v; u64 q[2]; } u;
    u.v = v;
    __hip_atomic_store((u64*)p,     u.q[0], __ATOMIC_RELAXED, __HIP_MEMORY_SCOPE_AGENT);
    __hip_atomic_store((u64*)p + 1, u.q[1], __ATOMIC_RELAXED, __HIP_MEMORY_SCOPE_AGENT);
}

// ---- distributed flag/epoch grid barrier (round-9, proven) ----
__device__ __forceinline__ void gbar2(int* __restrict__ flags, int* __restrict__ epoch,
                                      int nblk, int myid, int val, bool master) {
    __syncthreads();
    const int tid = threadIdx.x;
    if (tid < 64) {
        if (tid == 0) {
            asm volatile("s_waitcnt vmcnt(0)" ::: "memory");
            __hip_atomic_store(&flags[myid * BSTR], val, __ATOMIC_RELAXED, __HIP_MEMORY_SCOPE_AGENT);
        }
        if (master) {
            bool done = false;
            while (!done) {
                bool ok = true;
                for (int i = tid; i < nblk; i += 64)
                    ok &= (__hip_atomic_load(&flags[i * BSTR], __ATOMIC_RELAXED, __HIP_MEMORY_SCOPE_AGENT) >= val);
                done = __all(ok);
                if (!done) __builtin_amdgcn_s_sleep(1);
            }
            if (tid < NEP)
                __hip_atomic_store(&epoch[tid * BSTR], val, __ATOMIC_RELAXED, __HIP_MEMORY_SCOPE_AGENT);
        } else if (tid == 0) {
            int* ep = &epoch[(myid & (NEP - 1)) * BSTR];
            while (__hip_atomic_load(ep, __ATOMIC_RELAXED, __HIP_MEMORY_SCOPE_AGENT) < val)
                __builtin_amdgcn_s_sleep(1);
        }
        asm volatile("" ::: "memory");
    }
    __syncthreads();
}

// =====================================================================
// GEMM: C[m,n] = sum_k A[m,k]*W[n,k] (+bias)(opt tanh).
// A = hi/lo bf16 pair (g2l16-staged); W = fp32 -> bf16 (in-register).
// 2 MFMA per fragment. OM: 0 -> fp32 C; 1 -> bf16 hi/lo pair C.
// =====================================================================
template<int BM, bool BIAS, bool TANH, int OM>
__global__ __launch_bounds__(256) void gemmWf_k(
    const bf16* __restrict__ Ahi, const bf16* __restrict__ Alo,
    int64_t lda, int64_t sA,
    const float* __restrict__ W, int64_t ldw, int64_t sW,
    float* __restrict__ C, bf16* __restrict__ Chi, bf16* __restrict__ Clo,
    int64_t ldc, int64_t sC,
    const float* __restrict__ bias, int64_t sBias,
    int K)
{
    constexpr int FM = BM / 32;
    __shared__ __align__(16) bf16 Ah[BM * 32], Al[BM * 32];
    __shared__ __align__(16) bf16 Wl[128 * 32];
    const int z    = blockIdx.z;
    const bf16* Abh = Ahi + (int64_t)z * sA;
    const bf16* Abl = Alo + (int64_t)z * sA;
    const float* Wb = W + (int64_t)z * sW;
    const int n0   = blockIdx.x * 128;
    const int m0   = blockIdx.y * BM;
    const int tid  = threadIdx.x;
    const int lane = tid & 63, wid = tid >> 6;
    const int wm   = wid >> 1, wn = wid & 1;
    const int srow = lane >> 2;              // row within 16-row chunk
    const int skb  = (lane & 3) * 8;         // k element offset (8 elems = 16B bf16)
    const int r16  = lane & 15;
    const int k8   = (lane >> 4) * 8;

    f32x4 acc[FM][4];
    #pragma unroll
    for (int i = 0; i < FM; i++)
        #pragma unroll
        for (int j = 0; j < 4; j++)
            acc[i][j] = f32x4{0.f, 0.f, 0.f, 0.f};

    for (int k0 = 0; k0 < K; k0 += 32) {
        for (int c = wid; c < BM / 16; c += 4) {
            g2l16(Abh + (int64_t)(m0 + c * 16 + srow) * lda + k0 + skb, Ah + c * 512);
            g2l16(Abl + (int64_t)(m0 + c * 16 + srow) * lda + k0 + skb, Al + c * 512);
        }
        for (int c = wid; c < 8; c += 4) {
            const float* wp = Wb + (int64_t)(n0 + c * 16 + srow) * ldw + k0 + skb;
            bf16x8 wv;
            #pragma unroll
            for (int jj = 0; jj < 8; jj++) ((bf16*)&wv)[jj] = f2b(wp[jj]);
            *(bf16x8*)(Wl + c * 512 + lane * 8) = wv;
        }
        __syncthreads();
        bf16x8 afh[FM], afl[FM], wf[4];
        #pragma unroll
        for (int mt = 0; mt < FM; mt++) {
            const int off = (wm * (BM / 2) + mt * 16 + r16) * 32 + k8;
            afh[mt] = ld8(Ah + off);
            afl[mt] = ld8(Al + off);
        }
        #pragma unroll
        for (int nt = 0; nt < 4; nt++)
            wf[nt] = ld8(Wl + (wn * 64 + nt * 16 + r16) * 32 + k8);
        #pragma unroll
        for (int mt = 0; mt < FM; mt++)
            #pragma unroll
            for (int nt = 0; nt < 4; nt++) {
                acc[mt][nt] = mfma(afh[mt], wf[nt], acc[mt][nt]);
                acc[mt][nt] = mfma(afl[mt], wf[nt], acc[mt][nt]);
            }
        __syncthreads();
    }
    #pragma unroll
    for (int nt = 0; nt < 4; nt++) {
        const int n = n0 + wn * 64 + nt * 16 + r16;
        float bv = 0.f;
        if constexpr (BIAS) bv = bias[(int64_t)z * sBias + n];
        #pragma unroll
        for (int mt = 0; mt < FM; mt++) {
            const int mb = m0 + wm * (BM / 2) + mt * 16 + (lane >> 4) * 4;
            #pragma unroll
            for (int r = 0; r < 4; r++) {
                float v = acc[mt][nt][r] + bv;
                if constexpr (TANH) v = tanhf(v);
                const int64_t co = (int64_t)z * sC + (int64_t)(mb + r) * ldc + n;
                if constexpr (OM == 0) {
                    C[co] = v;
                } else {
                    bf16 hh = f2b(v);
                    Chi[co] = hh;
                    Clo[co] = f2b(v - b2f(hh));
                }
            }
        }
    }
}

__global__ void presplit_k(const float* __restrict__ x, bf16* __restrict__ hi,
                           bf16* __restrict__ lo, int n)
{
    const int i = blockIdx.x * 256 + threadIdx.x;
    if (i < n) {
        float v = x[i];
        bf16 h = f2b(v);
        hi[i] = h;
        lo[i] = f2b(v - b2f(h));
    }
}

// embed writing hi/lo pair
__global__ void embed2_k(const int* __restrict__ toks, const float* __restrict__ tab,
                         bf16* __restrict__ ohi, bf16* __restrict__ olo, int shifted)
{
    const int row = blockIdx.x;
    int tok;
    if (shifted) {
        const int t = row / NB, b = row - t * NB;
        tok = (t == 0) ? SOST : toks[(t - 1) * NB + b];
    } else {
        tok = toks[row];
    }
    const float4 v = ((const float4*)(tab + (int64_t)tok * HD))[threadIdx.x];
    bf16 h0 = f2b(v.x), h1 = f2b(v.y), h2 = f2b(v.z), h3 = f2b(v.w);
    bf16 hv[4] = {h0, h1, h2, h3};
    bf16 lv[4] = {f2b(v.x - b2f(h0)), f2b(v.y - b2f(h1)),
                  f2b(v.z - b2f(h2)), f2b(v.w - b2f(h3))};
    *(uint2*)(ohi + (int64_t)row * HD + threadIdx.x * 4) = *(uint2*)hv;
    *(uint2*)(olo + (int64_t)row * HD + threadIdx.x * 4) = *(uint2*)lv;
}

// =====================================================================
// Persistent encoder layer (round-11 structure), Y emitted as hi/lo.
// =====================================================================
__global__ __launch_bounds__(256, 1) void enc_persist_k(
    const float* __restrict__ gi,
    const bf16* __restrict__ whhHi,
    const bf16* __restrict__ whhLo,
    const float* __restrict__ bhh,
    float* __restrict__ h32,
    bf16* __restrict__ hsHi, bf16* __restrict__ hsLo,
    bf16* __restrict__ yHi, bf16* __restrict__ yLo,
    float* __restrict__ dh32, bf16* __restrict__ dhHi, bf16* __restrict__ dhLo,
    int* __restrict__ flags, int* __restrict__ epoch)
{
    __shared__ f32x4 red[4][6][64];
    const int d = blockIdx.y;
    const int j0 = blockIdx.x * 16;
    const int tid = threadIdx.x;
    const int lane = tid & 63, wid = tid >> 6;
    const int r16 = lane & 15, k8 = (lane >> 4) * 8;
    const int kq = wid * 128;
    const bf16* WdH = whhHi + (int64_t)d * 3 * HHD * HHD;
    const bf16* WdL = whhLo + (int64_t)d * 3 * HHD * HHD;
    const int j = j0 + r16;
    const int myid = d * 32 + blockIdx.x;
    const bool master = (myid == 0);

    bf16x8 wh[3][4], wl[3][4];
    #pragma unroll
    for (int g = 0; g < 3; g++)
        #pragma unroll
        for (int kk = 0; kk < 4; kk++) {
            const int64_t wo = (int64_t)(g * HHD + j0 + r16) * HHD + kq + kk * 32 + k8;
            wh[g][kk] = ld8(WdH + wo);
            wl[g][kk] = ld8(WdL + wo);
        }
    const float br = bhh[d * 3 * HHD + j];
    const float bz = bhh[d * 3 * HHD + HHD + j];
    const float bn = bhh[d * 3 * HHD + 2 * HHD + j];

    for (int s = 0; s < LI; s++) {
        const int t = d ? (LI - 1 - s) : s;
        const int par = s & 1, npar = par ^ 1;
        const bf16* rH = hsHi + (size_t)s * ESLOT + (size_t)d * NB * HHD;
        const bf16* rL = hsLo + (size_t)s * ESLOT + (size_t)d * NB * HHD;

        f32x4 acc[2][3];
        #pragma unroll
        for (int m = 0; m < 2; m++)
            #pragma unroll
            for (int g = 0; g < 3; g++) acc[m][g] = f32x4{0.f, 0.f, 0.f, 0.f};

        #pragma unroll
        for (int kk = 0; kk < 4; kk++) {
            const int o0 = r16 * HHD + kq + kk * 32 + k8;
            const int o1 = (16 + r16) * HHD + kq + kk * 32 + k8;
            bf16x8 a0h = ld8(rH + o0), a0l = ld8(rL + o0);
            bf16x8 a1h = ld8(rH + o1), a1l = ld8(rL + o1);
            #pragma unroll
            for (int g = 0; g < 3; g++) {
                acc[0][g] = mfma3(a0h, a0l, wh[g][kk], wl[g][kk], acc[0][g]);
                acc[1][g] = mfma3(a1h, a1l, wh[g][kk], wl[g][kk], acc[1][g]);
            }
        }
        #pragma unroll
        for (int m = 0; m < 2; m++)
            #pragma unroll
            for (int g = 0; g < 3; g++)
                red[wid][m * 3 + g][lane] = acc[m][g];
        __syncthreads();
        if (wid == 0) {
            f32x4 a2[2][3];
            #pragma unroll
            for (int m = 0; m < 2; m++)
                #pragma unroll
                for (int g = 0; g < 3; g++)
                    a2[m][g] = red[0][m * 3 + g][lane] + red[1][m * 3 + g][lane]
                             + red[2][m * 3 + g][lane] + red[3][m * 3 + g][lane];
            const float* gid = gi + ((int64_t)d * LI * NB + (int64_t)t * NB) * (3 * HHD);
            bf16* wH = hsHi + (size_t)(s + 1) * ESLOT + (size_t)d * NB * HHD;
            bf16* wL = hsLo + (size_t)(s + 1) * ESLOT + (size_t)d * NB * HHD;
            const int64_t hbase = (int64_t)(par * 2 + d) * NB * HHD;
            #pragma unroll
            for (int mt = 0; mt < 2; mt++)
                #pragma unroll
                for (int r = 0; r < 4; r++) {
                    const int b = mt * 16 + (lane >> 4) * 4 + r;
                    const float ir  = gid[b * 3 * HHD + j];
                    const float iz  = gid[b * 3 * HHD + HHD + j];
                    const float inn = gid[b * 3 * HHD + 2 * HHD + j];
                    const float rg = sigm(ir + a2[mt][0][r] + br);
                    const float zg = sigm(iz + a2[mt][1][r] + bz);
                    const float ng = tanhf(inn + rg * (a2[mt][2][r] + bn));
                    const float hold = h32[hbase + (int64_t)b * HHD + j];
                    const float hnew = (1.f - zg) * ng + zg * hold;
                    bf16 hh = f2b(hnew);
                    bf16 hl = f2b(hnew - b2f(hh));
                    h32[(int64_t)(npar * 2 + d) * NB * HHD + (int64_t)b * HHD + j] = hnew;
                    const int lo_ = b * HHD + j;
                    const float hn2 = __shfl_xor(hnew, 1);
                    if (s < LI - 1 && !(lane & 1)) {
                        bf16 hh2 = f2b(hn2);
                        bf16 hl2 = f2b(hn2 - b2f(hh2));
                        stc2(wH + lo_, hh, hh2);
                        stc2(wL + lo_, hl, hl2);
                    }
                    const int64_t yo = ((int64_t)t * NB + b) * HD + d * HHD + j;
                    yHi[yo] = hh;
                    yLo[yo] = hl;
                    if (s == LI - 1) {
                        const int64_t dof = (int64_t)b * HD + d * HHD + j;
                        dh32[dof] = hnew;
                        dhHi[dof] = hh;
                        dhLo[dof] = hl;
                    }
                }
        }
        if (s < LI - 1) gbar2(flags, epoch, 64, myid, s + 1, master);
    }
}

// =====================================================================
// Persistent decoder (round-11 structure), rnn emitted as hi/lo.
// =====================================================================
__global__ __launch_bounds__(512, 1) void dec_persist_k(
    const float* __restrict__ gi0,
    const bf16* __restrict__ wih1Hi, const bf16* __restrict__ wih1Lo,
    const bf16* __restrict__ whh0Hi, const bf16* __restrict__ whh0Lo,
    const bf16* __restrict__ whh1Hi, const bf16* __restrict__ whh1Lo,
    const float* __restrict__ bih1,
    const float* __restrict__ bhh0,
    const float* __restrict__ bhh1,
    float* __restrict__ h32,
    bf16* __restrict__ hsHi, bf16* __restrict__ hsLo,
    bf16* __restrict__ rnnHi, bf16* __restrict__ rnnLo,
    f32x4* __restrict__ part,
    int* __restrict__ flags, int* __restrict__ epoch,
    int* __restrict__ flagd)
{
    __shared__ f32x4 red[8][8][64];
    const int tid = threadIdx.x;
    const int lane = tid & 63, wid = tid >> 6;
    const int r16 = lane & 15, k8 = (lane >> 4) * 8;
    const int j0 = blockIdx.x * 16;
    const int j = j0 + r16;
    const int NBLK = 64 * 3;
    const int myid = blockIdx.y * 64 + blockIdx.x;
    const bool master = (myid == 0);

    if (blockIdx.y == 0) {
        const int kq = wid * 128;
        bf16x8 wh[3][4], wl[3][4];
        #pragma unroll
        for (int g = 0; g < 3; g++)
            #pragma unroll
            for (int kk = 0; kk < 4; kk++) {
                const int64_t wo = (int64_t)(g * HD + j0 + r16) * HD + kq + kk * 32 + k8;
                wh[g][kk] = ld8(whh0Hi + wo);
                wl[g][kk] = ld8(whh0Lo + wo);
            }
        const float b0r = bhh0[j], b0z = bhh0[HD + j], b0n = bhh0[2 * HD + j];

        for (int s = 0; s <= LO; s++) {
            if (s < LO) {
                const int t = s, par = t & 1, npar = par ^ 1;
                const bf16* rH = hsHi + (size_t)s * DSLOT;
                const bf16* rL = hsLo + (size_t)s * DSLOT;
                f32x4 acc[2][3];
                #pragma unroll
                for (int m = 0; m < 2; m++)
                    #pragma unroll
                    for (int g = 0; g < 3; g++) acc[m][g] = f32x4{0.f, 0.f, 0.f, 0.f};
                #pragma unroll
                for (int kk = 0; kk < 4; kk++) {
                    const int o0 = r16 * HD + kq + kk * 32 + k8;
                    const int o1 = (16 + r16) * HD + kq + kk * 32 + k8;
                    bf16x8 a0h = ld8(rH + o0), a0l = ld8(rL + o0);
                    bf16x8 a1h = ld8(rH + o1), a1l = ld8(rL + o1);
                    #pragma unroll
                    for (int g = 0; g < 3; g++) {
                        acc[0][g] = mfma3(a0h, a0l, wh[g][kk], wl[g][kk], acc[0][g]);
                        acc[1][g] = mfma3(a1h, a1l, wh[g][kk], wl[g][kk], acc[1][g]);
                    }
                }
                #pragma unroll
                for (int m = 0; m < 2; m++)
                    #pragma unroll
                    for (int g = 0; g < 3; g++)
                        red[wid][m * 3 + g][lane] = acc[m][g];
                __syncthreads();
                if (wid == 0) {
                    f32x4 a2[2][3];
                    #pragma unroll
                    for (int m = 0; m < 2; m++)
                        #pragma unroll
                        for (int g = 0; g < 3; g++) {
                            f32x4 v = red[0][m * 3 + g][lane];
                            #pragma unroll
                            for (int w2 = 1; w2 < 8; w2++) v += red[w2][m * 3 + g][lane];
                            a2[m][g] = v;
                        }
                    const float* gid = gi0 + (int64_t)t * NB * 3 * HD;
                    bf16* wHs = hsHi + (size_t)(s + 1) * DSLOT;
                    bf16* wLs = hsLo + (size_t)(s + 1) * DSLOT;
                    const int64_t hb = (int64_t)(par * NLAY + 0) * NB * HD;
                    #pragma unroll
                    for (int mt = 0; mt < 2; mt++)
                        #pragma unroll
                        for (int r = 0; r < 4; r++) {
                            const int b = mt * 16 + (lane >> 4) * 4 + r;
                            const float ir  = gid[b * 3 * HD + j];
                            const float iz  = gid[b * 3 * HD + HD + j];
                            const float inn = gid[b * 3 * HD + 2 * HD + j];
                            const float rg = sigm(ir + a2[mt][0][r] + b0r);
                            const float zg = sigm(iz + a2[mt][1][r] + b0z);
                            const float ng = tanhf(inn + rg * (a2[mt][2][r] + b0n));
                            const float hold = h32[hb + (int64_t)b * HD + j];
                            const float hnew = (1.f - zg) * ng + zg * hold;
                            bf16 hh = f2b(hnew);
                            bf16 hl = f2b(hnew - b2f(hh));
                            h32[(int64_t)(npar * NLAY + 0) * NB * HD + (int64_t)b * HD + j] = hnew;
                            const int lo_ = b * HD + j;
                            const float hn2 = __shfl_xor(hnew, 1);
                            if (!(lane & 1)) {
                                bf16 hh2 = f2b(hn2);
                                bf16 hl2 = f2b(hn2 - b2f(hh2));
                                stc2(wHs + lo_, hh, hh2);
                                stc2(wLs + lo_, hl, hl2);
                            }
                        }
                }
            }
            if (s < LO) gbar2(flags, epoch, NBLK, myid, s + 1, master);
        }
    } else {
        const int kh = blockIdx.y - 1;
        const int kb = kh * 512 + wid * 64;
        bf16x8 wIh[3][2], wIl[3][2], wHh[3][2], wHl[3][2];
        #pragma unroll
        for (int g = 0; g < 3; g++)
            #pragma unroll
            for (int kk = 0; kk < 2; kk++) {
                const int64_t wo = (int64_t)(g * HD + j0 + r16) * HD + kb + kk * 32 + k8;
                wIh[g][kk] = ld8(wih1Hi + wo);
                wIl[g][kk] = ld8(wih1Lo + wo);
                wHh[g][kk] = ld8(whh1Hi + wo);
                wHl[g][kk] = ld8(whh1Lo + wo);
            }
        const float brr = bih1[j] + bhh1[j];
        const float bzz = bih1[HD + j] + bhh1[HD + j];
        const float bin = bih1[2 * HD + j];
        const float bhn = bhh1[2 * HD + j];

        for (int s = 0; s <= LO; s++) {
            if (s >= 1) {
                const int t = s - 1;
                const int p1 = t & 1, np1 = p1 ^ 1;
                const bf16* xH = hsHi + (size_t)s * DSLOT;
                const bf16* xL = hsLo + (size_t)s * DSLOT;
                const bf16* yH = hsHi + (size_t)(s - 1) * DSLOT + (size_t)NB * HD;
                const bf16* yL = hsLo + (size_t)(s - 1) * DSLOT + (size_t)NB * HD;
                f32x4 arz[2][2], ain[2], ahn[2];
                #pragma unroll
                for (int i = 0; i < 2; i++) {
                    arz[i][0] = f32x4{0.f, 0.f, 0.f, 0.f};
                    arz[i][1] = f32x4{0.f, 0.f, 0.f, 0.f};
                    ain[i] = f32x4{0.f, 0.f, 0.f, 0.f};
                    ahn[i] = f32x4{0.f, 0.f, 0.f, 0.f};
                }
                #pragma unroll
                for (int kk = 0; kk < 2; kk++) {
                    const int o0 = r16 * HD + kb + kk * 32 + k8;
                    const int o1 = (16 + r16) * HD + kb + kk * 32 + k8;
                    bf16x8 x0h = ld8(xH + o0), x0l = ld8(xL + o0);
                    bf16x8 x1h = ld8(xH + o1), x1l = ld8(xL + o1);
                    bf16x8 y0h = ld8(yH + o0), y0l = ld8(yL + o0);
                    bf16x8 y1h = ld8(yH + o1), y1l = ld8(yL + o1);
                    arz[0][0] = mfma3(x0h, x0l, wIh[0][kk], wIl[0][kk], arz[0][0]);
                    arz[0][0] = mfma3(y0h, y0l, wHh[0][kk], wHl[0][kk], arz[0][0]);
                    arz[1][0] = mfma3(x1h, x1l, wIh[0][kk], wIl[0][kk], arz[1][0]);
                    arz[1][0] = mfma3(y1h, y1l, wHh[0][kk], wHl[0][kk], arz[1][0]);
                    arz[0][1] = mfma3(x0h, x0l, wIh[1][kk], wIl[1][kk], arz[0][1]);
                    arz[0][1] = mfma3(y0h, y0l, wHh[1][kk], wHl[1][kk], arz[0][1]);
                    arz[1][1] = mfma3(x1h, x1l, wIh[1][kk], wIl[1][kk], arz[1][1]);
                    arz[1][1] = mfma3(y1h, y1l, wHh[1][kk], wHl[1][kk], arz[1][1]);
                    ain[0] = mfma3(x0h, x0l, wIh[2][kk], wIl[2][kk], ain[0]);
                    ain[1] = mfma3(x1h, x1l, wIh[2][kk], wIl[2][kk], ain[1]);
                    ahn[0] = mfma3(y0h, y0l, wHh[2][kk], wHl[2][kk], ahn[0]);
                    ahn[1] = mfma3(y1h, y1l, wHh[2][kk], wHl[2][kk], ahn[1]);
                }
                red[wid][0][lane] = arz[0][0];
                red[wid][1][lane] = arz[1][0];
                red[wid][2][lane] = arz[0][1];
                red[wid][3][lane] = arz[1][1];
                red[wid][4][lane] = ain[0];
                red[wid][5][lane] = ain[1];
                red[wid][6][lane] = ahn[0];
                red[wid][7][lane] = ahn[1];
                __syncthreads();
                if (wid == 0) {
                    f32x4 p[8];
                    #pragma unroll
                    for (int grp = 0; grp < 8; grp++) {
                        f32x4 v = red[0][grp][lane];
                        #pragma unroll
                        for (int w2 = 1; w2 < 8; w2++) v += red[w2][grp][lane];
                        p[grp] = v;
                    }
                    if (kh == 1) {
                        #pragma unroll
                        for (int grp = 0; grp < 8; grp++)
                            stc4f((float*)&part[((size_t)blockIdx.x * 8 + grp) * 64 + lane], p[grp]);
                        asm volatile("s_waitcnt vmcnt(0)" ::: "memory");
                        if (lane == 0)
                            __hip_atomic_store(&flagd[blockIdx.x * BSTR], s, __ATOMIC_RELAXED, __HIP_MEMORY_SCOPE_AGENT);
                    } else {
                        while (__hip_atomic_load(&flagd[blockIdx.x * BSTR], __ATOMIC_RELAXED, __HIP_MEMORY_SCOPE_AGENT) < s)
                            __builtin_amdgcn_s_sleep(1);
                        asm volatile("" ::: "memory");
                        #pragma unroll
                        for (int grp = 0; grp < 8; grp++)
                            p[grp] += ldc4f((const float*)&part[((size_t)blockIdx.x * 8 + grp) * 64 + lane]);
                        bf16* wHs = hsHi + (size_t)s * DSLOT + (size_t)NB * HD;
                        bf16* wLs = hsLo + (size_t)s * DSLOT + (size_t)NB * HD;
                        const int64_t h1b = (int64_t)(p1 * NLAY + 1) * NB * HD;
                        #pragma unroll
                        for (int mt = 0; mt < 2; mt++)
                            #pragma unroll
                            for (int r = 0; r < 4; r++) {
                                const int b = mt * 16 + (lane >> 4) * 4 + r;
                                const float rg = sigm(p[0 + mt][r] + brr);
                                const float zg = sigm(p[2 + mt][r] + bzz);
                                const float ng = tanhf(p[4 + mt][r] + bin + rg * (p[6 + mt][r] + bhn));
                                const float hold = h32[h1b + (int64_t)b * HD + j];
                                const float hnew = (1.f - zg) * ng + zg * hold;
                                bf16 hh = f2b(hnew);
                                bf16 hl = f2b(hnew - b2f(hh));
                                h32[(int64_t)(np1 * NLAY + 1) * NB * HD + (int64_t)b * HD + j] = hnew;
                                const int lo_ = b * HD + j;
                                const float hn2 = __shfl_xor(hnew, 1);
                                if (!(lane & 1)) {
                                    bf16 hh2 = f2b(hn2);
                                    bf16 hl2 = f2b(hn2 - b2f(hh2));
                                    stc2(wHs + lo_, hh, hh2);
                                    stc2(wLs + lo_, hl, hl2);
                                }
                                const int64_t ro = ((int64_t)t * NB + b) * HD + j;
                                rnnHi[ro] = hh;
                                rnnLo[ro] = hl;
                            }
                    }
                }
            }
            if (s < LO) gbar2(flags, epoch, NBLK, myid, s + 1, master);
        }
    }
}

// =====================================================================
__global__ __launch_bounds__(64) void softmax_k(const float* __restrict__ sc,
                                                float* __restrict__ aout)
{
    const int row = blockIdx.x, l = threadIdx.x;
    float v0 = sc[row * LI + l], v1 = sc[row * LI + 64 + l];
    float m = fmaxf(v0, v1);
    #pragma unroll
    for (int o = 32; o > 0; o >>= 1) m = fmaxf(m, __shfl_xor(m, o));
    float e0 = expf(v0 - m), e1 = expf(v1 - m);
    float s = e0 + e1;
    #pragma unroll
    for (int o = 32; o > 0; o >>= 1) s += __shfl_xor(s, o);
    const float inv = 1.f / s;
    aout[row * LI + l] = e0 * inv;
    aout[row * LI + 64 + l] = e1 * inv;
}

// ctx from hi/lo enc outputs -> hi/lo JIN
__global__ __launch_bounds__(256) void ctx2_k(const float* __restrict__ at,
                                              const bf16* __restrict__ eHi,
                                              const bf16* __restrict__ eLo,
                                              bf16* __restrict__ jHi,
                                              bf16* __restrict__ jLo)
{
    const int b = blockIdx.y, h0 = blockIdx.x * 128;
    __shared__ __align__(16) float al[LO][LI];
    for (int i = threadIdx.x; i < LO * LI; i += 256) {
        const int to = i >> 7, ti = i & 127;
        al[to][ti] = at[(to * NB + b) * LI + ti];
    }
    __syncthreads();
    const int hc = h0 + (threadIdx.x & 127);
    const int rh = threadIdx.x >> 7;
    float acc[32];
    #pragma unroll
    for (int i = 0; i < 32; i++) acc[i] = 0.f;
    for (int t = 0; t < LI; t++) {
        const int64_t eo = ((int64_t)t * NB + b) * HD + hc;
        const float ev = b2f(eHi[eo]) + b2f(eLo[eo]);
        #pragma unroll
        for (int i = 0; i < 32; i++) acc[i] += ev * al[rh * 32 + i][t];
    }
    #pragma unroll
    for (int i = 0; i < 32; i++) {
        const int64_t jo = ((int64_t)(rh * 32 + i) * NB + b) * (2 * HD) + hc;
        bf16 hh = f2b(acc[i]);
        jHi[jo] = hh;
        jLo[jo] = f2b(acc[i] - b2f(hh));
    }
}

// copy RNN hi/lo into JIN[:, HD:2HD]
__global__ void rnncopy2_k(const bf16* __restrict__ rHi, const bf16* __restrict__ rLo,
                           bf16* __restrict__ jHi, bf16* __restrict__ jLo)
{
    const int idx = blockIdx.x * 256 + threadIdx.x;   // uint2 = 4 bf16
    const int row = idx >> 8;                         // HD/4 = 256 per row
    const int c = idx & 255;
    ((uint2*)jHi)[(int64_t)row * 512 + 256 + c] = ((const uint2*)rHi)[idx];
    ((uint2*)jLo)[(int64_t)row * 512 + 256 + c] = ((const uint2*)rLo)[idx];
}

// =====================================================================
extern "C" void kernel_launch(void* const* d_in, const int* in_sizes, int n_in,
                              void* d_out, int out_size, void* d_ws, size_t ws_size,
                              hipStream_t stream)
{
    (void)in_sizes; (void)n_in; (void)out_size; (void)ws_size;
    const int*   in_tok   = (const int*)d_in[0];
    const int*   out_tok  = (const int*)d_in[2];
    const float* enc_emb  = (const float*)d_in[4];
    const float* enc_wih  = (const float*)d_in[5];
    const float* enc_whh  = (const float*)d_in[6];
    const float* enc_bih  = (const float*)d_in[7];
    const float* enc_bhh  = (const float*)d_in[8];
    const float* dec_emb  = (const float*)d_in[9];
    const float* dec_wih  = (const float*)d_in[10];
    const float* dec_whh  = (const float*)d_in[11];
    const float* dec_bih  = (const float*)d_in[12];
    const float* dec_bhh  = (const float*)d_in[13];
    const float* attn_W   = (const float*)d_in[14];
    const float* joiner_W = (const float*)d_in[15];
    const float* joiner_b = (const float*)d_in[16];
    const float* proj_W   = (const float*)d_in[17];
    const float* proj_b   = (const float*)d_in[18];
    float* logits   = (float*)d_out;
    float* attn_out = logits + (size_t)LO * NB * NV;

    const size_t MB = 1ull << 20;
    char* o = (char*)d_out;   // logits region = 250 MiB fp32
    bf16* XB0HI  = (bf16*)(o);               // 8 MiB (dead after L0 gi)
    bf16* XB0LO  = (bf16*)(o + 8 * MB);      // 8 MiB
    bf16* XB1HI  = (bf16*)(o + 16 * MB);     // 8 MiB
    bf16* XB1LO  = (bf16*)(o + 24 * MB);     // 8 MiB
    bf16* EOUTHI = (bf16*)(o + 32 * MB);     // 8 MiB (alive until ctx)
    bf16* EOUTLO = (bf16*)(o + 40 * MB);     // 8 MiB
    float* PENC  = (float*)(o + 48 * MB);    // 16 MiB fp32 (W of scores)
    float* GI    = (float*)(o + 64 * MB);    // 48 MiB fp32
    float* DGI0  = (float*)(o + 112 * MB);   // 24 MiB fp32
    bf16* ENCH_HI = (bf16*)(o + 136 * MB);   // 8 MiB per-step slots
    bf16* ENCH_LO = (bf16*)(o + 144 * MB);   // 8 MiB
    bf16* JINHI  = (bf16*)(o + 152 * MB);    // 8 MiB (written post-dec)
    bf16* JINLO  = (bf16*)(o + 160 * MB);    // 8 MiB
    bf16* RNNHI  = (bf16*)(o + 168 * MB);    // 4 MiB
    bf16* RNNLO  = (bf16*)(o + 172 * MB);    // 4 MiB
    float* SC    = (float*)(o + 176 * MB);   // 1 MiB
    bf16* WencHi = (bf16*)(o + 177 * MB);    // 6 MiB
    bf16* WencLo = (bf16*)(o + 183 * MB);    // 6 MiB
    bf16* WdhHi  = (bf16*)(o + 189 * MB);    // 12 MiB
    bf16* WdhLo  = (bf16*)(o + 201 * MB);    // 12 MiB
    bf16* Wih1Hi = (bf16*)(o + 213 * MB);    // 6 MiB
    bf16* Wih1Lo = (bf16*)(o + 219 * MB);    // 6 MiB
    char* ba     = o + 225 * MB;             // 3 MiB barrier arena
    f32x4* PART  = (f32x4*)(o + 228 * MB);   // 0.5 MiB
    bf16* DEMBHI = (bf16*)(o + 229 * MB);    // 4 MiB
    bf16* DEMBLO = (bf16*)(o + 233 * MB);    // 4 MiB -> ends 237 < 250
    // per-step dec slots aliased over dead regions:
    bf16* DECH_HI = XB0HI;                   // 8.125 MiB (XB0 dead after L0 gi)
    bf16* DECH_LO = JINHI;                   // 8.125 MiB (JIN written post-dec)

    char* w = (char*)d_ws;
    bf16* VECSHI = (bf16*)(w);                        // 4 MiB
    bf16* VECSLO = (bf16*)(w + 4 * MB);               // 4 MiB
    float* EH32  = (float*)(w + 8 * MB);              // 512 KiB
    float* DH32  = (float*)(w + 8 * MB + 524288);     // 512 KiB

    const size_t KB = 1024;
    int* FL_E  = (int*)(ba);                 // 64 x 8KB = 512 KiB
    int* EP_E  = (int*)(ba + 512 * KB);      // 16 x 8KB = 128 KiB
    int* FL_D  = (int*)(ba + 640 * KB);      // 192 x 8KB = 1536 KiB
    int* EP_D  = (int*)(ba + 2176 * KB);     // 16 x 8KB = 128 KiB
    int* FLAGD = (int*)(ba + 2304 * KB);     // 64 x 8KB = 512 KiB -> 2816 KiB

    hipMemsetAsync(ba, 0, 3 * MB, stream);
    hipMemsetAsync(ENCH_HI, 0, (size_t)ESLOT * 2, stream);   // enc slot 0 = zeros
    hipMemsetAsync(ENCH_LO, 0, (size_t)ESLOT * 2, stream);

    // ---- pre-split recurrent weights (unchanged) ----
    const int nEnc = NLAY * 2 * 3 * HHD * HHD;
    const int nDhh = NLAY * 3 * HD * HD;
    const int nIh1 = 3 * HD * HD;
    presplit_k<<<dim3((nEnc + 255) / 256), dim3(256), 0, stream>>>(enc_whh, WencHi, WencLo, nEnc);
    presplit_k<<<dim3((nDhh + 255) / 256), dim3(256), 0, stream>>>(dec_whh, WdhHi, WdhLo, nDhh);
    presplit_k<<<dim3((nIh1 + 255) / 256), dim3(256), 0, stream>>>(dec_wih + (size_t)3 * HD * HD, Wih1Hi, Wih1Lo, nIh1);

    // ---- decoder prep ----
    embed2_k<<<dim3(LO * NB), dim3(256), 0, stream>>>(out_tok, dec_emb, DEMBHI, DEMBLO, 1);
    gemmWf_k<128, true, false, 0><<<dim3(3 * HD / 128, LO * NB / 128, 1), 256, 0, stream>>>(
        DEMBHI, DEMBLO, HD, 0, dec_wih, HD, 0,
        DGI0, nullptr, nullptr, 3 * HD, 0, dec_bih, 0, HD);

    // ---- encoder ----
    embed2_k<<<dim3(LI * NB), dim3(256), 0, stream>>>(in_tok, enc_emb, XB0HI, XB0LO, 0);
    for (int l = 0; l < NLAY; l++) {
        const bf16* XinH = l ? XB1HI : XB0HI;
        const bf16* XinL = l ? XB1LO : XB0LO;
        bf16* YoH = l ? EOUTHI : XB1HI;
        bf16* YoL = l ? EOUTLO : XB1LO;
        hipMemsetAsync(EH32, 0, (size_t)2 * 2 * NB * HHD * 4, stream);
        gemmWf_k<128, true, false, 0><<<dim3(3 * HHD / 128, LI * NB / 128, 2), 256, 0, stream>>>(
            XinH, XinL, HD, 0,
            enc_wih + (size_t)l * 2 * 3 * HHD * HD, HD, (int64_t)3 * HHD * HD,
            GI, nullptr, nullptr, 3 * HHD, (int64_t)LI * NB * 3 * HHD,
            enc_bih + l * 2 * 3 * HHD, 3 * HHD, HD);
        enc_persist_k<<<dim3(HHD / 16, 2), dim3(256), 0, stream>>>(
            GI,
            WencHi + (size_t)l * 2 * 3 * HHD * HHD,
            WencLo + (size_t)l * 2 * 3 * HHD * HHD,
            enc_bhh + l * 2 * 3 * HHD,
            EH32, ENCH_HI, ENCH_LO, YoH, YoL,
            DH32 + (size_t)l * NB * HD,
            DECH_HI + (size_t)l * NB * HD,
            DECH_LO + (size_t)l * NB * HD,
            FL_E, EP_E);
    }

    // proj_enc = enc_outputs @ attn_W^T (fp32 out; W of scores GEMM)
    gemmWf_k<128, false, false, 0><<<dim3(HD / 128, LI * NB / 128, 1), 256, 0, stream>>>(
        EOUTHI, EOUTLO, HD, 0, attn_W, HD, 0,
        PENC, nullptr, nullptr, HD, 0, nullptr, 0, HD);

    // ---- decoder recurrence (persistent, unchanged) ----
    dec_persist_k<<<dim3(HD / 16, 3), dim3(512), 0, stream>>>(
        DGI0,
        Wih1Hi, Wih1Lo,
        WdhHi, WdhLo,
        WdhHi + (size_t)3 * HD * HD, WdhLo + (size_t)3 * HD * HD,
        dec_bih + 3 * HD, dec_bhh, dec_bhh + 3 * HD,
        DH32, DECH_HI, DECH_LO, RNNHI, RNNLO, PART, FL_D, EP_D, FLAGD);

    // ---- batched epilogue ----
    gemmWf_k<64, false, false, 0><<<dim3(1, 1, NB), 256, 0, stream>>>(
        RNNHI, RNNLO, (int64_t)NB * HD, HD, PENC, (int64_t)NB * HD, HD,
        SC, nullptr, nullptr, (int64_t)NB * LI, LI, nullptr, 0, HD);
    softmax_k<<<dim3(LO * NB), dim3(64), 0, stream>>>(SC, attn_out);
    ctx2_k<<<dim3(HD / 128, NB), dim3(256), 0, stream>>>(attn_out, EOUTHI, EOUTLO, JINHI, JINLO);
    rnncopy2_k<<<dim3(LO * NB * HD / 4 / 256), dim3(256), 0, stream>>>(RNNHI, RNNLO, JINHI, JINLO);
    gemmWf_k<128, true, true, 1><<<dim3(HD / 128, LO * NB / 128, 1), 256, 0, stream>>>(
        JINHI, JINLO, 2 * HD, 0, joiner_W, 2 * HD, 0,
        nullptr, VECSHI, VECSLO, HD, 0, joiner_b, 0, 2 * HD);
    gemmWf_k<128, true, false, 0><<<dim3(NV / 128, LO * NB / 128, 1), 256, 0, stream>>>(
        VECSHI, VECSLO, HD, 0, proj_W, HD, 0,
        logits, nullptr, nullptr, NV, 0, proj_b, 0, HD);
}

// Round 13
// 4860.783 us; speedup vs baseline: 1.2574x; 1.0003x over previous
//
#include <hip/hip_runtime.h>
#include <hip/hip_bf16.h>
#include <stdint.h>

// ---- problem constants ----
constexpr int LI   = 128;    // L_IN
constexpr int LO   = 64;     // L_OUT
constexpr int NB   = 32;     // batch
constexpr int HD   = 1024;   // H
constexpr int HHD  = 512;    // HH
constexpr int NLAY = 2;
constexpr int NV   = 32000;  // V_OUT
constexpr int SOST = 1;

// Round-13: register-budget fix. dec_persist has run at VGPR_Count=128
// since round 6 while needing ~160 (W frags = 96 alone) -> W was silently
// spilled/rematerialized EVERY step (WRITE_SIZE 107MB = scratch traffic;
// 24us/iter = serialized reloads). amdgpu_waves_per_eu forces the
// allocator to use the full budget. No other changes vs round-12.

typedef __hip_bfloat16 bf16;
typedef __attribute__((ext_vector_type(8))) short bf16x8;
typedef __attribute__((ext_vector_type(4))) float f32x4;
typedef unsigned long long u64;

constexpr int BSTR = 2048;   // barrier flag stride in ints = 8 KB
constexpr int NEP  = 16;     // epoch replicas
constexpr int ESLOT = 2 * NB * HHD;     // enc per-step slot (elems)
constexpr int DSLOT = NLAY * NB * HD;   // dec per-step slot (elems)

__device__ __forceinline__ float b2f(bf16 x) { return __bfloat162float(x); }
__device__ __forceinline__ bf16  f2b(float x) { return __float2bfloat16(x); }
__device__ __forceinline__ float sigm(float x) { return 1.0f / (1.0f + expf(-x)); }

__device__ __forceinline__ f32x4 mfma(bf16x8 a, bf16x8 b, f32x4 c) {
    return __builtin_amdgcn_mfma_f32_16x16x32_bf16(a, b, c, 0, 0, 0);
}
__device__ __forceinline__ f32x4 mfma3(bf16x8 ah, bf16x8 al, bf16x8 bh, bf16x8 bl, f32x4 c) {
    c = mfma(ah, bh, c);
    c = mfma(ah, bl, c);
    c = mfma(al, bh, c);
    return c;
}
__device__ __forceinline__ bf16x8 ld8(const bf16* p) { return *(const bf16x8*)p; }

// async global->LDS, 16B per lane; LDS base wave-uniform
__device__ __forceinline__ void g2l16(const void* g, void* l) {
    __builtin_amdgcn_global_load_lds(
        (const __attribute__((address_space(1))) unsigned int*)g,
        (__attribute__((address_space(3))) unsigned int*)l,
        16, 0, 0);
}

// ---- coherent (agent/L3) helpers (recurrence exchange) ----
__device__ __forceinline__ void stc2(bf16* p, bf16 a, bf16 b) {
    unsigned v = (unsigned)*(const unsigned short*)&a |
                 ((unsigned)*(const unsigned short*)&b << 16);
    __hip_atomic_store((unsigned*)p, v, __ATOMIC_RELAXED, __HIP_MEMORY_SCOPE_AGENT);
}
__device__ __forceinline__ f32x4 ldc4f(const float* p) {
    union { f32x4 v; u64 q[2]; } u;
    u.q[0] = __hip_atomic_load((const u64*)p,     __ATOMIC_RELAXED, __HIP_MEMORY_SCOPE_AGENT);
    u.q[1] = __hip_atomic_load((const u64*)p + 1, __ATOMIC_RELAXED, __HIP_MEMORY_SCOPE_AGENT);
    return u.v;
}
__device__ __forceinline__ void stc4f(float* p, f32x4 v) {
    union { f32x4 v; u64 q[2]; } u;
    u.v = v;
    __hip_atomic_store((u64*)p,     u.q[0], __ATOMIC_RELAXED, __HIP_MEMORY_SCOPE_AGENT);
    __hip_atomic_store((u64*)p + 1, u.q[1], __ATOMIC_RELAXED, __HIP_MEMORY_SCOPE_AGENT);
}

__device__ __forceinline__ void split8(const float* p, bf16x8& h8, bf16x8& l8) {
    #pragma unroll
    for (int j = 0; j < 8; j++) {
        float v = p[j];
        bf16 h = f2b(v);
        bf16 l = f2b(v - b2f(h));
        ((bf16*)&h8)[j] = h;
        ((bf16*)&l8)[j] = l;
    }
}

// ---- distributed flag/epoch grid barrier (round-9, proven) ----
__device__ __forceinline__ void gbar2(int* __restrict__ flags, int* __restrict__ epoch,
                                      int nblk, int myid, int val, bool master) {
    __syncthreads();
    const int tid = threadIdx.x;
    if (tid < 64) {
        if (tid == 0) {
            asm volatile("s_waitcnt vmcnt(0)" ::: "memory");
            __hip_atomic_store(&flags[myid * BSTR], val, __ATOMIC_RELAXED, __HIP_MEMORY_SCOPE_AGENT);
        }
        if (master) {
            bool done = false;
            while (!done) {
                bool ok = true;
                for (int i = tid; i < nblk; i += 64)
                    ok &= (__hip_atomic_load(&flags[i * BSTR], __ATOMIC_RELAXED, __HIP_MEMORY_SCOPE_AGENT) >= val);
                done = __all(ok);
                if (!done) __builtin_amdgcn_s_sleep(1);
            }
            if (tid < NEP)
                __hip_atomic_store(&epoch[tid * BSTR], val, __ATOMIC_RELAXED, __HIP_MEMORY_SCOPE_AGENT);
        } else if (tid == 0) {
            int* ep = &epoch[(myid & (NEP - 1)) * BSTR];
            while (__hip_atomic_load(ep, __ATOMIC_RELAXED, __HIP_MEMORY_SCOPE_AGENT) < val)
                __builtin_amdgcn_s_sleep(1);
        }
        asm volatile("" ::: "memory");
    }
    __syncthreads();
}

// =====================================================================
// GEMM: C[m,n] = sum_k A[m,k]*W[n,k] (+bias)(opt tanh).
// A = hi/lo bf16 pair (g2l16-staged); W = fp32 -> bf16 (in-register).
// 2 MFMA per fragment. OM: 0 -> fp32 C; 1 -> bf16 hi/lo pair C.
// =====================================================================
template<int BM, bool BIAS, bool TANH, int OM>
__global__ __launch_bounds__(256) void gemmWf_k(
    const bf16* __restrict__ Ahi, const bf16* __restrict__ Alo,
    int64_t lda, int64_t sA,
    const float* __restrict__ W, int64_t ldw, int64_t sW,
    float* __restrict__ C, bf16* __restrict__ Chi, bf16* __restrict__ Clo,
    int64_t ldc, int64_t sC,
    const float* __restrict__ bias, int64_t sBias,
    int K)
{
    constexpr int FM = BM / 32;
    __shared__ __align__(16) bf16 Ah[BM * 32], Al[BM * 32];
    __shared__ __align__(16) bf16 Wl[128 * 32];
    const int z    = blockIdx.z;
    const bf16* Abh = Ahi + (int64_t)z * sA;
    const bf16* Abl = Alo + (int64_t)z * sA;
    const float* Wb = W + (int64_t)z * sW;
    const int n0   = blockIdx.x * 128;
    const int m0   = blockIdx.y * BM;
    const int tid  = threadIdx.x;
    const int lane = tid & 63, wid = tid >> 6;
    const int wm   = wid >> 1, wn = wid & 1;
    const int srow = lane >> 2;              // row within 16-row chunk
    const int skb  = (lane & 3) * 8;         // k element offset (8 elems = 16B bf16)
    const int r16  = lane & 15;
    const int k8   = (lane >> 4) * 8;

    f32x4 acc[FM][4];
    #pragma unroll
    for (int i = 0; i < FM; i++)
        #pragma unroll
        for (int j = 0; j < 4; j++)
            acc[i][j] = f32x4{0.f, 0.f, 0.f, 0.f};

    for (int k0 = 0; k0 < K; k0 += 32) {
        for (int c = wid; c < BM / 16; c += 4) {
            g2l16(Abh + (int64_t)(m0 + c * 16 + srow) * lda + k0 + skb, Ah + c * 512);
            g2l16(Abl + (int64_t)(m0 + c * 16 + srow) * lda + k0 + skb, Al + c * 512);
        }
        for (int c = wid; c < 8; c += 4) {
            const float* wp = Wb + (int64_t)(n0 + c * 16 + srow) * ldw + k0 + skb;
            bf16x8 wv;
            #pragma unroll
            for (int jj = 0; jj < 8; jj++) ((bf16*)&wv)[jj] = f2b(wp[jj]);
            *(bf16x8*)(Wl + c * 512 + lane * 8) = wv;
        }
        __syncthreads();
        bf16x8 afh[FM], afl[FM], wf[4];
        #pragma unroll
        for (int mt = 0; mt < FM; mt++) {
            const int off = (wm * (BM / 2) + mt * 16 + r16) * 32 + k8;
            afh[mt] = ld8(Ah + off);
            afl[mt] = ld8(Al + off);
        }
        #pragma unroll
        for (int nt = 0; nt < 4; nt++)
            wf[nt] = ld8(Wl + (wn * 64 + nt * 16 + r16) * 32 + k8);
        #pragma unroll
        for (int mt = 0; mt < FM; mt++)
            #pragma unroll
            for (int nt = 0; nt < 4; nt++) {
                acc[mt][nt] = mfma(afh[mt], wf[nt], acc[mt][nt]);
                acc[mt][nt] = mfma(afl[mt], wf[nt], acc[mt][nt]);
            }
        __syncthreads();
    }
    #pragma unroll
    for (int nt = 0; nt < 4; nt++) {
        const int n = n0 + wn * 64 + nt * 16 + r16;
        float bv = 0.f;
        if constexpr (BIAS) bv = bias[(int64_t)z * sBias + n];
        #pragma unroll
        for (int mt = 0; mt < FM; mt++) {
            const int mb = m0 + wm * (BM / 2) + mt * 16 + (lane >> 4) * 4;
            #pragma unroll
            for (int r = 0; r < 4; r++) {
                float v = acc[mt][nt][r] + bv;
                if constexpr (TANH) v = tanhf(v);
                const int64_t co = (int64_t)z * sC + (int64_t)(mb + r) * ldc + n;
                if constexpr (OM == 0) {
                    C[co] = v;
                } else {
                    bf16 hh = f2b(v);
                    Chi[co] = hh;
                    Clo[co] = f2b(v - b2f(hh));
                }
            }
        }
    }
}

__global__ void presplit_k(const float* __restrict__ x, bf16* __restrict__ hi,
                           bf16* __restrict__ lo, int n)
{
    const int i = blockIdx.x * 256 + threadIdx.x;
    if (i < n) {
        float v = x[i];
        bf16 h = f2b(v);
        hi[i] = h;
        lo[i] = f2b(v - b2f(h));
    }
}

// embed writing hi/lo pair
__global__ void embed2_k(const int* __restrict__ toks, const float* __restrict__ tab,
                         bf16* __restrict__ ohi, bf16* __restrict__ olo, int shifted)
{
    const int row = blockIdx.x;
    int tok;
    if (shifted) {
        const int t = row / NB, b = row - t * NB;
        tok = (t == 0) ? SOST : toks[(t - 1) * NB + b];
    } else {
        tok = toks[row];
    }
    const float4 v = ((const float4*)(tab + (int64_t)tok * HD))[threadIdx.x];
    bf16 h0 = f2b(v.x), h1 = f2b(v.y), h2 = f2b(v.z), h3 = f2b(v.w);
    bf16 hv[4] = {h0, h1, h2, h3};
    bf16 lv[4] = {f2b(v.x - b2f(h0)), f2b(v.y - b2f(h1)),
                  f2b(v.z - b2f(h2)), f2b(v.w - b2f(h3))};
    *(uint2*)(ohi + (int64_t)row * HD + threadIdx.x * 4) = *(uint2*)hv;
    *(uint2*)(olo + (int64_t)row * HD + threadIdx.x * 4) = *(uint2*)lv;
}

// =====================================================================
// Persistent encoder layer (round-12 structure). waves_per_eu(1,1):
// full VGPR budget for the W fragments (no spill headroom issues).
// =====================================================================
__global__ __launch_bounds__(256, 1) __attribute__((amdgpu_waves_per_eu(1, 1)))
void enc_persist_k(
    const float* __restrict__ gi,
    const bf16* __restrict__ whhHi,
    const bf16* __restrict__ whhLo,
    const float* __restrict__ bhh,
    float* __restrict__ h32,
    bf16* __restrict__ hsHi, bf16* __restrict__ hsLo,
    bf16* __restrict__ yHi, bf16* __restrict__ yLo,
    float* __restrict__ dh32, bf16* __restrict__ dhHi, bf16* __restrict__ dhLo,
    int* __restrict__ flags, int* __restrict__ epoch)
{
    __shared__ f32x4 red[4][6][64];
    const int d = blockIdx.y;
    const int j0 = blockIdx.x * 16;
    const int tid = threadIdx.x;
    const int lane = tid & 63, wid = tid >> 6;
    const int r16 = lane & 15, k8 = (lane >> 4) * 8;
    const int kq = wid * 128;
    const bf16* WdH = whhHi + (int64_t)d * 3 * HHD * HHD;
    const bf16* WdL = whhLo + (int64_t)d * 3 * HHD * HHD;
    const int j = j0 + r16;
    const int myid = d * 32 + blockIdx.x;
    const bool master = (myid == 0);

    bf16x8 wh[3][4], wl[3][4];
    #pragma unroll
    for (int g = 0; g < 3; g++)
        #pragma unroll
        for (int kk = 0; kk < 4; kk++) {
            const int64_t wo = (int64_t)(g * HHD + j0 + r16) * HHD + kq + kk * 32 + k8;
            wh[g][kk] = ld8(WdH + wo);
            wl[g][kk] = ld8(WdL + wo);
        }
    const float br = bhh[d * 3 * HHD + j];
    const float bz = bhh[d * 3 * HHD + HHD + j];
    const float bn = bhh[d * 3 * HHD + 2 * HHD + j];

    for (int s = 0; s < LI; s++) {
        const int t = d ? (LI - 1 - s) : s;
        const int par = s & 1, npar = par ^ 1;
        const bf16* rH = hsHi + (size_t)s * ESLOT + (size_t)d * NB * HHD;
        const bf16* rL = hsLo + (size_t)s * ESLOT + (size_t)d * NB * HHD;

        f32x4 acc[2][3];
        #pragma unroll
        for (int m = 0; m < 2; m++)
            #pragma unroll
            for (int g = 0; g < 3; g++) acc[m][g] = f32x4{0.f, 0.f, 0.f, 0.f};

        #pragma unroll
        for (int kk = 0; kk < 4; kk++) {
            const int o0 = r16 * HHD + kq + kk * 32 + k8;
            const int o1 = (16 + r16) * HHD + kq + kk * 32 + k8;
            bf16x8 a0h = ld8(rH + o0), a0l = ld8(rL + o0);
            bf16x8 a1h = ld8(rH + o1), a1l = ld8(rL + o1);
            #pragma unroll
            for (int g = 0; g < 3; g++) {
                acc[0][g] = mfma3(a0h, a0l, wh[g][kk], wl[g][kk], acc[0][g]);
                acc[1][g] = mfma3(a1h, a1l, wh[g][kk], wl[g][kk], acc[1][g]);
            }
        }
        #pragma unroll
        for (int m = 0; m < 2; m++)
            #pragma unroll
            for (int g = 0; g < 3; g++)
                red[wid][m * 3 + g][lane] = acc[m][g];
        __syncthreads();
        if (wid == 0) {
            f32x4 a2[2][3];
            #pragma unroll
            for (int m = 0; m < 2; m++)
                #pragma unroll
                for (int g = 0; g < 3; g++)
                    a2[m][g] = red[0][m * 3 + g][lane] + red[1][m * 3 + g][lane]
                             + red[2][m * 3 + g][lane] + red[3][m * 3 + g][lane];
            const float* gid = gi + ((int64_t)d * LI * NB + (int64_t)t * NB) * (3 * HHD);
            bf16* wH = hsHi + (size_t)(s + 1) * ESLOT + (size_t)d * NB * HHD;
            bf16* wL = hsLo + (size_t)(s + 1) * ESLOT + (size_t)d * NB * HHD;
            const int64_t hbase = (int64_t)(par * 2 + d) * NB * HHD;
            #pragma unroll
            for (int mt = 0; mt < 2; mt++)
                #pragma unroll
                for (int r = 0; r < 4; r++) {
                    const int b = mt * 16 + (lane >> 4) * 4 + r;
                    const float ir  = gid[b * 3 * HHD + j];
                    const float iz  = gid[b * 3 * HHD + HHD + j];
                    const float inn = gid[b * 3 * HHD + 2 * HHD + j];
                    const float rg = sigm(ir + a2[mt][0][r] + br);
                    const float zg = sigm(iz + a2[mt][1][r] + bz);
                    const float ng = tanhf(inn + rg * (a2[mt][2][r] + bn));
                    const float hold = h32[hbase + (int64_t)b * HHD + j];
                    const float hnew = (1.f - zg) * ng + zg * hold;
                    bf16 hh = f2b(hnew);
                    bf16 hl = f2b(hnew - b2f(hh));
                    h32[(int64_t)(npar * 2 + d) * NB * HHD + (int64_t)b * HHD + j] = hnew;
                    const int lo_ = b * HHD + j;
                    const float hn2 = __shfl_xor(hnew, 1);
                    if (s < LI - 1 && !(lane & 1)) {
                        bf16 hh2 = f2b(hn2);
                        bf16 hl2 = f2b(hn2 - b2f(hh2));
                        stc2(wH + lo_, hh, hh2);
                        stc2(wL + lo_, hl, hl2);
                    }
                    const int64_t yo = ((int64_t)t * NB + b) * HD + d * HHD + j;
                    yHi[yo] = hh;
                    yLo[yo] = hl;
                    if (s == LI - 1) {
                        const int64_t dof = (int64_t)b * HD + d * HHD + j;
                        dh32[dof] = hnew;
                        dhHi[dof] = hh;
                        dhLo[dof] = hl;
                    }
                }
        }
        if (s < LI - 1) gbar2(flags, epoch, 64, myid, s + 1, master);
    }
}

// =====================================================================
// Persistent decoder (round-12 structure). waves_per_eu(2,2): forces
// 256-VGPR budget so the 96-VGPR W fragments actually stay in registers
// (round-6..12 ran at VGPR=128 -> silent spill, ~24us/iter).
// =====================================================================
__global__ __launch_bounds__(512, 1) __attribute__((amdgpu_waves_per_eu(2, 2)))
void dec_persist_k(
    const float* __restrict__ gi0,
    const bf16* __restrict__ wih1Hi, const bf16* __restrict__ wih1Lo,
    const bf16* __restrict__ whh0Hi, const bf16* __restrict__ whh0Lo,
    const bf16* __restrict__ whh1Hi, const bf16* __restrict__ whh1Lo,
    const float* __restrict__ bih1,
    const float* __restrict__ bhh0,
    const float* __restrict__ bhh1,
    float* __restrict__ h32,
    bf16* __restrict__ hsHi, bf16* __restrict__ hsLo,
    bf16* __restrict__ rnnHi, bf16* __restrict__ rnnLo,
    f32x4* __restrict__ part,
    int* __restrict__ flags, int* __restrict__ epoch,
    int* __restrict__ flagd)
{
    __shared__ f32x4 red[8][8][64];
    const int tid = threadIdx.x;
    const int lane = tid & 63, wid = tid >> 6;
    const int r16 = lane & 15, k8 = (lane >> 4) * 8;
    const int j0 = blockIdx.x * 16;
    const int j = j0 + r16;
    const int NBLK = 64 * 3;
    const int myid = blockIdx.y * 64 + blockIdx.x;
    const bool master = (myid == 0);

    if (blockIdx.y == 0) {
        const int kq = wid * 128;
        bf16x8 wh[3][4], wl[3][4];
        #pragma unroll
        for (int g = 0; g < 3; g++)
            #pragma unroll
            for (int kk = 0; kk < 4; kk++) {
                const int64_t wo = (int64_t)(g * HD + j0 + r16) * HD + kq + kk * 32 + k8;
                wh[g][kk] = ld8(whh0Hi + wo);
                wl[g][kk] = ld8(whh0Lo + wo);
            }
        const float b0r = bhh0[j], b0z = bhh0[HD + j], b0n = bhh0[2 * HD + j];

        for (int s = 0; s <= LO; s++) {
            if (s < LO) {
                const int t = s, par = t & 1, npar = par ^ 1;
                const bf16* rH = hsHi + (size_t)s * DSLOT;
                const bf16* rL = hsLo + (size_t)s * DSLOT;
                f32x4 acc[2][3];
                #pragma unroll
                for (int m = 0; m < 2; m++)
                    #pragma unroll
                    for (int g = 0; g < 3; g++) acc[m][g] = f32x4{0.f, 0.f, 0.f, 0.f};
                #pragma unroll
                for (int kk = 0; kk < 4; kk++) {
                    const int o0 = r16 * HD + kq + kk * 32 + k8;
                    const int o1 = (16 + r16) * HD + kq + kk * 32 + k8;
                    bf16x8 a0h = ld8(rH + o0), a0l = ld8(rL + o0);
                    bf16x8 a1h = ld8(rH + o1), a1l = ld8(rL + o1);
                    #pragma unroll
                    for (int g = 0; g < 3; g++) {
                        acc[0][g] = mfma3(a0h, a0l, wh[g][kk], wl[g][kk], acc[0][g]);
                        acc[1][g] = mfma3(a1h, a1l, wh[g][kk], wl[g][kk], acc[1][g]);
                    }
                }
                #pragma unroll
                for (int m = 0; m < 2; m++)
                    #pragma unroll
                    for (int g = 0; g < 3; g++)
                        red[wid][m * 3 + g][lane] = acc[m][g];
                __syncthreads();
                if (wid == 0) {
                    f32x4 a2[2][3];
                    #pragma unroll
                    for (int m = 0; m < 2; m++)
                        #pragma unroll
                        for (int g = 0; g < 3; g++) {
                            f32x4 v = red[0][m * 3 + g][lane];
                            #pragma unroll
                            for (int w2 = 1; w2 < 8; w2++) v += red[w2][m * 3 + g][lane];
                            a2[m][g] = v;
                        }
                    const float* gid = gi0 + (int64_t)t * NB * 3 * HD;
                    bf16* wHs = hsHi + (size_t)(s + 1) * DSLOT;
                    bf16* wLs = hsLo + (size_t)(s + 1) * DSLOT;
                    const int64_t hb = (int64_t)(par * NLAY + 0) * NB * HD;
                    #pragma unroll
                    for (int mt = 0; mt < 2; mt++)
                        #pragma unroll
                        for (int r = 0; r < 4; r++) {
                            const int b = mt * 16 + (lane >> 4) * 4 + r;
                            const float ir  = gid[b * 3 * HD + j];
                            const float iz  = gid[b * 3 * HD + HD + j];
                            const float inn = gid[b * 3 * HD + 2 * HD + j];
                            const float rg = sigm(ir + a2[mt][0][r] + b0r);
                            const float zg = sigm(iz + a2[mt][1][r] + b0z);
                            const float ng = tanhf(inn + rg * (a2[mt][2][r] + b0n));
                            const float hold = h32[hb + (int64_t)b * HD + j];
                            const float hnew = (1.f - zg) * ng + zg * hold;
                            bf16 hh = f2b(hnew);
                            bf16 hl = f2b(hnew - b2f(hh));
                            h32[(int64_t)(npar * NLAY + 0) * NB * HD + (int64_t)b * HD + j] = hnew;
                            const int lo_ = b * HD + j;
                            const float hn2 = __shfl_xor(hnew, 1);
                            if (!(lane & 1)) {
                                bf16 hh2 = f2b(hn2);
                                bf16 hl2 = f2b(hn2 - b2f(hh2));
                                stc2(wHs + lo_, hh, hh2);
                                stc2(wLs + lo_, hl, hl2);
                            }
                        }
                }
            }
            if (s < LO) gbar2(flags, epoch, NBLK, myid, s + 1, master);
        }
    } else {
        const int kh = blockIdx.y - 1;
        const int kb = kh * 512 + wid * 64;
        bf16x8 wIh[3][2], wIl[3][2], wHh[3][2], wHl[3][2];
        #pragma unroll
        for (int g = 0; g < 3; g++)
            #pragma unroll
            for (int kk = 0; kk < 2; kk++) {
                const int64_t wo = (int64_t)(g * HD + j0 + r16) * HD + kb + kk * 32 + k8;
                wIh[g][kk] = ld8(wih1Hi + wo);
                wIl[g][kk] = ld8(wih1Lo + wo);
                wHh[g][kk] = ld8(whh1Hi + wo);
                wHl[g][kk] = ld8(whh1Lo + wo);
            }
        const float brr = bih1[j] + bhh1[j];
        const float bzz = bih1[HD + j] + bhh1[HD + j];
        const float bin = bih1[2 * HD + j];
        const float bhn = bhh1[2 * HD + j];

        for (int s = 0; s <= LO; s++) {
            if (s >= 1) {
                const int t = s - 1;
                const int p1 = t & 1, np1 = p1 ^ 1;
                const bf16* xH = hsHi + (size_t)s * DSLOT;
                const bf16* xL = hsLo + (size_t)s * DSLOT;
                const bf16* yH = hsHi + (size_t)(s - 1) * DSLOT + (size_t)NB * HD;
                const bf16* yL = hsLo + (size_t)(s - 1) * DSLOT + (size_t)NB * HD;
                f32x4 arz[2][2], ain[2], ahn[2];
                #pragma unroll
                for (int i = 0; i < 2; i++) {
                    arz[i][0] = f32x4{0.f, 0.f, 0.f, 0.f};
                    arz[i][1] = f32x4{0.f, 0.f, 0.f, 0.f};
                    ain[i] = f32x4{0.f, 0.f, 0.f, 0.f};
                    ahn[i] = f32x4{0.f, 0.f, 0.f, 0.f};
                }
                #pragma unroll
                for (int kk = 0; kk < 2; kk++) {
                    const int o0 = r16 * HD + kb + kk * 32 + k8;
                    const int o1 = (16 + r16) * HD + kb + kk * 32 + k8;
                    bf16x8 x0h = ld8(xH + o0), x0l = ld8(xL + o0);
                    bf16x8 x1h = ld8(xH + o1), x1l = ld8(xL + o1);
                    bf16x8 y0h = ld8(yH + o0), y0l = ld8(yL + o0);
                    bf16x8 y1h = ld8(yH + o1), y1l = ld8(yL + o1);
                    arz[0][0] = mfma3(x0h, x0l, wIh[0][kk], wIl[0][kk], arz[0][0]);
                    arz[0][0] = mfma3(y0h, y0l, wHh[0][kk], wHl[0][kk], arz[0][0]);
                    arz[1][0] = mfma3(x1h, x1l, wIh[0][kk], wIl[0][kk], arz[1][0]);
                    arz[1][0] = mfma3(y1h, y1l, wHh[0][kk], wHl[0][kk], arz[1][0]);
                    arz[0][1] = mfma3(x0h, x0l, wIh[1][kk], wIl[1][kk], arz[0][1]);
                    arz[0][1] = mfma3(y0h, y0l, wHh[1][kk], wHl[1][kk], arz[0][1]);
                    arz[1][1] = mfma3(x1h, x1l, wIh[1][kk], wIl[1][kk], arz[1][1]);
                    arz[1][1] = mfma3(y1h, y1l, wHh[1][kk], wHl[1][kk], arz[1][1]);
                    ain[0] = mfma3(x0h, x0l, wIh[2][kk], wIl[2][kk], ain[0]);
                    ain[1] = mfma3(x1h, x1l, wIh[2][kk], wIl[2][kk], ain[1]);
                    ahn[0] = mfma3(y0h, y0l, wHh[2][kk], wHl[2][kk], ahn[0]);
                    ahn[1] = mfma3(y1h, y1l, wHh[2][kk], wHl[2][kk], ahn[1]);
                }
                red[wid][0][lane] = arz[0][0];
                red[wid][1][lane] = arz[1][0];
                red[wid][2][lane] = arz[0][1];
                red[wid][3][lane] = arz[1][1];
                red[wid][4][lane] = ain[0];
                red[wid][5][lane] = ain[1];
                red[wid][6][lane] = ahn[0];
                red[wid][7][lane] = ahn[1];
                __syncthreads();
                if (wid == 0) {
                    f32x4 p[8];
                    #pragma unroll
                    for (int grp = 0; grp < 8; grp++) {
                        f32x4 v = red[0][grp][lane];
                        #pragma unroll
                        for (int w2 = 1; w2 < 8; w2++) v += red[w2][grp][lane];
                        p[grp] = v;
                    }
                    if (kh == 1) {
                        #pragma unroll
                        for (int grp = 0; grp < 8; grp++)
                            stc4f((float*)&part[((size_t)blockIdx.x * 8 + grp) * 64 + lane], p[grp]);
                        asm volatile("s_waitcnt vmcnt(0)" ::: "memory");
                        if (lane == 0)
                            __hip_atomic_store(&flagd[blockIdx.x * BSTR], s, __ATOMIC_RELAXED, __HIP_MEMORY_SCOPE_AGENT);
                    } else {
                        while (__hip_atomic_load(&flagd[blockIdx.x * BSTR], __ATOMIC_RELAXED, __HIP_MEMORY_SCOPE_AGENT) < s)
                            __builtin_amdgcn_s_sleep(1);
                        asm volatile("" ::: "memory");
                        #pragma unroll
                        for (int grp = 0; grp < 8; grp++)
                            p[grp] += ldc4f((const float*)&part[((size_t)blockIdx.x * 8 + grp) * 64 + lane]);
                        bf16* wHs = hsHi + (size_t)s * DSLOT + (size_t)NB * HD;
                        bf16* wLs = hsLo + (size_t)s * DSLOT + (size_t)NB * HD;
                        const int64_t h1b = (int64_t)(p1 * NLAY + 1) * NB * HD;
                        #pragma unroll
                        for (int mt = 0; mt < 2; mt++)
                            #pragma unroll
                            for (int r = 0; r < 4; r++) {
                                const int b = mt * 16 + (lane >> 4) * 4 + r;
                                const float rg = sigm(p[0 + mt][r] + brr);
                                const float zg = sigm(p[2 + mt][r] + bzz);
                                const float ng = tanhf(p[4 + mt][r] + bin + rg * (p[6 + mt][r] + bhn));
                                const float hold = h32[h1b + (int64_t)b * HD + j];
                                const float hnew = (1.f - zg) * ng + zg * hold;
                                bf16 hh = f2b(hnew);
                                bf16 hl = f2b(hnew - b2f(hh));
                                h32[(int64_t)(np1 * NLAY + 1) * NB * HD + (int64_t)b * HD + j] = hnew;
                                const int lo_ = b * HD + j;
                                const float hn2 = __shfl_xor(hnew, 1);
                                if (!(lane & 1)) {
                                    bf16 hh2 = f2b(hn2);
                                    bf16 hl2 = f2b(hn2 - b2f(hh2));
                                    stc2(wHs + lo_, hh, hh2);
                                    stc2(wLs + lo_, hl, hl2);
                                }
                                const int64_t ro = ((int64_t)t * NB + b) * HD + j;
                                rnnHi[ro] = hh;
                                rnnLo[ro] = hl;
                            }
                    }
                }
            }
            if (s < LO) gbar2(flags, epoch, NBLK, myid, s + 1, master);
        }
    }
}

// =====================================================================
__global__ __launch_bounds__(64) void softmax_k(const float* __restrict__ sc,
                                                float* __restrict__ aout)
{
    const int row = blockIdx.x, l = threadIdx.x;
    float v0 = sc[row * LI + l], v1 = sc[row * LI + 64 + l];
    float m = fmaxf(v0, v1);
    #pragma unroll
    for (int o = 32; o > 0; o >>= 1) m = fmaxf(m, __shfl_xor(m, o));
    float e0 = expf(v0 - m), e1 = expf(v1 - m);
    float s = e0 + e1;
    #pragma unroll
    for (int o = 32; o > 0; o >>= 1) s += __shfl_xor(s, o);
    const float inv = 1.f / s;
    aout[row * LI + l] = e0 * inv;
    aout[row * LI + 64 + l] = e1 * inv;
}

// ctx from hi/lo enc outputs -> hi/lo JIN
__global__ __launch_bounds__(256) void ctx2_k(const float* __restrict__ at,
                                              const bf16* __restrict__ eHi,
                                              const bf16* __restrict__ eLo,
                                              bf16* __restrict__ jHi,
                                              bf16* __restrict__ jLo)
{
    const int b = blockIdx.y, h0 = blockIdx.x * 128;
    __shared__ __align__(16) float al[LO][LI];
    for (int i = threadIdx.x; i < LO * LI; i += 256) {
        const int to = i >> 7, ti = i & 127;
        al[to][ti] = at[(to * NB + b) * LI + ti];
    }
    __syncthreads();
    const int hc = h0 + (threadIdx.x & 127);
    const int rh = threadIdx.x >> 7;
    float acc[32];
    #pragma unroll
    for (int i = 0; i < 32; i++) acc[i] = 0.f;
    for (int t = 0; t < LI; t++) {
        const int64_t eo = ((int64_t)t * NB + b) * HD + hc;
        const float ev = b2f(eHi[eo]) + b2f(eLo[eo]);
        #pragma unroll
        for (int i = 0; i < 32; i++) acc[i] += ev * al[rh * 32 + i][t];
    }
    #pragma unroll
    for (int i = 0; i < 32; i++) {
        const int64_t jo = ((int64_t)(rh * 32 + i) * NB + b) * (2 * HD) + hc;
        bf16 hh = f2b(acc[i]);
        jHi[jo] = hh;
        jLo[jo] = f2b(acc[i] - b2f(hh));
    }
}

// copy RNN hi/lo into JIN[:, HD:2HD]
__global__ void rnncopy2_k(const bf16* __restrict__ rHi, const bf16* __restrict__ rLo,
                           bf16* __restrict__ jHi, bf16* __restrict__ jLo)
{
    const int idx = blockIdx.x * 256 + threadIdx.x;   // uint2 = 4 bf16
    const int row = idx >> 8;                         // HD/4 = 256 per row
    const int c = idx & 255;
    ((uint2*)jHi)[(int64_t)row * 512 + 256 + c] = ((const uint2*)rHi)[idx];
    ((uint2*)jLo)[(int64_t)row * 512 + 256 + c] = ((const uint2*)rLo)[idx];
}

// =====================================================================
extern "C" void kernel_launch(void* const* d_in, const int* in_sizes, int n_in,
                              void* d_out, int out_size, void* d_ws, size_t ws_size,
                              hipStream_t stream)
{
    (void)in_sizes; (void)n_in; (void)out_size; (void)ws_size;
    const int*   in_tok   = (const int*)d_in[0];
    const int*   out_tok  = (const int*)d_in[2];
    const float* enc_emb  = (const float*)d_in[4];
    const float* enc_wih  = (const float*)d_in[5];
    const float* enc_whh  = (const float*)d_in[6];
    const float* enc_bih  = (const float*)d_in[7];
    const float* enc_bhh  = (const float*)d_in[8];
    const float* dec_emb  = (const float*)d_in[9];
    const float* dec_wih  = (const float*)d_in[10];
    const float* dec_whh  = (const float*)d_in[11];
    const float* dec_bih  = (const float*)d_in[12];
    const float* dec_bhh  = (const float*)d_in[13];
    const float* attn_W   = (const float*)d_in[14];
    const float* joiner_W = (const float*)d_in[15];
    const float* joiner_b = (const float*)d_in[16];
    const float* proj_W   = (const float*)d_in[17];
    const float* proj_b   = (const float*)d_in[18];
    float* logits   = (float*)d_out;
    float* attn_out = logits + (size_t)LO * NB * NV;

    const size_t MB = 1ull << 20;
    char* o = (char*)d_out;   // logits region = 250 MiB fp32
    bf16* XB0HI  = (bf16*)(o);               // 8 MiB (dead after L0 gi)
    bf16* XB0LO  = (bf16*)(o + 8 * MB);      // 8 MiB
    bf16* XB1HI  = (bf16*)(o + 16 * MB);     // 8 MiB
    bf16* XB1LO  = (bf16*)(o + 24 * MB);     // 8 MiB
    bf16* EOUTHI = (bf16*)(o + 32 * MB);     // 8 MiB (alive until ctx)
    bf16* EOUTLO = (bf16*)(o + 40 * MB);     // 8 MiB
    float* PENC  = (float*)(o + 48 * MB);    // 16 MiB fp32 (W of scores)
    float* GI    = (float*)(o + 64 * MB);    // 48 MiB fp32
    float* DGI0  = (float*)(o + 112 * MB);   // 24 MiB fp32
    bf16* ENCH_HI = (bf16*)(o + 136 * MB);   // 8 MiB per-step slots
    bf16* ENCH_LO = (bf16*)(o + 144 * MB);   // 8 MiB
    bf16* JINHI  = (bf16*)(o + 152 * MB);    // 8 MiB (written post-dec)
    bf16* JINLO  = (bf16*)(o + 160 * MB);    // 8 MiB
    bf16* RNNHI  = (bf16*)(o + 168 * MB);    // 4 MiB
    bf16* RNNLO  = (bf16*)(o + 172 * MB);    // 4 MiB
    float* SC    = (float*)(o + 176 * MB);   // 1 MiB
    bf16* WencHi = (bf16*)(o + 177 * MB);    // 6 MiB
    bf16* WencLo = (bf16*)(o + 183 * MB);    // 6 MiB
    bf16* WdhHi  = (bf16*)(o + 189 * MB);    // 12 MiB
    bf16* WdhLo  = (bf16*)(o + 201 * MB);    // 12 MiB
    bf16* Wih1Hi = (bf16*)(o + 213 * MB);    // 6 MiB
    bf16* Wih1Lo = (bf16*)(o + 219 * MB);    // 6 MiB
    char* ba     = o + 225 * MB;             // 3 MiB barrier arena
    f32x4* PART  = (f32x4*)(o + 228 * MB);   // 0.5 MiB
    bf16* DEMBHI = (bf16*)(o + 229 * MB);    // 4 MiB
    bf16* DEMBLO = (bf16*)(o + 233 * MB);    // 4 MiB -> ends 237 < 250
    // per-step dec slots aliased over dead regions:
    bf16* DECH_HI = XB0HI;                   // 8.125 MiB (XB0 dead after L0 gi)
    bf16* DECH_LO = JINHI;                   // 8.125 MiB (JIN written post-dec)

    char* w = (char*)d_ws;
    bf16* VECSHI = (bf16*)(w);                        // 4 MiB
    bf16* VECSLO = (bf16*)(w + 4 * MB);               // 4 MiB
    float* EH32  = (float*)(w + 8 * MB);              // 512 KiB
    float* DH32  = (float*)(w + 8 * MB + 524288);     // 512 KiB

    const size_t KB = 1024;
    int* FL_E  = (int*)(ba);                 // 64 x 8KB = 512 KiB
    int* EP_E  = (int*)(ba + 512 * KB);      // 16 x 8KB = 128 KiB
    int* FL_D  = (int*)(ba + 640 * KB);      // 192 x 8KB = 1536 KiB
    int* EP_D  = (int*)(ba + 2176 * KB);     // 16 x 8KB = 128 KiB
    int* FLAGD = (int*)(ba + 2304 * KB);     // 64 x 8KB = 512 KiB -> 2816 KiB

    hipMemsetAsync(ba, 0, 3 * MB, stream);
    hipMemsetAsync(ENCH_HI, 0, (size_t)ESLOT * 2, stream);   // enc slot 0 = zeros
    hipMemsetAsync(ENCH_LO, 0, (size_t)ESLOT * 2, stream);

    // ---- pre-split recurrent weights ----
    const int nEnc = NLAY * 2 * 3 * HHD * HHD;
    const int nDhh = NLAY * 3 * HD * HD;
    const int nIh1 = 3 * HD * HD;
    presplit_k<<<dim3((nEnc + 255) / 256), dim3(256), 0, stream>>>(enc_whh, WencHi, WencLo, nEnc);
    presplit_k<<<dim3((nDhh + 255) / 256), dim3(256), 0, stream>>>(dec_whh, WdhHi, WdhLo, nDhh);
    presplit_k<<<dim3((nIh1 + 255) / 256), dim3(256), 0, stream>>>(dec_wih + (size_t)3 * HD * HD, Wih1Hi, Wih1Lo, nIh1);

    // ---- decoder prep ----
    embed2_k<<<dim3(LO * NB), dim3(256), 0, stream>>>(out_tok, dec_emb, DEMBHI, DEMBLO, 1);
    gemmWf_k<128, true, false, 0><<<dim3(3 * HD / 128, LO * NB / 128, 1), 256, 0, stream>>>(
        DEMBHI, DEMBLO, HD, 0, dec_wih, HD, 0,
        DGI0, nullptr, nullptr, 3 * HD, 0, dec_bih, 0, HD);

    // ---- encoder ----
    embed2_k<<<dim3(LI * NB), dim3(256), 0, stream>>>(in_tok, enc_emb, XB0HI, XB0LO, 0);
    for (int l = 0; l < NLAY; l++) {
        const bf16* XinH = l ? XB1HI : XB0HI;
        const bf16* XinL = l ? XB1LO : XB0LO;
        bf16* YoH = l ? EOUTHI : XB1HI;
        bf16* YoL = l ? EOUTLO : XB1LO;
        hipMemsetAsync(EH32, 0, (size_t)2 * 2 * NB * HHD * 4, stream);
        gemmWf_k<128, true, false, 0><<<dim3(3 * HHD / 128, LI * NB / 128, 2), 256, 0, stream>>>(
            XinH, XinL, HD, 0,
            enc_wih + (size_t)l * 2 * 3 * HHD * HD, HD, (int64_t)3 * HHD * HD,
            GI, nullptr, nullptr, 3 * HHD, (int64_t)LI * NB * 3 * HHD,
            enc_bih + l * 2 * 3 * HHD, 3 * HHD, HD);
        enc_persist_k<<<dim3(HHD / 16, 2), dim3(256), 0, stream>>>(
            GI,
            WencHi + (size_t)l * 2 * 3 * HHD * HHD,
            WencLo + (size_t)l * 2 * 3 * HHD * HHD,
            enc_bhh + l * 2 * 3 * HHD,
            EH32, ENCH_HI, ENCH_LO, YoH, YoL,
            DH32 + (size_t)l * NB * HD,
            DECH_HI + (size_t)l * NB * HD,
            DECH_LO + (size_t)l * NB * HD,
            FL_E, EP_E);
    }

    // proj_enc = enc_outputs @ attn_W^T (fp32 out; W of scores GEMM)
    gemmWf_k<128, false, false, 0><<<dim3(HD / 128, LI * NB / 128, 1), 256, 0, stream>>>(
        EOUTHI, EOUTLO, HD, 0, attn_W, HD, 0,
        PENC, nullptr, nullptr, HD, 0, nullptr, 0, HD);

    // ---- decoder recurrence (persistent) ----
    dec_persist_k<<<dim3(HD / 16, 3), dim3(512), 0, stream>>>(
        DGI0,
        Wih1Hi, Wih1Lo,
        WdhHi, WdhLo,
        WdhHi + (size_t)3 * HD * HD, WdhLo + (size_t)3 * HD * HD,
        dec_bih + 3 * HD, dec_bhh, dec_bhh + 3 * HD,
        DH32, DECH_HI, DECH_LO, RNNHI, RNNLO, PART, FL_D, EP_D, FLAGD);

    // ---- batched epilogue ----
    gemmWf_k<64, false, false, 0><<<dim3(1, 1, NB), 256, 0, stream>>>(
        RNNHI, RNNLO, (int64_t)NB * HD, HD, PENC, (int64_t)NB * HD, HD,
        SC, nullptr, nullptr, (int64_t)NB * LI, LI, nullptr, 0, HD);
    softmax_k<<<dim3(LO * NB), dim3(64), 0, stream>>>(SC, attn_out);
    ctx2_k<<<dim3(HD / 128, NB), dim3(256), 0, stream>>>(attn_out, EOUTHI, EOUTLO, JINHI, JINLO);
    rnncopy2_k<<<dim3(LO * NB * HD / 4 / 256), dim3(256), 0, stream>>>(RNNHI, RNNLO, JINHI, JINLO);
    gemmWf_k<128, true, true, 1><<<dim3(HD / 128, LO * NB / 128, 1), 256, 0, stream>>>(
        JINHI, JINLO, 2 * HD, 0, joiner_W, 2 * HD, 0,
        nullptr, VECSHI, VECSLO, HD, 0, joiner_b, 0, 2 * HD);
    gemmWf_k<128, true, false, 0><<<dim3(NV / 128, LO * NB / 128, 1), 256, 0, stream>>>(
        VECSHI, VECSLO, HD, 0, proj_W, HD, 0,
        logits, nullptr, nullptr, NV, 0, proj_b, 0, HD);
}

// Round 14
// 4380.481 us; speedup vs baseline: 1.3953x; 1.1096x over previous
//
#include <hip/hip_runtime.h>
#include <hip/hip_bf16.h>
#include <stdint.h>

// ---- problem constants ----
constexpr int LI   = 128;    // L_IN
constexpr int LO   = 64;     // L_OUT
constexpr int NB   = 32;     // batch
constexpr int HD   = 1024;   // H
constexpr int HHD  = 512;    // HH
constexpr int NLAY = 2;
constexpr int NV   = 32000;  // V_OUT
constexpr int SOST = 1;

// Round-14: decoder sync-mechanism A/B — persistent grid-barrier loop
// replaced by 65 graph-replayed per-step launches (kernel boundary =
// free acquire/release coherence; plain loads/stores for h slots).
// All math/data layouts identical to round-13. Encoder unchanged.

typedef __hip_bfloat16 bf16;
typedef __attribute__((ext_vector_type(8))) short bf16x8;
typedef __attribute__((ext_vector_type(4))) float f32x4;
typedef unsigned long long u64;

constexpr int BSTR = 2048;   // barrier flag stride in ints = 8 KB
constexpr int NEP  = 16;     // epoch replicas
constexpr int ESLOT = 2 * NB * HHD;     // enc per-step slot (elems)
constexpr int DSLOT = NLAY * NB * HD;   // dec per-step slot (elems)

__device__ __forceinline__ float b2f(bf16 x) { return __bfloat162float(x); }
__device__ __forceinline__ bf16  f2b(float x) { return __float2bfloat16(x); }
__device__ __forceinline__ float sigm(float x) { return 1.0f / (1.0f + expf(-x)); }

__device__ __forceinline__ f32x4 mfma(bf16x8 a, bf16x8 b, f32x4 c) {
    return __builtin_amdgcn_mfma_f32_16x16x32_bf16(a, b, c, 0, 0, 0);
}
__device__ __forceinline__ f32x4 mfma3(bf16x8 ah, bf16x8 al, bf16x8 bh, bf16x8 bl, f32x4 c) {
    c = mfma(ah, bh, c);
    c = mfma(ah, bl, c);
    c = mfma(al, bh, c);
    return c;
}
__device__ __forceinline__ bf16x8 ld8(const bf16* p) { return *(const bf16x8*)p; }

// async global->LDS, 16B per lane; LDS base wave-uniform
__device__ __forceinline__ void g2l16(const void* g, void* l) {
    __builtin_amdgcn_global_load_lds(
        (const __attribute__((address_space(1))) unsigned int*)g,
        (__attribute__((address_space(3))) unsigned int*)l,
        16, 0, 0);
}

// ---- coherent (agent/L3) helpers ----
__device__ __forceinline__ void stc2(bf16* p, bf16 a, bf16 b) {
    unsigned v = (unsigned)*(const unsigned short*)&a |
                 ((unsigned)*(const unsigned short*)&b << 16);
    __hip_atomic_store((unsigned*)p, v, __ATOMIC_RELAXED, __HIP_MEMORY_SCOPE_AGENT);
}
__device__ __forceinline__ f32x4 ldc4f(const float* p) {
    union { f32x4 v; u64 q[2]; } u;
    u.q[0] = __hip_atomic_load((const u64*)p,     __ATOMIC_RELAXED, __HIP_MEMORY_SCOPE_AGENT);
    u.q[1] = __hip_atomic_load((const u64*)p + 1, __ATOMIC_RELAXED, __HIP_MEMORY_SCOPE_AGENT);
    return u.v;
}
__device__ __forceinline__ void stc4f(float* p, f32x4 v) {
    union { f32x4 v; u64 q[2]; } u;
    u.v = v;
    __hip_atomic_store((u64*)p,     u.q[0], __ATOMIC_RELAXED, __HIP_MEMORY_SCOPE_AGENT);
    __hip_atomic_store((u64*)p + 1, u.q[1], __ATOMIC_RELAXED, __HIP_MEMORY_SCOPE_AGENT);
}

__device__ __forceinline__ void split8(const float* p, bf16x8& h8, bf16x8& l8) {
    #pragma unroll
    for (int j = 0; j < 8; j++) {
        float v = p[j];
        bf16 h = f2b(v);
        bf16 l = f2b(v - b2f(h));
        ((bf16*)&h8)[j] = h;
        ((bf16*)&l8)[j] = l;
    }
}

// ---- distributed flag/epoch grid barrier (encoder only) ----
__device__ __forceinline__ void gbar2(int* __restrict__ flags, int* __restrict__ epoch,
                                      int nblk, int myid, int val, bool master) {
    __syncthreads();
    const int tid = threadIdx.x;
    if (tid < 64) {
        if (tid == 0) {
            asm volatile("s_waitcnt vmcnt(0)" ::: "memory");
            __hip_atomic_store(&flags[myid * BSTR], val, __ATOMIC_RELAXED, __HIP_MEMORY_SCOPE_AGENT);
        }
        if (master) {
            bool done = false;
            while (!done) {
                bool ok = true;
                for (int i = tid; i < nblk; i += 64)
                    ok &= (__hip_atomic_load(&flags[i * BSTR], __ATOMIC_RELAXED, __HIP_MEMORY_SCOPE_AGENT) >= val);
                done = __all(ok);
                if (!done) __builtin_amdgcn_s_sleep(1);
            }
            if (tid < NEP)
                __hip_atomic_store(&epoch[tid * BSTR], val, __ATOMIC_RELAXED, __HIP_MEMORY_SCOPE_AGENT);
        } else if (tid == 0) {
            int* ep = &epoch[(myid & (NEP - 1)) * BSTR];
            while (__hip_atomic_load(ep, __ATOMIC_RELAXED, __HIP_MEMORY_SCOPE_AGENT) < val)
                __builtin_amdgcn_s_sleep(1);
        }
        asm volatile("" ::: "memory");
    }
    __syncthreads();
}

// =====================================================================
// GEMM: C[m,n] = sum_k A[m,k]*W[n,k] (+bias)(opt tanh).
// A = hi/lo bf16 pair (g2l16-staged); W = fp32 -> bf16 (in-register).
// 2 MFMA per fragment. OM: 0 -> fp32 C; 1 -> bf16 hi/lo pair C.
// =====================================================================
template<int BM, bool BIAS, bool TANH, int OM>
__global__ __launch_bounds__(256) void gemmWf_k(
    const bf16* __restrict__ Ahi, const bf16* __restrict__ Alo,
    int64_t lda, int64_t sA,
    const float* __restrict__ W, int64_t ldw, int64_t sW,
    float* __restrict__ C, bf16* __restrict__ Chi, bf16* __restrict__ Clo,
    int64_t ldc, int64_t sC,
    const float* __restrict__ bias, int64_t sBias,
    int K)
{
    constexpr int FM = BM / 32;
    __shared__ __align__(16) bf16 Ah[BM * 32], Al[BM * 32];
    __shared__ __align__(16) bf16 Wl[128 * 32];
    const int z    = blockIdx.z;
    const bf16* Abh = Ahi + (int64_t)z * sA;
    const bf16* Abl = Alo + (int64_t)z * sA;
    const float* Wb = W + (int64_t)z * sW;
    const int n0   = blockIdx.x * 128;
    const int m0   = blockIdx.y * BM;
    const int tid  = threadIdx.x;
    const int lane = tid & 63, wid = tid >> 6;
    const int wm   = wid >> 1, wn = wid & 1;
    const int srow = lane >> 2;
    const int skb  = (lane & 3) * 8;
    const int r16  = lane & 15;
    const int k8   = (lane >> 4) * 8;

    f32x4 acc[FM][4];
    #pragma unroll
    for (int i = 0; i < FM; i++)
        #pragma unroll
        for (int j = 0; j < 4; j++)
            acc[i][j] = f32x4{0.f, 0.f, 0.f, 0.f};

    for (int k0 = 0; k0 < K; k0 += 32) {
        for (int c = wid; c < BM / 16; c += 4) {
            g2l16(Abh + (int64_t)(m0 + c * 16 + srow) * lda + k0 + skb, Ah + c * 512);
            g2l16(Abl + (int64_t)(m0 + c * 16 + srow) * lda + k0 + skb, Al + c * 512);
        }
        for (int c = wid; c < 8; c += 4) {
            const float* wp = Wb + (int64_t)(n0 + c * 16 + srow) * ldw + k0 + skb;
            bf16x8 wv;
            #pragma unroll
            for (int jj = 0; jj < 8; jj++) ((bf16*)&wv)[jj] = f2b(wp[jj]);
            *(bf16x8*)(Wl + c * 512 + lane * 8) = wv;
        }
        __syncthreads();
        bf16x8 afh[FM], afl[FM], wf[4];
        #pragma unroll
        for (int mt = 0; mt < FM; mt++) {
            const int off = (wm * (BM / 2) + mt * 16 + r16) * 32 + k8;
            afh[mt] = ld8(Ah + off);
            afl[mt] = ld8(Al + off);
        }
        #pragma unroll
        for (int nt = 0; nt < 4; nt++)
            wf[nt] = ld8(Wl + (wn * 64 + nt * 16 + r16) * 32 + k8);
        #pragma unroll
        for (int mt = 0; mt < FM; mt++)
            #pragma unroll
            for (int nt = 0; nt < 4; nt++) {
                acc[mt][nt] = mfma(afh[mt], wf[nt], acc[mt][nt]);
                acc[mt][nt] = mfma(afl[mt], wf[nt], acc[mt][nt]);
            }
        __syncthreads();
    }
    #pragma unroll
    for (int nt = 0; nt < 4; nt++) {
        const int n = n0 + wn * 64 + nt * 16 + r16;
        float bv = 0.f;
        if constexpr (BIAS) bv = bias[(int64_t)z * sBias + n];
        #pragma unroll
        for (int mt = 0; mt < FM; mt++) {
            const int mb = m0 + wm * (BM / 2) + mt * 16 + (lane >> 4) * 4;
            #pragma unroll
            for (int r = 0; r < 4; r++) {
                float v = acc[mt][nt][r] + bv;
                if constexpr (TANH) v = tanhf(v);
                const int64_t co = (int64_t)z * sC + (int64_t)(mb + r) * ldc + n;
                if constexpr (OM == 0) {
                    C[co] = v;
                } else {
                    bf16 hh = f2b(v);
                    Chi[co] = hh;
                    Clo[co] = f2b(v - b2f(hh));
                }
            }
        }
    }
}

__global__ void presplit_k(const float* __restrict__ x, bf16* __restrict__ hi,
                           bf16* __restrict__ lo, int n)
{
    const int i = blockIdx.x * 256 + threadIdx.x;
    if (i < n) {
        float v = x[i];
        bf16 h = f2b(v);
        hi[i] = h;
        lo[i] = f2b(v - b2f(h));
    }
}

// embed writing hi/lo pair
__global__ void embed2_k(const int* __restrict__ toks, const float* __restrict__ tab,
                         bf16* __restrict__ ohi, bf16* __restrict__ olo, int shifted)
{
    const int row = blockIdx.x;
    int tok;
    if (shifted) {
        const int t = row / NB, b = row - t * NB;
        tok = (t == 0) ? SOST : toks[(t - 1) * NB + b];
    } else {
        tok = toks[row];
    }
    const float4 v = ((const float4*)(tab + (int64_t)tok * HD))[threadIdx.x];
    bf16 h0 = f2b(v.x), h1 = f2b(v.y), h2 = f2b(v.z), h3 = f2b(v.w);
    bf16 hv[4] = {h0, h1, h2, h3};
    bf16 lv[4] = {f2b(v.x - b2f(h0)), f2b(v.y - b2f(h1)),
                  f2b(v.z - b2f(h2)), f2b(v.w - b2f(h3))};
    *(uint2*)(ohi + (int64_t)row * HD + threadIdx.x * 4) = *(uint2*)hv;
    *(uint2*)(olo + (int64_t)row * HD + threadIdx.x * 4) = *(uint2*)lv;
}

// =====================================================================
// Persistent encoder layer (round-13, unchanged/passing).
// =====================================================================
__global__ __launch_bounds__(256, 1) void enc_persist_k(
    const float* __restrict__ gi,
    const bf16* __restrict__ whhHi,
    const bf16* __restrict__ whhLo,
    const float* __restrict__ bhh,
    float* __restrict__ h32,
    bf16* __restrict__ hsHi, bf16* __restrict__ hsLo,
    bf16* __restrict__ yHi, bf16* __restrict__ yLo,
    float* __restrict__ dh32, bf16* __restrict__ dhHi, bf16* __restrict__ dhLo,
    int* __restrict__ flags, int* __restrict__ epoch)
{
    __shared__ f32x4 red[4][6][64];
    const int d = blockIdx.y;
    const int j0 = blockIdx.x * 16;
    const int tid = threadIdx.x;
    const int lane = tid & 63, wid = tid >> 6;
    const int r16 = lane & 15, k8 = (lane >> 4) * 8;
    const int kq = wid * 128;
    const bf16* WdH = whhHi + (int64_t)d * 3 * HHD * HHD;
    const bf16* WdL = whhLo + (int64_t)d * 3 * HHD * HHD;
    const int j = j0 + r16;
    const int myid = d * 32 + blockIdx.x;
    const bool master = (myid == 0);

    bf16x8 wh[3][4], wl[3][4];
    #pragma unroll
    for (int g = 0; g < 3; g++)
        #pragma unroll
        for (int kk = 0; kk < 4; kk++) {
            const int64_t wo = (int64_t)(g * HHD + j0 + r16) * HHD + kq + kk * 32 + k8;
            wh[g][kk] = ld8(WdH + wo);
            wl[g][kk] = ld8(WdL + wo);
        }
    const float br = bhh[d * 3 * HHD + j];
    const float bz = bhh[d * 3 * HHD + HHD + j];
    const float bn = bhh[d * 3 * HHD + 2 * HHD + j];

    for (int s = 0; s < LI; s++) {
        const int t = d ? (LI - 1 - s) : s;
        const int par = s & 1, npar = par ^ 1;
        const bf16* rH = hsHi + (size_t)s * ESLOT + (size_t)d * NB * HHD;
        const bf16* rL = hsLo + (size_t)s * ESLOT + (size_t)d * NB * HHD;

        f32x4 acc[2][3];
        #pragma unroll
        for (int m = 0; m < 2; m++)
            #pragma unroll
            for (int g = 0; g < 3; g++) acc[m][g] = f32x4{0.f, 0.f, 0.f, 0.f};

        #pragma unroll
        for (int kk = 0; kk < 4; kk++) {
            const int o0 = r16 * HHD + kq + kk * 32 + k8;
            const int o1 = (16 + r16) * HHD + kq + kk * 32 + k8;
            bf16x8 a0h = ld8(rH + o0), a0l = ld8(rL + o0);
            bf16x8 a1h = ld8(rH + o1), a1l = ld8(rL + o1);
            #pragma unroll
            for (int g = 0; g < 3; g++) {
                acc[0][g] = mfma3(a0h, a0l, wh[g][kk], wl[g][kk], acc[0][g]);
                acc[1][g] = mfma3(a1h, a1l, wh[g][kk], wl[g][kk], acc[1][g]);
            }
        }
        #pragma unroll
        for (int m = 0; m < 2; m++)
            #pragma unroll
            for (int g = 0; g < 3; g++)
                red[wid][m * 3 + g][lane] = acc[m][g];
        __syncthreads();
        if (wid == 0) {
            f32x4 a2[2][3];
            #pragma unroll
            for (int m = 0; m < 2; m++)
                #pragma unroll
                for (int g = 0; g < 3; g++)
                    a2[m][g] = red[0][m * 3 + g][lane] + red[1][m * 3 + g][lane]
                             + red[2][m * 3 + g][lane] + red[3][m * 3 + g][lane];
            const float* gid = gi + ((int64_t)d * LI * NB + (int64_t)t * NB) * (3 * HHD);
            bf16* wH = hsHi + (size_t)(s + 1) * ESLOT + (size_t)d * NB * HHD;
            bf16* wL = hsLo + (size_t)(s + 1) * ESLOT + (size_t)d * NB * HHD;
            const int64_t hbase = (int64_t)(par * 2 + d) * NB * HHD;
            #pragma unroll
            for (int mt = 0; mt < 2; mt++)
                #pragma unroll
                for (int r = 0; r < 4; r++) {
                    const int b = mt * 16 + (lane >> 4) * 4 + r;
                    const float ir  = gid[b * 3 * HHD + j];
                    const float iz  = gid[b * 3 * HHD + HHD + j];
                    const float inn = gid[b * 3 * HHD + 2 * HHD + j];
                    const float rg = sigm(ir + a2[mt][0][r] + br);
                    const float zg = sigm(iz + a2[mt][1][r] + bz);
                    const float ng = tanhf(inn + rg * (a2[mt][2][r] + bn));
                    const float hold = h32[hbase + (int64_t)b * HHD + j];
                    const float hnew = (1.f - zg) * ng + zg * hold;
                    bf16 hh = f2b(hnew);
                    bf16 hl = f2b(hnew - b2f(hh));
                    h32[(int64_t)(npar * 2 + d) * NB * HHD + (int64_t)b * HHD + j] = hnew;
                    const int lo_ = b * HHD + j;
                    const float hn2 = __shfl_xor(hnew, 1);
                    if (s < LI - 1 && !(lane & 1)) {
                        bf16 hh2 = f2b(hn2);
                        bf16 hl2 = f2b(hn2 - b2f(hh2));
                        stc2(wH + lo_, hh, hh2);
                        stc2(wL + lo_, hl, hl2);
                    }
                    const int64_t yo = ((int64_t)t * NB + b) * HD + d * HHD + j;
                    yHi[yo] = hh;
                    yLo[yo] = hl;
                    if (s == LI - 1) {
                        const int64_t dof = (int64_t)b * HD + d * HHD + j;
                        dh32[dof] = hnew;
                        dhHi[dof] = hh;
                        dhLo[dof] = hl;
                    }
                }
        }
        if (s < LI - 1) gbar2(flags, epoch, 64, myid, s + 1, master);
    }
}

// =====================================================================
// Decoder PER-STEP kernel (round-13 math, kernel boundary = coherence).
// Launch s = 0..LO. Grid (64, 3) x 512 thr.
//  y=0: layer0 @ t=s (if s<LO): reads slot s (layer0 part), writes slot s+1.
//  y=1,2: layer1 K-half @ t=s-1 (if s>=1): reads slot s (l0) + s-1 (l1),
//         kh1 -> PART -> flagd (atomic, intra-launch); kh0 -> cell -> slot s.
// Plain loads/stores for slots/h32/rnn (cross-launch coherence via dispatch).
// =====================================================================
__global__ __launch_bounds__(512) void dec_step_k(
    const float* __restrict__ gi0,
    const bf16* __restrict__ wih1Hi, const bf16* __restrict__ wih1Lo,
    const bf16* __restrict__ whh0Hi, const bf16* __restrict__ whh0Lo,
    const bf16* __restrict__ whh1Hi, const bf16* __restrict__ whh1Lo,
    const float* __restrict__ bih1,
    const float* __restrict__ bhh0,
    const float* __restrict__ bhh1,
    float* __restrict__ h32,
    bf16* __restrict__ hsHi, bf16* __restrict__ hsLo,
    bf16* __restrict__ rnnHi, bf16* __restrict__ rnnLo,
    f32x4* __restrict__ part,
    int* __restrict__ flagd,
    int s)
{
    __shared__ f32x4 red[8][8][64];
    const int tid = threadIdx.x;
    const int lane = tid & 63, wid = tid >> 6;
    const int r16 = lane & 15, k8 = (lane >> 4) * 8;
    const int j0 = blockIdx.x * 16;
    const int j = j0 + r16;

    if (blockIdx.y == 0) {
        if (s >= LO) return;
        const int t = s, par = t & 1, npar = par ^ 1;
        const int kq = wid * 128;
        bf16x8 wh[3][4], wl[3][4];
        #pragma unroll
        for (int g = 0; g < 3; g++)
            #pragma unroll
            for (int kk = 0; kk < 4; kk++) {
                const int64_t wo = (int64_t)(g * HD + j0 + r16) * HD + kq + kk * 32 + k8;
                wh[g][kk] = ld8(whh0Hi + wo);
                wl[g][kk] = ld8(whh0Lo + wo);
            }
        const bf16* rH = hsHi + (size_t)s * DSLOT;
        const bf16* rL = hsLo + (size_t)s * DSLOT;
        f32x4 acc[2][3];
        #pragma unroll
        for (int m = 0; m < 2; m++)
            #pragma unroll
            for (int g = 0; g < 3; g++) acc[m][g] = f32x4{0.f, 0.f, 0.f, 0.f};
        #pragma unroll
        for (int kk = 0; kk < 4; kk++) {
            const int o0 = r16 * HD + kq + kk * 32 + k8;
            const int o1 = (16 + r16) * HD + kq + kk * 32 + k8;
            bf16x8 a0h = ld8(rH + o0), a0l = ld8(rL + o0);
            bf16x8 a1h = ld8(rH + o1), a1l = ld8(rL + o1);
            #pragma unroll
            for (int g = 0; g < 3; g++) {
                acc[0][g] = mfma3(a0h, a0l, wh[g][kk], wl[g][kk], acc[0][g]);
                acc[1][g] = mfma3(a1h, a1l, wh[g][kk], wl[g][kk], acc[1][g]);
            }
        }
        #pragma unroll
        for (int m = 0; m < 2; m++)
            #pragma unroll
            for (int g = 0; g < 3; g++)
                red[wid][m * 3 + g][lane] = acc[m][g];
        __syncthreads();
        if (wid == 0) {
            const float b0r = bhh0[j], b0z = bhh0[HD + j], b0n = bhh0[2 * HD + j];
            f32x4 a2[2][3];
            #pragma unroll
            for (int m = 0; m < 2; m++)
                #pragma unroll
                for (int g = 0; g < 3; g++) {
                    f32x4 v = red[0][m * 3 + g][lane];
                    #pragma unroll
                    for (int w2 = 1; w2 < 8; w2++) v += red[w2][m * 3 + g][lane];
                    a2[m][g] = v;
                }
            const float* gid = gi0 + (int64_t)t * NB * 3 * HD;
            bf16* wHs = hsHi + (size_t)(s + 1) * DSLOT;
            bf16* wLs = hsLo + (size_t)(s + 1) * DSLOT;
            const int64_t hb = (int64_t)(par * NLAY + 0) * NB * HD;
            #pragma unroll
            for (int mt = 0; mt < 2; mt++)
                #pragma unroll
                for (int r = 0; r < 4; r++) {
                    const int b = mt * 16 + (lane >> 4) * 4 + r;
                    const float ir  = gid[b * 3 * HD + j];
                    const float iz  = gid[b * 3 * HD + HD + j];
                    const float inn = gid[b * 3 * HD + 2 * HD + j];
                    const float rg = sigm(ir + a2[mt][0][r] + b0r);
                    const float zg = sigm(iz + a2[mt][1][r] + b0z);
                    const float ng = tanhf(inn + rg * (a2[mt][2][r] + b0n));
                    const float hold = h32[hb + (int64_t)b * HD + j];
                    const float hnew = (1.f - zg) * ng + zg * hold;
                    bf16 hh = f2b(hnew);
                    bf16 hl = f2b(hnew - b2f(hh));
                    h32[(int64_t)(npar * NLAY + 0) * NB * HD + (int64_t)b * HD + j] = hnew;
                    const int lo_ = b * HD + j;
                    wHs[lo_] = hh;
                    wLs[lo_] = hl;
                }
        }
    } else {
        if (s < 1) return;
        const int t = s - 1;
        const int p1 = t & 1, np1 = p1 ^ 1;
        const int kh = blockIdx.y - 1;
        const int kb = kh * 512 + wid * 64;
        bf16x8 wIh[3][2], wIl[3][2], wHh[3][2], wHl[3][2];
        #pragma unroll
        for (int g = 0; g < 3; g++)
            #pragma unroll
            for (int kk = 0; kk < 2; kk++) {
                const int64_t wo = (int64_t)(g * HD + j0 + r16) * HD + kb + kk * 32 + k8;
                wIh[g][kk] = ld8(wih1Hi + wo);
                wIl[g][kk] = ld8(wih1Lo + wo);
                wHh[g][kk] = ld8(whh1Hi + wo);
                wHl[g][kk] = ld8(whh1Lo + wo);
            }
        const bf16* xH = hsHi + (size_t)s * DSLOT;
        const bf16* xL = hsLo + (size_t)s * DSLOT;
        const bf16* yH = hsHi + (size_t)(s - 1) * DSLOT + (size_t)NB * HD;
        const bf16* yL = hsLo + (size_t)(s - 1) * DSLOT + (size_t)NB * HD;
        f32x4 arz[2][2], ain[2], ahn[2];
        #pragma unroll
        for (int i = 0; i < 2; i++) {
            arz[i][0] = f32x4{0.f, 0.f, 0.f, 0.f};
            arz[i][1] = f32x4{0.f, 0.f, 0.f, 0.f};
            ain[i] = f32x4{0.f, 0.f, 0.f, 0.f};
            ahn[i] = f32x4{0.f, 0.f, 0.f, 0.f};
        }
        #pragma unroll
        for (int kk = 0; kk < 2; kk++) {
            const int o0 = r16 * HD + kb + kk * 32 + k8;
            const int o1 = (16 + r16) * HD + kb + kk * 32 + k8;
            bf16x8 x0h = ld8(xH + o0), x0l = ld8(xL + o0);
            bf16x8 x1h = ld8(xH + o1), x1l = ld8(xL + o1);
            bf16x8 y0h = ld8(yH + o0), y0l = ld8(yL + o0);
            bf16x8 y1h = ld8(yH + o1), y1l = ld8(yL + o1);
            arz[0][0] = mfma3(x0h, x0l, wIh[0][kk], wIl[0][kk], arz[0][0]);
            arz[0][0] = mfma3(y0h, y0l, wHh[0][kk], wHl[0][kk], arz[0][0]);
            arz[1][0] = mfma3(x1h, x1l, wIh[0][kk], wIl[0][kk], arz[1][0]);
            arz[1][0] = mfma3(y1h, y1l, wHh[0][kk], wHl[0][kk], arz[1][0]);
            arz[0][1] = mfma3(x0h, x0l, wIh[1][kk], wIl[1][kk], arz[0][1]);
            arz[0][1] = mfma3(y0h, y0l, wHh[1][kk], wHl[1][kk], arz[0][1]);
            arz[1][1] = mfma3(x1h, x1l, wIh[1][kk], wIl[1][kk], arz[1][1]);
            arz[1][1] = mfma3(y1h, y1l, wHh[1][kk], wHl[1][kk], arz[1][1]);
            ain[0] = mfma3(x0h, x0l, wIh[2][kk], wIl[2][kk], ain[0]);
            ain[1] = mfma3(x1h, x1l, wIh[2][kk], wIl[2][kk], ain[1]);
            ahn[0] = mfma3(y0h, y0l, wHh[2][kk], wHl[2][kk], ahn[0]);
            ahn[1] = mfma3(y1h, y1l, wHh[2][kk], wHl[2][kk], ahn[1]);
        }
        red[wid][0][lane] = arz[0][0];
        red[wid][1][lane] = arz[1][0];
        red[wid][2][lane] = arz[0][1];
        red[wid][3][lane] = arz[1][1];
        red[wid][4][lane] = ain[0];
        red[wid][5][lane] = ain[1];
        red[wid][6][lane] = ahn[0];
        red[wid][7][lane] = ahn[1];
        __syncthreads();
        if (wid == 0) {
            f32x4 p[8];
            #pragma unroll
            for (int grp = 0; grp < 8; grp++) {
                f32x4 v = red[0][grp][lane];
                #pragma unroll
                for (int w2 = 1; w2 < 8; w2++) v += red[w2][grp][lane];
                p[grp] = v;
            }
            if (kh == 1) {
                #pragma unroll
                for (int grp = 0; grp < 8; grp++)
                    stc4f((float*)&part[((size_t)blockIdx.x * 8 + grp) * 64 + lane], p[grp]);
                asm volatile("s_waitcnt vmcnt(0)" ::: "memory");
                if (lane == 0)
                    __hip_atomic_store(&flagd[blockIdx.x * BSTR], s, __ATOMIC_RELAXED, __HIP_MEMORY_SCOPE_AGENT);
            } else {
                while (__hip_atomic_load(&flagd[blockIdx.x * BSTR], __ATOMIC_RELAXED, __HIP_MEMORY_SCOPE_AGENT) < s)
                    __builtin_amdgcn_s_sleep(1);
                asm volatile("" ::: "memory");
                #pragma unroll
                for (int grp = 0; grp < 8; grp++)
                    p[grp] += ldc4f((const float*)&part[((size_t)blockIdx.x * 8 + grp) * 64 + lane]);
                const float brr = bih1[j] + bhh1[j];
                const float bzz = bih1[HD + j] + bhh1[HD + j];
                const float bin = bih1[2 * HD + j];
                const float bhn = bhh1[2 * HD + j];
                bf16* wHs = hsHi + (size_t)s * DSLOT + (size_t)NB * HD;
                bf16* wLs = hsLo + (size_t)s * DSLOT + (size_t)NB * HD;
                const int64_t h1b = (int64_t)(p1 * NLAY + 1) * NB * HD;
                #pragma unroll
                for (int mt = 0; mt < 2; mt++)
                    #pragma unroll
                    for (int r = 0; r < 4; r++) {
                        const int b = mt * 16 + (lane >> 4) * 4 + r;
                        const float rg = sigm(p[0 + mt][r] + brr);
                        const float zg = sigm(p[2 + mt][r] + bzz);
                        const float ng = tanhf(p[4 + mt][r] + bin + rg * (p[6 + mt][r] + bhn));
                        const float hold = h32[h1b + (int64_t)b * HD + j];
                        const float hnew = (1.f - zg) * ng + zg * hold;
                        bf16 hh = f2b(hnew);
                        bf16 hl = f2b(hnew - b2f(hh));
                        h32[(int64_t)(np1 * NLAY + 1) * NB * HD + (int64_t)b * HD + j] = hnew;
                        const int lo_ = b * HD + j;
                        wHs[lo_] = hh;
                        wLs[lo_] = hl;
                        const int64_t ro = ((int64_t)t * NB + b) * HD + j;
                        rnnHi[ro] = hh;
                        rnnLo[ro] = hl;
                    }
            }
        }
    }
}

// =====================================================================
__global__ __launch_bounds__(64) void softmax_k(const float* __restrict__ sc,
                                                float* __restrict__ aout)
{
    const int row = blockIdx.x, l = threadIdx.x;
    float v0 = sc[row * LI + l], v1 = sc[row * LI + 64 + l];
    float m = fmaxf(v0, v1);
    #pragma unroll
    for (int o = 32; o > 0; o >>= 1) m = fmaxf(m, __shfl_xor(m, o));
    float e0 = expf(v0 - m), e1 = expf(v1 - m);
    float s = e0 + e1;
    #pragma unroll
    for (int o = 32; o > 0; o >>= 1) s += __shfl_xor(s, o);
    const float inv = 1.f / s;
    aout[row * LI + l] = e0 * inv;
    aout[row * LI + 64 + l] = e1 * inv;
}

// ctx from hi/lo enc outputs -> hi/lo JIN
__global__ __launch_bounds__(256) void ctx2_k(const float* __restrict__ at,
                                              const bf16* __restrict__ eHi,
                                              const bf16* __restrict__ eLo,
                                              bf16* __restrict__ jHi,
                                              bf16* __restrict__ jLo)
{
    const int b = blockIdx.y, h0 = blockIdx.x * 128;
    __shared__ __align__(16) float al[LO][LI];
    for (int i = threadIdx.x; i < LO * LI; i += 256) {
        const int to = i >> 7, ti = i & 127;
        al[to][ti] = at[(to * NB + b) * LI + ti];
    }
    __syncthreads();
    const int hc = h0 + (threadIdx.x & 127);
    const int rh = threadIdx.x >> 7;
    float acc[32];
    #pragma unroll
    for (int i = 0; i < 32; i++) acc[i] = 0.f;
    for (int t = 0; t < LI; t++) {
        const int64_t eo = ((int64_t)t * NB + b) * HD + hc;
        const float ev = b2f(eHi[eo]) + b2f(eLo[eo]);
        #pragma unroll
        for (int i = 0; i < 32; i++) acc[i] += ev * al[rh * 32 + i][t];
    }
    #pragma unroll
    for (int i = 0; i < 32; i++) {
        const int64_t jo = ((int64_t)(rh * 32 + i) * NB + b) * (2 * HD) + hc;
        bf16 hh = f2b(acc[i]);
        jHi[jo] = hh;
        jLo[jo] = f2b(acc[i] - b2f(hh));
    }
}

// copy RNN hi/lo into JIN[:, HD:2HD]
__global__ void rnncopy2_k(const bf16* __restrict__ rHi, const bf16* __restrict__ rLo,
                           bf16* __restrict__ jHi, bf16* __restrict__ jLo)
{
    const int idx = blockIdx.x * 256 + threadIdx.x;
    const int row = idx >> 8;
    const int c = idx & 255;
    ((uint2*)jHi)[(int64_t)row * 512 + 256 + c] = ((const uint2*)rHi)[idx];
    ((uint2*)jLo)[(int64_t)row * 512 + 256 + c] = ((const uint2*)rLo)[idx];
}

// =====================================================================
extern "C" void kernel_launch(void* const* d_in, const int* in_sizes, int n_in,
                              void* d_out, int out_size, void* d_ws, size_t ws_size,
                              hipStream_t stream)
{
    (void)in_sizes; (void)n_in; (void)out_size; (void)ws_size;
    const int*   in_tok   = (const int*)d_in[0];
    const int*   out_tok  = (const int*)d_in[2];
    const float* enc_emb  = (const float*)d_in[4];
    const float* enc_wih  = (const float*)d_in[5];
    const float* enc_whh  = (const float*)d_in[6];
    const float* enc_bih  = (const float*)d_in[7];
    const float* enc_bhh  = (const float*)d_in[8];
    const float* dec_emb  = (const float*)d_in[9];
    const float* dec_wih  = (const float*)d_in[10];
    const float* dec_whh  = (const float*)d_in[11];
    const float* dec_bih  = (const float*)d_in[12];
    const float* dec_bhh  = (const float*)d_in[13];
    const float* attn_W   = (const float*)d_in[14];
    const float* joiner_W = (const float*)d_in[15];
    const float* joiner_b = (const float*)d_in[16];
    const float* proj_W   = (const float*)d_in[17];
    const float* proj_b   = (const float*)d_in[18];
    float* logits   = (float*)d_out;
    float* attn_out = logits + (size_t)LO * NB * NV;

    const size_t MB = 1ull << 20;
    char* o = (char*)d_out;   // logits region = 250 MiB fp32
    bf16* XB0HI  = (bf16*)(o);               // 8 MiB (dead after L0 gi)
    bf16* XB0LO  = (bf16*)(o + 8 * MB);      // 8 MiB
    bf16* XB1HI  = (bf16*)(o + 16 * MB);     // 8 MiB
    bf16* XB1LO  = (bf16*)(o + 24 * MB);     // 8 MiB
    bf16* EOUTHI = (bf16*)(o + 32 * MB);     // 8 MiB (alive until ctx)
    bf16* EOUTLO = (bf16*)(o + 40 * MB);     // 8 MiB
    float* PENC  = (float*)(o + 48 * MB);    // 16 MiB fp32
    float* GI    = (float*)(o + 64 * MB);    // 48 MiB fp32
    float* DGI0  = (float*)(o + 112 * MB);   // 24 MiB fp32
    bf16* ENCH_HI = (bf16*)(o + 136 * MB);   // 8 MiB per-step slots
    bf16* ENCH_LO = (bf16*)(o + 144 * MB);   // 8 MiB
    bf16* JINHI  = (bf16*)(o + 152 * MB);    // 8 MiB (written post-dec)
    bf16* JINLO  = (bf16*)(o + 160 * MB);    // 8 MiB
    bf16* RNNHI  = (bf16*)(o + 168 * MB);    // 4 MiB
    bf16* RNNLO  = (bf16*)(o + 172 * MB);    // 4 MiB
    float* SC    = (float*)(o + 176 * MB);   // 1 MiB
    bf16* WencHi = (bf16*)(o + 177 * MB);    // 6 MiB
    bf16* WencLo = (bf16*)(o + 183 * MB);    // 6 MiB
    bf16* WdhHi  = (bf16*)(o + 189 * MB);    // 12 MiB
    bf16* WdhLo  = (bf16*)(o + 201 * MB);    // 12 MiB
    bf16* Wih1Hi = (bf16*)(o + 213 * MB);    // 6 MiB
    bf16* Wih1Lo = (bf16*)(o + 219 * MB);    // 6 MiB
    char* ba     = o + 225 * MB;             // 3 MiB barrier arena
    f32x4* PART  = (f32x4*)(o + 228 * MB);   // 0.5 MiB
    bf16* DEMBHI = (bf16*)(o + 229 * MB);    // 4 MiB
    bf16* DEMBLO = (bf16*)(o + 233 * MB);    // 4 MiB -> ends 237 < 250
    bf16* DECH_HI = XB0HI;                   // dec per-step slots (XB0 dead)
    bf16* DECH_LO = JINHI;                   // (JIN written post-dec)

    char* w = (char*)d_ws;
    bf16* VECSHI = (bf16*)(w);                        // 4 MiB
    bf16* VECSLO = (bf16*)(w + 4 * MB);               // 4 MiB
    float* EH32  = (float*)(w + 8 * MB);              // 512 KiB
    float* DH32  = (float*)(w + 8 * MB + 524288);     // 512 KiB

    const size_t KB = 1024;
    int* FL_E  = (int*)(ba);                 // 64 x 8KB = 512 KiB
    int* EP_E  = (int*)(ba + 512 * KB);      // 16 x 8KB = 128 KiB
    int* FLAGD = (int*)(ba + 640 * KB);      // 64 x 8KB = 512 KiB -> 1152 KiB

    hipMemsetAsync(ba, 0, 2 * MB, stream);
    hipMemsetAsync(ENCH_HI, 0, (size_t)ESLOT * 2, stream);   // enc slot 0 = zeros
    hipMemsetAsync(ENCH_LO, 0, (size_t)ESLOT * 2, stream);

    // ---- pre-split recurrent weights ----
    const int nEnc = NLAY * 2 * 3 * HHD * HHD;
    const int nDhh = NLAY * 3 * HD * HD;
    const int nIh1 = 3 * HD * HD;
    presplit_k<<<dim3((nEnc + 255) / 256), dim3(256), 0, stream>>>(enc_whh, WencHi, WencLo, nEnc);
    presplit_k<<<dim3((nDhh + 255) / 256), dim3(256), 0, stream>>>(dec_whh, WdhHi, WdhLo, nDhh);
    presplit_k<<<dim3((nIh1 + 255) / 256), dim3(256), 0, stream>>>(dec_wih + (size_t)3 * HD * HD, Wih1Hi, Wih1Lo, nIh1);

    // ---- decoder prep ----
    embed2_k<<<dim3(LO * NB), dim3(256), 0, stream>>>(out_tok, dec_emb, DEMBHI, DEMBLO, 1);
    gemmWf_k<128, true, false, 0><<<dim3(3 * HD / 128, LO * NB / 128, 1), 256, 0, stream>>>(
        DEMBHI, DEMBLO, HD, 0, dec_wih, HD, 0,
        DGI0, nullptr, nullptr, 3 * HD, 0, dec_bih, 0, HD);

    // ---- encoder ----
    embed2_k<<<dim3(LI * NB), dim3(256), 0, stream>>>(in_tok, enc_emb, XB0HI, XB0LO, 0);
    for (int l = 0; l < NLAY; l++) {
        const bf16* XinH = l ? XB1HI : XB0HI;
        const bf16* XinL = l ? XB1LO : XB0LO;
        bf16* YoH = l ? EOUTHI : XB1HI;
        bf16* YoL = l ? EOUTLO : XB1LO;
        hipMemsetAsync(EH32, 0, (size_t)2 * 2 * NB * HHD * 4, stream);
        gemmWf_k<128, true, false, 0><<<dim3(3 * HHD / 128, LI * NB / 128, 2), 256, 0, stream>>>(
            XinH, XinL, HD, 0,
            enc_wih + (size_t)l * 2 * 3 * HHD * HD, HD, (int64_t)3 * HHD * HD,
            GI, nullptr, nullptr, 3 * HHD, (int64_t)LI * NB * 3 * HHD,
            enc_bih + l * 2 * 3 * HHD, 3 * HHD, HD);
        enc_persist_k<<<dim3(HHD / 16, 2), dim3(256), 0, stream>>>(
            GI,
            WencHi + (size_t)l * 2 * 3 * HHD * HHD,
            WencLo + (size_t)l * 2 * 3 * HHD * HHD,
            enc_bhh + l * 2 * 3 * HHD,
            EH32, ENCH_HI, ENCH_LO, YoH, YoL,
            DH32 + (size_t)l * NB * HD,
            DECH_HI + (size_t)l * NB * HD,
            DECH_LO + (size_t)l * NB * HD,
            FL_E, EP_E);
    }

    // proj_enc = enc_outputs @ attn_W^T
    gemmWf_k<128, false, false, 0><<<dim3(HD / 128, LI * NB / 128, 1), 256, 0, stream>>>(
        EOUTHI, EOUTLO, HD, 0, attn_W, HD, 0,
        PENC, nullptr, nullptr, HD, 0, nullptr, 0, HD);

    // ---- decoder recurrence: 65 per-step launches ----
    for (int s = 0; s <= LO; s++)
        dec_step_k<<<dim3(HD / 16, 3), dim3(512), 0, stream>>>(
            DGI0,
            Wih1Hi, Wih1Lo,
            WdhHi, WdhLo,
            WdhHi + (size_t)3 * HD * HD, WdhLo + (size_t)3 * HD * HD,
            dec_bih + 3 * HD, dec_bhh, dec_bhh + 3 * HD,
            DH32, DECH_HI, DECH_LO, RNNHI, RNNLO, PART, FLAGD, s);

    // ---- batched epilogue ----
    gemmWf_k<64, false, false, 0><<<dim3(1, 1, NB), 256, 0, stream>>>(
        RNNHI, RNNLO, (int64_t)NB * HD, HD, PENC, (int64_t)NB * HD, HD,
        SC, nullptr, nullptr, (int64_t)NB * LI, LI, nullptr, 0, HD);
    softmax_k<<<dim3(LO * NB), dim3(64), 0, stream>>>(SC, attn_out);
    ctx2_k<<<dim3(HD / 128, NB), dim3(256), 0, stream>>>(attn_out, EOUTHI, EOUTLO, JINHI, JINLO);
    rnncopy2_k<<<dim3(LO * NB * HD / 4 / 256), dim3(256), 0, stream>>>(RNNHI, RNNLO, JINHI, JINLO);
    gemmWf_k<128, true, true, 1><<<dim3(HD / 128, LO * NB / 128, 1), 256, 0, stream>>>(
        JINHI, JINLO, 2 * HD, 0, joiner_W, 2 * HD, 0,
        nullptr, VECSHI, VECSLO, HD, 0, joiner_b, 0, 2 * HD);
    gemmWf_k<128, true, false, 0><<<dim3(NV / 128, LO * NB / 128, 1), 256, 0, stream>>>(
        VECSHI, VECSLO, HD, 0, proj_W, HD, 0,
        logits, nullptr, nullptr, NV, 0, proj_b, 0, HD);
}